// Round 12
// baseline (309.313 us; speedup 1.0000x reference)
//
#include <hip/hip_runtime.h>
#include <math.h>

// Problem constants
#define BATCH 8
#define CH 256
#define HH 45
#define WW 80
#define HW 3600        // 45*80
#define PTOT 28800     // BATCH*HW

typedef unsigned short u16;
typedef unsigned int   u32;
typedef __attribute__((ext_vector_type(8))) short bf16x8;
typedef __attribute__((ext_vector_type(4))) float f32x4;

struct __align__(8) us4 { u16 x, y, z, w; };

__device__ __forceinline__ u16 bf16_rne(float x) {
  u32 u = __float_as_uint(x);
  u += 0x7FFF + ((u >> 16) & 1);
  return (u16)(u >> 16);
}

// ---------------------------------------------------------------------------
// K0: weight prep (all bf16 transposes)
// ---------------------------------------------------------------------------
__global__ __launch_bounds__(256) void prep_wts(
    const float* __restrict__ conv1_w, const float* __restrict__ off_w,
    const float* __restrict__ dcn_w,
    u16* __restrict__ w1b, u16* __restrict__ wt_offb, u16* __restrict__ wt_b)
{
  int i = blockIdx.x * 256 + threadIdx.x;
  if (i < 256 * 256) {
    w1b[i] = bf16_rne(conv1_w[i]);
  }
  if (i < 9 * 32 * 512) {
    int tap = i >> 14;
    int r   = i & 16383;
    int oc  = r >> 9;
    int c   = r & 511;
    float v = (oc < 27) ? off_w[((size_t)oc * 512 + c) * 9 + tap] : 0.f;
    wt_offb[i] = bf16_rne(v);
  }
  if (i < 9 * 256 * 256) {
    int c = i & 255;
    int oc = (i >> 8) & 255;
    int tap = i >> 16;
    wt_b[i] = bf16_rne(dcn_w[((size_t)oc * 256 + c) * 9 + tap]);
  }
}

// ---------------------------------------------------------------------------
// K1: flip-transpose x -> concat[P][0:256] bf16 (w-flipped NHWC)
// ---------------------------------------------------------------------------
__global__ __launch_bounds__(256) void flip_transpose(
    const float* __restrict__ x, u16* __restrict__ concat)
{
  __shared__ float tile[32][36];
  const int b  = blockIdx.z;
  const int c0 = blockIdx.y * 32;
  const int p0 = blockIdx.x * 32;
  int rem = HW - p0; if (rem > 32) rem = 32;
  const int t = threadIdx.x;
  {
    int c = t >> 3, p4 = (t & 7) * 4;
    if (p4 < rem) {
      float4 v = *(const float4*)(x + ((size_t)b * CH + c0 + c) * HW + p0 + p4);
      *(float4*)&tile[c][p4] = v;
    }
  }
  __syncthreads();
  {
    int r = t >> 3, cq = (t & 7) * 4;
    if (r < rem) {
      int p = p0 + r;
      int h = p / WW, w = p - h * WW;
      int pf = h * WW + (WW - 1 - w);
      us4 o;
      o.x = bf16_rne(tile[cq + 0][r]);
      o.y = bf16_rne(tile[cq + 1][r]);
      o.z = bf16_rne(tile[cq + 2][r]);
      o.w = bf16_rne(tile[cq + 3][r]);
      *(us4*)(concat + ((size_t)b * HW + pf) * 512 + c0 + cq) = o;
    }
  }
}

// ---------------------------------------------------------------------------
// K2: conv1 via MFMA, XCD b-swizzled: grid (232 = 8b x 29 ptiles, 2 octiles).
// Fused per-block (sum,sumsq) partials -> part_c1[slot][128][2],
// slot = (wv>>1) + 2*blockIdx.x + 464*blockIdx.y.
// ---------------------------------------------------------------------------
__global__ __launch_bounds__(256) void conv1_mfma(
    const u16* __restrict__ concat, const u16* __restrict__ w1b,
    float* __restrict__ out1, float* __restrict__ part_c1)
{
  const int t = threadIdx.x;
  const int wv = t >> 6, lane = t & 63;
  const int lr = lane & 15, lk = lane >> 4;
  const int id = blockIdx.x;
  const int b  = id & 7;
  const int pt = id >> 3;                    // 0..28
  const int oc0 = blockIdx.y * 128 + (wv & 1) * 64;
  const int p0  = pt * 128 + (wv >> 1) * 64; // within image

  const u16* bptr[4];
#pragma unroll
  for (int nt = 0; nt < 4; nt++) {
    int pl = p0 + nt * 16 + lr;
    int pc = pl < HW ? pl : HW - 1;
    int h = pc / WW, w = pc - h * WW;
    int pf = b * HW + h * WW + (WW - 1 - w);
    bptr[nt] = concat + (size_t)pf * 512 + lk * 8;
  }
  const u16* aptr = w1b + ((size_t)(oc0 + lr)) * 256 + lk * 8;

  f32x4 acc[4][4];
#pragma unroll
  for (int mt = 0; mt < 4; mt++)
#pragma unroll
    for (int nt = 0; nt < 4; nt++) acc[mt][nt] = (f32x4)0.f;

#pragma unroll
  for (int cc = 0; cc < 8; cc++) {
    bf16x8 af[4], bfv[4];
#pragma unroll
    for (int mt = 0; mt < 4; mt++)
      af[mt] = *(const bf16x8*)(aptr + (size_t)mt * 16 * 256 + cc * 32);
#pragma unroll
    for (int nt = 0; nt < 4; nt++)
      bfv[nt] = *(const bf16x8*)(bptr[nt] + cc * 32);
#pragma unroll
    for (int mt = 0; mt < 4; mt++)
#pragma unroll
      for (int nt = 0; nt < 4; nt++)
        acc[mt][nt] = __builtin_amdgcn_mfma_f32_16x16x32_bf16(
            af[mt], bfv[nt], acc[mt][nt], 0, 0, 0);
  }

#pragma unroll
  for (int mt = 0; mt < 4; mt++) {
    int oc = oc0 + mt * 16 + lk * 4;
#pragma unroll
    for (int nt = 0; nt < 4; nt++) {
      int pl = p0 + nt * 16 + lr;
      if (pl < HW) {
        float* dst = out1 + ((size_t)(b * CH + oc)) * HW + pl;
#pragma unroll
        for (int r = 0; r < 4; r++)
          dst[(size_t)r * HW] = acc[mt][nt][r];
      }
    }
  }

  // fused stats partials: sum over this wave's valid positions
  float sv[4][4], sq[4][4];
#pragma unroll
  for (int mt = 0; mt < 4; mt++)
#pragma unroll
    for (int r = 0; r < 4; r++) { sv[mt][r] = 0.f; sq[mt][r] = 0.f; }
#pragma unroll
  for (int mt = 0; mt < 4; mt++)
#pragma unroll
    for (int nt = 0; nt < 4; nt++) {
      int pl = p0 + nt * 16 + lr;
      if (pl < HW) {
#pragma unroll
        for (int r = 0; r < 4; r++) {
          float v = acc[mt][nt][r];
          sv[mt][r] += v; sq[mt][r] += v * v;
        }
      }
    }
#pragma unroll
  for (int m = 1; m < 16; m <<= 1) {
#pragma unroll
    for (int mt = 0; mt < 4; mt++)
#pragma unroll
      for (int r = 0; r < 4; r++) {
        sv[mt][r] += __shfl_xor(sv[mt][r], m, 64);
        sq[mt][r] += __shfl_xor(sq[mt][r], m, 64);
      }
  }
  if (lr == 0) {
    int slot = (wv >> 1) + 2 * blockIdx.x + 464 * blockIdx.y;
    float* pp = part_c1 + (size_t)slot * 128 * 2;
#pragma unroll
    for (int mt = 0; mt < 4; mt++)
#pragma unroll
      for (int r = 0; r < 4; r++) {
        int ocl = (wv & 1) * 64 + mt * 16 + lk * 4 + r;
        pp[ocl * 2]     = sv[mt][r];
        pp[ocl * 2 + 1] = sq[mt][r];
      }
  }
}

// ---------------------------------------------------------------------------
// K3a: finalize conv1 stats: sum 464 slots per channel-half.
// ---------------------------------------------------------------------------
__global__ __launch_bounds__(256) void stats_fin_c1(
    const float* __restrict__ part_c1, float* __restrict__ st)
{
  const int c = threadIdx.x;
  const int y = c >> 7, ocl = c & 127;
  const float* base = part_c1 + (size_t)y * 464 * 128 * 2 + ocl * 2;
  float s = 0.f, s2 = 0.f;
#pragma unroll 8
  for (int i = 0; i < 464; i++) {
    s  += base[(size_t)i * 256];
    s2 += base[(size_t)i * 256 + 1];
  }
  float m = s / (float)PTOT;
  float var = s2 / (float)PTOT - m * m;
  st[c] = m;
  st[CH + c] = rsqrtf(var + 1e-5f);
}

// ---------------------------------------------------------------------------
// K3b: finalize deform stats: sum 456 block slots per channel.
// ---------------------------------------------------------------------------
__global__ __launch_bounds__(256) void stats_fin_d(
    const float* __restrict__ part_d, float* __restrict__ st)
{
  const int c = threadIdx.x;
  float s = 0.f, s2 = 0.f;
#pragma unroll 8
  for (int i = 0; i < 456; i++) {
    s  += part_d[(size_t)i * 512 + c * 2];
    s2 += part_d[(size_t)i * 512 + c * 2 + 1];
  }
  float m = s / (float)PTOT;
  float var = s2 / (float)PTOT - m * m;
  st[c] = m;
  st[CH + c] = rsqrtf(var + 1e-5f);
}

// ---------------------------------------------------------------------------
// K4: read RAW out1, write normalized bf16 into concat[P][256:512].
// ---------------------------------------------------------------------------
__global__ __launch_bounds__(256) void norm_transpose(
    const float* __restrict__ out1, const float* __restrict__ st,
    const float* __restrict__ g, const float* __restrict__ bb,
    u16* __restrict__ concat)
{
  __shared__ float tile[32][36];
  const int b  = blockIdx.z;
  const int c0 = blockIdx.y * 32;
  const int p0 = blockIdx.x * 32;
  int rem = HW - p0; if (rem > 32) rem = 32;
  const int t = threadIdx.x;

  {
    int c  = t >> 3;
    int p4 = (t & 7) * 4;
    int cg = c0 + c;
    float m  = st[cg], rs = st[CH + cg];
    float sc = g[cg] * rs;
    float sh = bb[cg] - m * sc;
    if (p4 < rem) {
      size_t base = ((size_t)b * CH + cg) * HW + p0;
      float4 v = *(const float4*)(out1 + base + p4);
      v.x = v.x * sc + sh; v.y = v.y * sc + sh;
      v.z = v.z * sc + sh; v.w = v.w * sc + sh;
      *(float4*)&tile[c][p4] = v;
    }
  }
  __syncthreads();
  {
    int r  = t >> 3;
    int cq = (t & 7) * 4;
    if (r < rem) {
      us4 o;
      o.x = bf16_rne(tile[cq + 0][r]);
      o.y = bf16_rne(tile[cq + 1][r]);
      o.z = bf16_rne(tile[cq + 2][r]);
      o.w = bf16_rne(tile[cq + 3][r]);
      *(us4*)(concat + ((size_t)b * HW + p0 + r) * 512 + 256 + c0 + cq) = o;
    }
  }
}

// ---------------------------------------------------------------------------
// K5: offset conv via MFMA, tap-split 3-ways; XCD b-swizzled.
// ---------------------------------------------------------------------------
__global__ __launch_bounds__(128) void off_mfma(
    const u16* __restrict__ concat, const u16* __restrict__ wt_offb,
    float* __restrict__ offp3)
{
  const int t = threadIdx.x;
  const int g = blockIdx.y;
  const int wv = t >> 6, lane = t & 63;
  const int lr = lane & 15, lk = lane >> 4;
  const int id = blockIdx.x;
  const int b    = id & 7;
  const int tile = id >> 3;            // 0..112
  int pl = tile * 32 + wv * 16 + lr;   // 0..3615
  const bool pvalid = pl < HW;
  if (!pvalid) pl = HW - 1;
  const int P = b * HW + pl;
  const int h = pl / WW, w = pl - h * WW;

  f32x4 acc[2];
  acc[0] = (f32x4)0.f; acc[1] = (f32x4)0.f;

#pragma unroll 1
  for (int tl = 0; tl < 3; tl++) {
    int tap = g * 3 + tl;
    int dy = tap / 3 - 1, dx = tap % 3 - 1;
    bool valid = ((unsigned)(h + dy) < HH) && ((unsigned)(w + dx) < WW);
    int Ps = valid ? (P + dy * WW + dx) : P;
    const u16* bp = concat + (size_t)Ps * 512 + lk * 8;
    const u16* ap = wt_offb + ((size_t)tap * 32 + lr) * 512 + lk * 8;
#pragma unroll
    for (int cc = 0; cc < 16; cc++) {
      bf16x8 bfv = *(const bf16x8*)(bp + cc * 32);
      if (!valid) bfv = (bf16x8)(short)0;
      bf16x8 af0 = *(const bf16x8*)(ap + cc * 32);
      bf16x8 af1 = *(const bf16x8*)(ap + 16 * 512 + cc * 32);
      acc[0] = __builtin_amdgcn_mfma_f32_16x16x32_bf16(af0, bfv, acc[0], 0, 0, 0);
      acc[1] = __builtin_amdgcn_mfma_f32_16x16x32_bf16(af1, bfv, acc[1], 0, 0, 0);
    }
  }

  if (pvalid) {
#pragma unroll
    for (int mt = 0; mt < 2; mt++) {
      int oc = mt * 16 + lk * 4;
#pragma unroll
      for (int r = 0; r < 4; r++)
        offp3[((size_t)g * 32 + oc + r) * PTOT + P] = acc[mt][r];
    }
  }
}

// ---------------------------------------------------------------------------
// K6: finalize offsets -> bilinear params per (tap, P). Sums 3 tap-group partials.
// ---------------------------------------------------------------------------
__global__ __launch_bounds__(256) void off_finalize(
    const float* __restrict__ offp3, const float* __restrict__ off_b,
    float4* __restrict__ wts4, int4* __restrict__ idx4)
{
  int i = blockIdx.x * 256 + threadIdx.x;
  if (i >= 9 * PTOT) return;
  int k = i / PTOT;
  int P = i - k * PTOT;
  int b = P / HW;
  int p = P - b * HW;
  int h = p / WW;
  int w = p - h * WW;

  float dy = off_b[2 * k], dx = off_b[2 * k + 1], ml = off_b[18 + k];
#pragma unroll
  for (int g = 0; g < 3; g++) {
    const float* base = offp3 + (size_t)g * 32 * PTOT + P;
    dy += base[(size_t)(2 * k    ) * PTOT];
    dx += base[(size_t)(2 * k + 1) * PTOT];
    ml += base[(size_t)(18 + k   ) * PTOT];
  }

  float m = 1.f / (1.f + expf(-ml));
  float ph = dy + (float)(k / 3 - 1) + (float)h;
  float pw = dx + (float)(k % 3 - 1) + (float)w;
  float h0f = floorf(ph), w0f = floorf(pw);
  float lh = ph - h0f, lw = pw - w0f;
  int h0 = (int)h0f, w0 = (int)w0f;
  int h1 = h0 + 1, w1 = w0 + 1;
  float vh0 = (h0 >= 0 && h0 < HH) ? 1.f : 0.f;
  float vh1 = (h1 >= 0 && h1 < HH) ? 1.f : 0.f;
  float vw0 = (w0 >= 0 && w0 < WW) ? 1.f : 0.f;
  float vw1 = (w1 >= 0 && w1 < WW) ? 1.f : 0.f;
  float4 wv;
  wv.x = (1.f - lh) * (1.f - lw) * m * vh0 * vw0;
  wv.y = (1.f - lh) * lw         * m * vh0 * vw1;
  wv.z = lh * (1.f - lw)         * m * vh1 * vw0;
  wv.w = lh * lw                 * m * vh1 * vw1;
  int hc0 = min(max(h0, 0), HH - 1), hc1 = min(max(h1, 0), HH - 1);
  int wc0 = min(max(w0, 0), WW - 1), wc1 = min(max(w1, 0), WW - 1);
  int base = b * HW;
  int4 iv;
  iv.x = (base + hc0 * WW + wc0) * 512 + 256;
  iv.y = (base + hc0 * WW + wc1) * 512 + 256;
  iv.z = (base + hc1 * WW + wc0) * 512 + 256;
  iv.w = (base + hc1 * WW + wc1) * 512 + 256;
  wts4[i] = wv;
  idx4[i] = iv;
}

// ---------------------------------------------------------------------------
// K7: deformable conv via MFMA bf16 — R5/R10 structure (frozen, 114 us) +
// fused per-block stats partials -> part_d[blockIdx][256][2].
// ---------------------------------------------------------------------------
__global__ __launch_bounds__(512) void deform_mfma(
    const u16* __restrict__ concat,
    const float4* __restrict__ wts4, const int4* __restrict__ idx4,
    const u16* __restrict__ wt_b,
    float* __restrict__ d, float* __restrict__ part_d)
{
  __shared__ u16   samp[64 * 256];   // swizzled: byte ^= (pos&7)<<4
  __shared__ float4 sw4[64];
  __shared__ int4   sidx4[64];

  const int t    = threadIdx.x;
  const int wv   = t >> 6;           // 0..7
  const int lane = t & 63;
  const int lr = lane & 15, lk = lane >> 4;
  const int id   = blockIdx.x;
  const int b    = id & 7;
  const int tile = id >> 3;          // 0..56
  const int P0   = b * HW + tile * 64;
  int lim  = HW - tile * 64;         // valid positions in this tile (<=64)
  if (lim > 64) lim = 64;

  f32x4 acc[2][4];
#pragma unroll
  for (int mt = 0; mt < 2; mt++)
#pragma unroll
    for (int nt = 0; nt < 4; nt++) acc[mt][nt] = (f32x4)0.f;

  const int c4 = lane * 4;

  for (int tap = 0; tap < 9; tap++) {
    __syncthreads();
    if (t < 64) {
      int off = (t < lim) ? t : (lim - 1);
      sw4[t]   = wts4[(size_t)tap * PTOT + P0 + off];
      sidx4[t] = idx4[(size_t)tap * PTOT + P0 + off];
    }
    __syncthreads();

    // build samp: 8 iters, each wave one pos per iter
#pragma unroll 2
    for (int it = 0; it < 8; it++) {
      int pos = it * 8 + wv;
      int4  iv = sidx4[pos];
      float4 wq = sw4[pos];
      uint2 u0 = *(const uint2*)(concat + iv.x + c4);
      uint2 u1 = *(const uint2*)(concat + iv.y + c4);
      uint2 u2 = *(const uint2*)(concat + iv.z + c4);
      uint2 u3 = *(const uint2*)(concat + iv.w + c4);
      float a0, a1, a2, a3;
      a0  = wq.x * __uint_as_float(u0.x << 16);
      a1  = wq.x * __uint_as_float(u0.x & 0xFFFF0000u);
      a2  = wq.x * __uint_as_float(u0.y << 16);
      a3  = wq.x * __uint_as_float(u0.y & 0xFFFF0000u);
      a0 = fmaf(wq.y, __uint_as_float(u1.x << 16), a0);
      a1 = fmaf(wq.y, __uint_as_float(u1.x & 0xFFFF0000u), a1);
      a2 = fmaf(wq.y, __uint_as_float(u1.y << 16), a2);
      a3 = fmaf(wq.y, __uint_as_float(u1.y & 0xFFFF0000u), a3);
      a0 = fmaf(wq.z, __uint_as_float(u2.x << 16), a0);
      a1 = fmaf(wq.z, __uint_as_float(u2.x & 0xFFFF0000u), a1);
      a2 = fmaf(wq.z, __uint_as_float(u2.y << 16), a2);
      a3 = fmaf(wq.z, __uint_as_float(u2.y & 0xFFFF0000u), a3);
      a0 = fmaf(wq.w, __uint_as_float(u3.x << 16), a0);
      a1 = fmaf(wq.w, __uint_as_float(u3.x & 0xFFFF0000u), a1);
      a2 = fmaf(wq.w, __uint_as_float(u3.y << 16), a2);
      a3 = fmaf(wq.w, __uint_as_float(u3.y & 0xFFFF0000u), a3);
      uint2 r;
      r.x = (__float_as_uint(a0) >> 16) | (__float_as_uint(a1) & 0xFFFF0000u);
      r.y = (__float_as_uint(a2) >> 16) | (__float_as_uint(a3) & 0xFFFF0000u);
      u32 byte = (u32)pos * 512u + (u32)c4 * 2u;
      byte ^= (u32)(pos & 7) << 4;
      *(uint2*)((char*)samp + byte) = r;
    }
    __syncthreads();

#pragma unroll 1
    for (int cc = 0; cc < 8; cc++) {
      int c0 = cc * 32;
      bf16x8 bfr[4];
#pragma unroll
      for (int nt = 0; nt < 4; nt++) {
        int pos = nt * 16 + lr;
        u32 byte = (u32)pos * 512u + (u32)(c0 + lk * 8) * 2u;
        byte ^= (u32)(pos & 7) << 4;
        bfr[nt] = *(const bf16x8*)((const char*)samp + byte);
      }
      const u16* wp = wt_b + ((size_t)tap * 256 + wv * 32 + lr) * 256
                      + c0 + lk * 8;
      bf16x8 afr[2];
#pragma unroll
      for (int mt = 0; mt < 2; mt++)
        afr[mt] = *(const bf16x8*)(wp + (size_t)mt * 16 * 256);
#pragma unroll
      for (int mt = 0; mt < 2; mt++)
#pragma unroll
        for (int nt = 0; nt < 4; nt++)
          acc[mt][nt] = __builtin_amdgcn_mfma_f32_16x16x32_bf16(
              afr[mt], bfr[nt], acc[mt][nt], 0, 0, 0);
    }
  }

  // epilogue: D[oc][pos] -> d NCHW
#pragma unroll
  for (int mt = 0; mt < 2; mt++) {
    int oc = wv * 32 + mt * 16 + lk * 4;
#pragma unroll
    for (int nt = 0; nt < 4; nt++) {
      int pl = tile * 64 + nt * 16 + lr;
      if (pl < HW) {
        float* dst = d + ((size_t)(b * CH + oc)) * HW + pl;
#pragma unroll
        for (int r = 0; r < 4; r++)
          dst[(size_t)r * HW] = acc[mt][nt][r];
      }
    }
  }

  // fused stats partials (sum over this block's valid positions)
  float sv[2][4], sq[2][4];
#pragma unroll
  for (int mt = 0; mt < 2; mt++)
#pragma unroll
    for (int r = 0; r < 4; r++) { sv[mt][r] = 0.f; sq[mt][r] = 0.f; }
#pragma unroll
  for (int mt = 0; mt < 2; mt++)
#pragma unroll
    for (int nt = 0; nt < 4; nt++) {
      int pl = tile * 64 + nt * 16 + lr;
      if (pl < HW) {
#pragma unroll
        for (int r = 0; r < 4; r++) {
          float v = acc[mt][nt][r];
          sv[mt][r] += v; sq[mt][r] += v * v;
        }
      }
    }
#pragma unroll
  for (int m = 1; m < 16; m <<= 1) {
#pragma unroll
    for (int mt = 0; mt < 2; mt++)
#pragma unroll
      for (int r = 0; r < 4; r++) {
        sv[mt][r] += __shfl_xor(sv[mt][r], m, 64);
        sq[mt][r] += __shfl_xor(sq[mt][r], m, 64);
      }
  }
  if (lr == 0) {
    float* pp = part_d + (size_t)blockIdx.x * 512;
#pragma unroll
    for (int mt = 0; mt < 2; mt++)
#pragma unroll
      for (int r = 0; r < 4; r++) {
        int oc = wv * 32 + mt * 16 + lk * 4 + r;
        pp[oc * 2]     = sv[mt][r];
        pp[oc * 2 + 1] = sq[mt][r];
      }
  }
}

// ---------------------------------------------------------------------------
// K8: final = relu(d*sc2+sh2 + (out1raw*sc1+sh1)), all NCHW, float4.
// ---------------------------------------------------------------------------
__global__ __launch_bounds__(256) void final_nchw(
    const float* __restrict__ d, const float* __restrict__ out1raw,
    const float* __restrict__ st1, const float* __restrict__ g1,
    const float* __restrict__ b1,
    const float* __restrict__ st2, const float* __restrict__ g2,
    const float* __restrict__ b2, float* __restrict__ out)
{
  u32 i4 = blockIdx.x * 256 + threadIdx.x;
  u32 e = i4 * 4;
  int row = (int)(e / HW);
  int c = row & 255;
  float m1 = st1[c], rs1 = st1[CH + c];
  float sc1 = g1[c] * rs1;
  float sh1 = b1[c] - m1 * sc1;
  float m2 = st2[c], rs2 = st2[CH + c];
  float sc2 = g2[c] * rs2;
  float sh2 = b2[c] - m2 * sc2;
  float4 dv = *(const float4*)(d + e);
  float4 xv = *(const float4*)(out1raw + e);
  float4 o;
  o.x = dv.x * sc2 + sh2 + xv.x * sc1 + sh1;
  o.y = dv.y * sc2 + sh2 + xv.y * sc1 + sh1;
  o.z = dv.z * sc2 + sh2 + xv.z * sc1 + sh1;
  o.w = dv.w * sc2 + sh2 + xv.w * sc1 + sh1;
  o.x = o.x > 0.f ? o.x : 0.f;
  o.y = o.y > 0.f ? o.y : 0.f;
  o.z = o.z > 0.f ? o.z : 0.f;
  o.w = o.w > 0.f ? o.w : 0.f;
  *(float4*)(out + e) = o;
}

// ---------------------------------------------------------------------------
extern "C" void kernel_launch(void* const* d_in, const int* in_sizes, int n_in,
                              void* d_out, int out_size, void* d_ws, size_t ws_size,
                              hipStream_t stream)
{
  const float* x       = (const float*)d_in[0];
  const float* conv1_w = (const float*)d_in[1];
  const float* bn1_g   = (const float*)d_in[2];
  const float* bn1_b   = (const float*)d_in[3];
  const float* off_w   = (const float*)d_in[4];
  const float* off_b   = (const float*)d_in[5];
  const float* dcn_w   = (const float*)d_in[6];
  const float* norm_g  = (const float*)d_in[8];
  const float* norm_b  = (const float*)d_in[9];
  float* out = (float*)d_out;

  char* ws = (char*)d_ws;
  size_t o = 0;
  float* out1    = (float*)(ws + o); o += (size_t)PTOT * CH * 4;       // 29.5 MB (RAW conv1 output)
  u16*   concat  = (u16*)  (ws + o); o += (size_t)PTOT * 512 * 2;      // 29.5 MB NHWC bf16 [flipx | xp]
  float* dbuf    = (float*)(ws + o); o += (size_t)PTOT * CH * 4;       // 29.5 MB NCHW
  float* offp3   = (float*)(ws + o); o += (size_t)96 * PTOT * 4;       // 11.1 MB
  u16*   wt_b    = (u16*)  (ws + o); o += (size_t)9 * 256 * 256 * 2;   // 1.18 MB
  u16*   wt_offb = (u16*)  (ws + o); o += (size_t)9 * 32 * 512 * 2;    // 0.29 MB
  u16*   w1b     = (u16*)  (ws + o); o += (size_t)256 * 256 * 2;       // 0.13 MB
  float4* wts4   = (float4*)(ws + o); o += (size_t)9 * PTOT * 16;      // 4.15 MB
  int4*   idx4   = (int4*) (ws + o); o += (size_t)9 * PTOT * 16;       // 4.15 MB
  float* st      = (float*)(ws + o); o += 512 * 4;
  float* st2     = (float*)(ws + o); o += 512 * 4;
  float* part_c1 = (float*)(ws + o); o += (size_t)928 * 128 * 2 * 4;   // 950 KB
  float* part_d  = (float*)(ws + o); o += (size_t)456 * 512 * 4;       // 934 KB

  prep_wts<<<2304, 256, 0, stream>>>(conv1_w, off_w, dcn_w, w1b, wt_offb, wt_b);
  flip_transpose<<<dim3(113, 8, 8), 256, 0, stream>>>(x, concat);
  conv1_mfma<<<dim3(232, 2), 256, 0, stream>>>(concat, w1b, out1, part_c1);
  stats_fin_c1<<<1, 256, 0, stream>>>(part_c1, st);
  norm_transpose<<<dim3(113, 8, 8), 256, 0, stream>>>(out1, st, bn1_g, bn1_b, concat);
  off_mfma<<<dim3(904, 3), 128, 0, stream>>>(concat, wt_offb, offp3);
  off_finalize<<<(9 * PTOT + 255) / 256, 256, 0, stream>>>(offp3, off_b, wts4, idx4);
  deform_mfma<<<456, 512, 0, stream>>>(concat, wts4, idx4, wt_b, dbuf, part_d);
  stats_fin_d<<<1, 256, 0, stream>>>(part_d, st2);
  final_nchw<<<7200, 256, 0, stream>>>(dbuf, out1, st, bn1_g, bn1_b,
                                       st2, norm_g, norm_b, out);
}

// Round 13
// 274.598 us; speedup vs baseline: 1.1264x; 1.1264x over previous
//
#include <hip/hip_runtime.h>
#include <math.h>

// Problem constants
#define BATCH 8
#define CH 256
#define HH 45
#define WW 80
#define HW 3600        // 45*80
#define PTOT 28800     // BATCH*HW

typedef unsigned short u16;
typedef unsigned int   u32;
typedef __attribute__((ext_vector_type(8))) short bf16x8;
typedef __attribute__((ext_vector_type(4))) float f32x4;

struct __align__(8) us4 { u16 x, y, z, w; };

__device__ __forceinline__ u16 bf16_rne(float x) {
  u32 u = __float_as_uint(x);
  u += 0x7FFF + ((u >> 16) & 1);
  return (u16)(u >> 16);
}

// ---------------------------------------------------------------------------
// K0: weight prep (all bf16 transposes)
// ---------------------------------------------------------------------------
__global__ __launch_bounds__(256) void prep_wts(
    const float* __restrict__ conv1_w, const float* __restrict__ off_w,
    const float* __restrict__ dcn_w,
    u16* __restrict__ w1b, u16* __restrict__ wt_offb, u16* __restrict__ wt_b)
{
  int i = blockIdx.x * 256 + threadIdx.x;
  if (i < 256 * 256) {
    w1b[i] = bf16_rne(conv1_w[i]);
  }
  if (i < 9 * 32 * 512) {
    int tap = i >> 14;
    int r   = i & 16383;
    int oc  = r >> 9;
    int c   = r & 511;
    float v = (oc < 27) ? off_w[((size_t)oc * 512 + c) * 9 + tap] : 0.f;
    wt_offb[i] = bf16_rne(v);
  }
  if (i < 9 * 256 * 256) {
    int c = i & 255;
    int oc = (i >> 8) & 255;
    int tap = i >> 16;
    wt_b[i] = bf16_rne(dcn_w[((size_t)oc * 256 + c) * 9 + tap]);
  }
}

// ---------------------------------------------------------------------------
// K1: flip-transpose x -> concat[P][0:256] bf16 (w-flipped NHWC)
// ---------------------------------------------------------------------------
__global__ __launch_bounds__(256) void flip_transpose(
    const float* __restrict__ x, u16* __restrict__ concat)
{
  __shared__ float tile[32][36];
  const int b  = blockIdx.z;
  const int c0 = blockIdx.y * 32;
  const int p0 = blockIdx.x * 32;
  int rem = HW - p0; if (rem > 32) rem = 32;
  const int t = threadIdx.x;
  {
    int c = t >> 3, p4 = (t & 7) * 4;
    if (p4 < rem) {
      float4 v = *(const float4*)(x + ((size_t)b * CH + c0 + c) * HW + p0 + p4);
      *(float4*)&tile[c][p4] = v;
    }
  }
  __syncthreads();
  {
    int r = t >> 3, cq = (t & 7) * 4;
    if (r < rem) {
      int p = p0 + r;
      int h = p / WW, w = p - h * WW;
      int pf = h * WW + (WW - 1 - w);
      us4 o;
      o.x = bf16_rne(tile[cq + 0][r]);
      o.y = bf16_rne(tile[cq + 1][r]);
      o.z = bf16_rne(tile[cq + 2][r]);
      o.w = bf16_rne(tile[cq + 3][r]);
      *(us4*)(concat + ((size_t)b * HW + pf) * 512 + c0 + cq) = o;
    }
  }
}

// ---------------------------------------------------------------------------
// K2: conv1 via MFMA, XCD b-swizzled + fused stats partials.
// ---------------------------------------------------------------------------
__global__ __launch_bounds__(256) void conv1_mfma(
    const u16* __restrict__ concat, const u16* __restrict__ w1b,
    float* __restrict__ out1, float* __restrict__ part_c1)
{
  const int t = threadIdx.x;
  const int wv = t >> 6, lane = t & 63;
  const int lr = lane & 15, lk = lane >> 4;
  const int id = blockIdx.x;
  const int b  = id & 7;
  const int pt = id >> 3;                    // 0..28
  const int oc0 = blockIdx.y * 128 + (wv & 1) * 64;
  const int p0  = pt * 128 + (wv >> 1) * 64; // within image

  const u16* bptr[4];
#pragma unroll
  for (int nt = 0; nt < 4; nt++) {
    int pl = p0 + nt * 16 + lr;
    int pc = pl < HW ? pl : HW - 1;
    int h = pc / WW, w = pc - h * WW;
    int pf = b * HW + h * WW + (WW - 1 - w);
    bptr[nt] = concat + (size_t)pf * 512 + lk * 8;
  }
  const u16* aptr = w1b + ((size_t)(oc0 + lr)) * 256 + lk * 8;

  f32x4 acc[4][4];
#pragma unroll
  for (int mt = 0; mt < 4; mt++)
#pragma unroll
    for (int nt = 0; nt < 4; nt++) acc[mt][nt] = (f32x4)0.f;

#pragma unroll
  for (int cc = 0; cc < 8; cc++) {
    bf16x8 af[4], bfv[4];
#pragma unroll
    for (int mt = 0; mt < 4; mt++)
      af[mt] = *(const bf16x8*)(aptr + (size_t)mt * 16 * 256 + cc * 32);
#pragma unroll
    for (int nt = 0; nt < 4; nt++)
      bfv[nt] = *(const bf16x8*)(bptr[nt] + cc * 32);
#pragma unroll
    for (int mt = 0; mt < 4; mt++)
#pragma unroll
      for (int nt = 0; nt < 4; nt++)
        acc[mt][nt] = __builtin_amdgcn_mfma_f32_16x16x32_bf16(
            af[mt], bfv[nt], acc[mt][nt], 0, 0, 0);
  }

#pragma unroll
  for (int mt = 0; mt < 4; mt++) {
    int oc = oc0 + mt * 16 + lk * 4;
#pragma unroll
    for (int nt = 0; nt < 4; nt++) {
      int pl = p0 + nt * 16 + lr;
      if (pl < HW) {
        float* dst = out1 + ((size_t)(b * CH + oc)) * HW + pl;
#pragma unroll
        for (int r = 0; r < 4; r++)
          dst[(size_t)r * HW] = acc[mt][nt][r];
      }
    }
  }

  // fused stats partials: sum over this wave's valid positions
  float sv[4][4], sq[4][4];
#pragma unroll
  for (int mt = 0; mt < 4; mt++)
#pragma unroll
    for (int r = 0; r < 4; r++) { sv[mt][r] = 0.f; sq[mt][r] = 0.f; }
#pragma unroll
  for (int mt = 0; mt < 4; mt++)
#pragma unroll
    for (int nt = 0; nt < 4; nt++) {
      int pl = p0 + nt * 16 + lr;
      if (pl < HW) {
#pragma unroll
        for (int r = 0; r < 4; r++) {
          float v = acc[mt][nt][r];
          sv[mt][r] += v; sq[mt][r] += v * v;
        }
      }
    }
#pragma unroll
  for (int m = 1; m < 16; m <<= 1) {
#pragma unroll
    for (int mt = 0; mt < 4; mt++)
#pragma unroll
      for (int r = 0; r < 4; r++) {
        sv[mt][r] += __shfl_xor(sv[mt][r], m, 64);
        sq[mt][r] += __shfl_xor(sq[mt][r], m, 64);
      }
  }
  if (lr == 0) {
    int slot = (wv >> 1) + 2 * blockIdx.x + 464 * blockIdx.y;
    float* pp = part_c1 + (size_t)slot * 128 * 2;
#pragma unroll
    for (int mt = 0; mt < 4; mt++)
#pragma unroll
      for (int r = 0; r < 4; r++) {
        int ocl = (wv & 1) * 64 + mt * 16 + lk * 4 + r;
        pp[ocl * 2]     = sv[mt][r];
        pp[ocl * 2 + 1] = sq[mt][r];
      }
  }
}

// ---------------------------------------------------------------------------
// K3a: finalize conv1 stats — 256 blocks (one per channel), 256 thr each.
// ---------------------------------------------------------------------------
__global__ __launch_bounds__(256) void stats_fin_c1(
    const float* __restrict__ part_c1, float* __restrict__ st)
{
  const int c = blockIdx.x;
  const int y = c >> 7, ocl = c & 127;
  const int t = threadIdx.x;
  const float* base = part_c1 + (size_t)y * 464 * 256 + ocl * 2;
  float s = 0.f, s2 = 0.f;
  for (int i = t; i < 464; i += 256) {
    s  += base[(size_t)i * 256];
    s2 += base[(size_t)i * 256 + 1];
  }
  __shared__ float ls[256], ls2[256];
  ls[t] = s; ls2[t] = s2;
  __syncthreads();
  for (int off = 128; off > 0; off >>= 1) {
    if (t < off) { ls[t] += ls[t + off]; ls2[t] += ls2[t + off]; }
    __syncthreads();
  }
  if (t == 0) {
    float m = ls[0] / (float)PTOT;
    float var = ls2[0] / (float)PTOT - m * m;
    st[c] = m;
    st[CH + c] = rsqrtf(var + 1e-5f);
  }
}

// ---------------------------------------------------------------------------
// K3b: finalize deform stats — 256 blocks (one per channel), 256 thr each.
// ---------------------------------------------------------------------------
__global__ __launch_bounds__(256) void stats_fin_d(
    const float* __restrict__ part_d, float* __restrict__ st)
{
  const int c = blockIdx.x;
  const int t = threadIdx.x;
  float s = 0.f, s2 = 0.f;
  for (int i = t; i < 456; i += 256) {
    s  += part_d[(size_t)i * 512 + c * 2];
    s2 += part_d[(size_t)i * 512 + c * 2 + 1];
  }
  __shared__ float ls[256], ls2[256];
  ls[t] = s; ls2[t] = s2;
  __syncthreads();
  for (int off = 128; off > 0; off >>= 1) {
    if (t < off) { ls[t] += ls[t + off]; ls2[t] += ls2[t + off]; }
    __syncthreads();
  }
  if (t == 0) {
    float m = ls[0] / (float)PTOT;
    float var = ls2[0] / (float)PTOT - m * m;
    st[c] = m;
    st[CH + c] = rsqrtf(var + 1e-5f);
  }
}

// ---------------------------------------------------------------------------
// K4: read RAW out1, write normalized bf16 into concat[P][256:512].
// ---------------------------------------------------------------------------
__global__ __launch_bounds__(256) void norm_transpose(
    const float* __restrict__ out1, const float* __restrict__ st,
    const float* __restrict__ g, const float* __restrict__ bb,
    u16* __restrict__ concat)
{
  __shared__ float tile[32][36];
  const int b  = blockIdx.z;
  const int c0 = blockIdx.y * 32;
  const int p0 = blockIdx.x * 32;
  int rem = HW - p0; if (rem > 32) rem = 32;
  const int t = threadIdx.x;

  {
    int c  = t >> 3;
    int p4 = (t & 7) * 4;
    int cg = c0 + c;
    float m  = st[cg], rs = st[CH + cg];
    float sc = g[cg] * rs;
    float sh = bb[cg] - m * sc;
    if (p4 < rem) {
      size_t base = ((size_t)b * CH + cg) * HW + p0;
      float4 v = *(const float4*)(out1 + base + p4);
      v.x = v.x * sc + sh; v.y = v.y * sc + sh;
      v.z = v.z * sc + sh; v.w = v.w * sc + sh;
      *(float4*)&tile[c][p4] = v;
    }
  }
  __syncthreads();
  {
    int r  = t >> 3;
    int cq = (t & 7) * 4;
    if (r < rem) {
      us4 o;
      o.x = bf16_rne(tile[cq + 0][r]);
      o.y = bf16_rne(tile[cq + 1][r]);
      o.z = bf16_rne(tile[cq + 2][r]);
      o.w = bf16_rne(tile[cq + 3][r]);
      *(us4*)(concat + ((size_t)b * HW + p0 + r) * 512 + 256 + c0 + cq) = o;
    }
  }
}

// ---------------------------------------------------------------------------
// K5: offset conv via MFMA, tap-split 3-ways; XCD b-swizzled.
// ---------------------------------------------------------------------------
__global__ __launch_bounds__(128) void off_mfma(
    const u16* __restrict__ concat, const u16* __restrict__ wt_offb,
    float* __restrict__ offp3)
{
  const int t = threadIdx.x;
  const int g = blockIdx.y;
  const int wv = t >> 6, lane = t & 63;
  const int lr = lane & 15, lk = lane >> 4;
  const int id = blockIdx.x;
  const int b    = id & 7;
  const int tile = id >> 3;            // 0..112
  int pl = tile * 32 + wv * 16 + lr;   // 0..3615
  const bool pvalid = pl < HW;
  if (!pvalid) pl = HW - 1;
  const int P = b * HW + pl;
  const int h = pl / WW, w = pl - h * WW;

  f32x4 acc[2];
  acc[0] = (f32x4)0.f; acc[1] = (f32x4)0.f;

#pragma unroll 1
  for (int tl = 0; tl < 3; tl++) {
    int tap = g * 3 + tl;
    int dy = tap / 3 - 1, dx = tap % 3 - 1;
    bool valid = ((unsigned)(h + dy) < HH) && ((unsigned)(w + dx) < WW);
    int Ps = valid ? (P + dy * WW + dx) : P;
    const u16* bp = concat + (size_t)Ps * 512 + lk * 8;
    const u16* ap = wt_offb + ((size_t)tap * 32 + lr) * 512 + lk * 8;
#pragma unroll
    for (int cc = 0; cc < 16; cc++) {
      bf16x8 bfv = *(const bf16x8*)(bp + cc * 32);
      if (!valid) bfv = (bf16x8)(short)0;
      bf16x8 af0 = *(const bf16x8*)(ap + cc * 32);
      bf16x8 af1 = *(const bf16x8*)(ap + 16 * 512 + cc * 32);
      acc[0] = __builtin_amdgcn_mfma_f32_16x16x32_bf16(af0, bfv, acc[0], 0, 0, 0);
      acc[1] = __builtin_amdgcn_mfma_f32_16x16x32_bf16(af1, bfv, acc[1], 0, 0, 0);
    }
  }

  if (pvalid) {
#pragma unroll
    for (int mt = 0; mt < 2; mt++) {
      int oc = mt * 16 + lk * 4;
#pragma unroll
      for (int r = 0; r < 4; r++)
        offp3[((size_t)g * 32 + oc + r) * PTOT + P] = acc[mt][r];
    }
  }
}

// ---------------------------------------------------------------------------
// K6: finalize offsets -> bilinear params per (tap, P). Sums 3 tap-group partials.
// ---------------------------------------------------------------------------
__global__ __launch_bounds__(256) void off_finalize(
    const float* __restrict__ offp3, const float* __restrict__ off_b,
    float4* __restrict__ wts4, int4* __restrict__ idx4)
{
  int i = blockIdx.x * 256 + threadIdx.x;
  if (i >= 9 * PTOT) return;
  int k = i / PTOT;
  int P = i - k * PTOT;
  int b = P / HW;
  int p = P - b * HW;
  int h = p / WW;
  int w = p - h * WW;

  float dy = off_b[2 * k], dx = off_b[2 * k + 1], ml = off_b[18 + k];
#pragma unroll
  for (int g = 0; g < 3; g++) {
    const float* base = offp3 + (size_t)g * 32 * PTOT + P;
    dy += base[(size_t)(2 * k    ) * PTOT];
    dx += base[(size_t)(2 * k + 1) * PTOT];
    ml += base[(size_t)(18 + k   ) * PTOT];
  }

  float m = 1.f / (1.f + expf(-ml));
  float ph = dy + (float)(k / 3 - 1) + (float)h;
  float pw = dx + (float)(k % 3 - 1) + (float)w;
  float h0f = floorf(ph), w0f = floorf(pw);
  float lh = ph - h0f, lw = pw - w0f;
  int h0 = (int)h0f, w0 = (int)w0f;
  int h1 = h0 + 1, w1 = w0 + 1;
  float vh0 = (h0 >= 0 && h0 < HH) ? 1.f : 0.f;
  float vh1 = (h1 >= 0 && h1 < HH) ? 1.f : 0.f;
  float vw0 = (w0 >= 0 && w0 < WW) ? 1.f : 0.f;
  float vw1 = (w1 >= 0 && w1 < WW) ? 1.f : 0.f;
  float4 wv;
  wv.x = (1.f - lh) * (1.f - lw) * m * vh0 * vw0;
  wv.y = (1.f - lh) * lw         * m * vh0 * vw1;
  wv.z = lh * (1.f - lw)         * m * vh1 * vw0;
  wv.w = lh * lw                 * m * vh1 * vw1;
  int hc0 = min(max(h0, 0), HH - 1), hc1 = min(max(h1, 0), HH - 1);
  int wc0 = min(max(w0, 0), WW - 1), wc1 = min(max(w1, 0), WW - 1);
  int base = b * HW;
  int4 iv;
  iv.x = (base + hc0 * WW + wc0) * 512 + 256;
  iv.y = (base + hc0 * WW + wc1) * 512 + 256;
  iv.z = (base + hc1 * WW + wc0) * 512 + 256;
  iv.w = (base + hc1 * WW + wc1) * 512 + 256;
  wts4[i] = wv;
  idx4[i] = iv;
}

// ---------------------------------------------------------------------------
// K7: deformable conv via MFMA bf16 — R5/R10 structure (frozen, 114 us) +
// fused per-block stats partials -> part_d[blockIdx][256][2].
// ---------------------------------------------------------------------------
__global__ __launch_bounds__(512) void deform_mfma(
    const u16* __restrict__ concat,
    const float4* __restrict__ wts4, const int4* __restrict__ idx4,
    const u16* __restrict__ wt_b,
    float* __restrict__ d, float* __restrict__ part_d)
{
  __shared__ u16   samp[64 * 256];   // swizzled: byte ^= (pos&7)<<4
  __shared__ float4 sw4[64];
  __shared__ int4   sidx4[64];

  const int t    = threadIdx.x;
  const int wv   = t >> 6;           // 0..7
  const int lane = t & 63;
  const int lr = lane & 15, lk = lane >> 4;
  const int id   = blockIdx.x;
  const int b    = id & 7;
  const int tile = id >> 3;          // 0..56
  const int P0   = b * HW + tile * 64;
  int lim  = HW - tile * 64;         // valid positions in this tile (<=64)
  if (lim > 64) lim = 64;

  f32x4 acc[2][4];
#pragma unroll
  for (int mt = 0; mt < 2; mt++)
#pragma unroll
    for (int nt = 0; nt < 4; nt++) acc[mt][nt] = (f32x4)0.f;

  const int c4 = lane * 4;

  for (int tap = 0; tap < 9; tap++) {
    __syncthreads();
    if (t < 64) {
      int off = (t < lim) ? t : (lim - 1);
      sw4[t]   = wts4[(size_t)tap * PTOT + P0 + off];
      sidx4[t] = idx4[(size_t)tap * PTOT + P0 + off];
    }
    __syncthreads();

    // build samp: 8 iters, each wave one pos per iter
#pragma unroll 2
    for (int it = 0; it < 8; it++) {
      int pos = it * 8 + wv;
      int4  iv = sidx4[pos];
      float4 wq = sw4[pos];
      uint2 u0 = *(const uint2*)(concat + iv.x + c4);
      uint2 u1 = *(const uint2*)(concat + iv.y + c4);
      uint2 u2 = *(const uint2*)(concat + iv.z + c4);
      uint2 u3 = *(const uint2*)(concat + iv.w + c4);
      float a0, a1, a2, a3;
      a0  = wq.x * __uint_as_float(u0.x << 16);
      a1  = wq.x * __uint_as_float(u0.x & 0xFFFF0000u);
      a2  = wq.x * __uint_as_float(u0.y << 16);
      a3  = wq.x * __uint_as_float(u0.y & 0xFFFF0000u);
      a0 = fmaf(wq.y, __uint_as_float(u1.x << 16), a0);
      a1 = fmaf(wq.y, __uint_as_float(u1.x & 0xFFFF0000u), a1);
      a2 = fmaf(wq.y, __uint_as_float(u1.y << 16), a2);
      a3 = fmaf(wq.y, __uint_as_float(u1.y & 0xFFFF0000u), a3);
      a0 = fmaf(wq.z, __uint_as_float(u2.x << 16), a0);
      a1 = fmaf(wq.z, __uint_as_float(u2.x & 0xFFFF0000u), a1);
      a2 = fmaf(wq.z, __uint_as_float(u2.y << 16), a2);
      a3 = fmaf(wq.z, __uint_as_float(u2.y & 0xFFFF0000u), a3);
      a0 = fmaf(wq.w, __uint_as_float(u3.x << 16), a0);
      a1 = fmaf(wq.w, __uint_as_float(u3.x & 0xFFFF0000u), a1);
      a2 = fmaf(wq.w, __uint_as_float(u3.y << 16), a2);
      a3 = fmaf(wq.w, __uint_as_float(u3.y & 0xFFFF0000u), a3);
      uint2 r;
      r.x = (__float_as_uint(a0) >> 16) | (__float_as_uint(a1) & 0xFFFF0000u);
      r.y = (__float_as_uint(a2) >> 16) | (__float_as_uint(a3) & 0xFFFF0000u);
      u32 byte = (u32)pos * 512u + (u32)c4 * 2u;
      byte ^= (u32)(pos & 7) << 4;
      *(uint2*)((char*)samp + byte) = r;
    }
    __syncthreads();

#pragma unroll 1
    for (int cc = 0; cc < 8; cc++) {
      int c0 = cc * 32;
      bf16x8 bfr[4];
#pragma unroll
      for (int nt = 0; nt < 4; nt++) {
        int pos = nt * 16 + lr;
        u32 byte = (u32)pos * 512u + (u32)(c0 + lk * 8) * 2u;
        byte ^= (u32)(pos & 7) << 4;
        bfr[nt] = *(const bf16x8*)((const char*)samp + byte);
      }
      const u16* wp = wt_b + ((size_t)tap * 256 + wv * 32 + lr) * 256
                      + c0 + lk * 8;
      bf16x8 afr[2];
#pragma unroll
      for (int mt = 0; mt < 2; mt++)
        afr[mt] = *(const bf16x8*)(wp + (size_t)mt * 16 * 256);
#pragma unroll
      for (int mt = 0; mt < 2; mt++)
#pragma unroll
        for (int nt = 0; nt < 4; nt++)
          acc[mt][nt] = __builtin_amdgcn_mfma_f32_16x16x32_bf16(
              afr[mt], bfr[nt], acc[mt][nt], 0, 0, 0);
    }
  }

  // epilogue: D[oc][pos] -> d NCHW
#pragma unroll
  for (int mt = 0; mt < 2; mt++) {
    int oc = wv * 32 + mt * 16 + lk * 4;
#pragma unroll
    for (int nt = 0; nt < 4; nt++) {
      int pl = tile * 64 + nt * 16 + lr;
      if (pl < HW) {
        float* dst = d + ((size_t)(b * CH + oc)) * HW + pl;
#pragma unroll
        for (int r = 0; r < 4; r++)
          dst[(size_t)r * HW] = acc[mt][nt][r];
      }
    }
  }

  // fused stats partials (sum over this block's valid positions)
  float sv[2][4], sq[2][4];
#pragma unroll
  for (int mt = 0; mt < 2; mt++)
#pragma unroll
    for (int r = 0; r < 4; r++) { sv[mt][r] = 0.f; sq[mt][r] = 0.f; }
#pragma unroll
  for (int mt = 0; mt < 2; mt++)
#pragma unroll
    for (int nt = 0; nt < 4; nt++) {
      int pl = tile * 64 + nt * 16 + lr;
      if (pl < HW) {
#pragma unroll
        for (int r = 0; r < 4; r++) {
          float v = acc[mt][nt][r];
          sv[mt][r] += v; sq[mt][r] += v * v;
        }
      }
    }
#pragma unroll
  for (int m = 1; m < 16; m <<= 1) {
#pragma unroll
    for (int mt = 0; mt < 2; mt++)
#pragma unroll
      for (int r = 0; r < 4; r++) {
        sv[mt][r] += __shfl_xor(sv[mt][r], m, 64);
        sq[mt][r] += __shfl_xor(sq[mt][r], m, 64);
      }
  }
  if (lr == 0) {
    float* pp = part_d + (size_t)blockIdx.x * 512;
#pragma unroll
    for (int mt = 0; mt < 2; mt++)
#pragma unroll
      for (int r = 0; r < 4; r++) {
        int oc = wv * 32 + mt * 16 + lk * 4 + r;
        pp[oc * 2]     = sv[mt][r];
        pp[oc * 2 + 1] = sq[mt][r];
      }
  }
}

// ---------------------------------------------------------------------------
// K8: final = relu(d*sc2+sh2 + (out1raw*sc1+sh1)), all NCHW, float4.
// ---------------------------------------------------------------------------
__global__ __launch_bounds__(256) void final_nchw(
    const float* __restrict__ d, const float* __restrict__ out1raw,
    const float* __restrict__ st1, const float* __restrict__ g1,
    const float* __restrict__ b1,
    const float* __restrict__ st2, const float* __restrict__ g2,
    const float* __restrict__ b2, float* __restrict__ out)
{
  u32 i4 = blockIdx.x * 256 + threadIdx.x;
  u32 e = i4 * 4;
  int row = (int)(e / HW);
  int c = row & 255;
  float m1 = st1[c], rs1 = st1[CH + c];
  float sc1 = g1[c] * rs1;
  float sh1 = b1[c] - m1 * sc1;
  float m2 = st2[c], rs2 = st2[CH + c];
  float sc2 = g2[c] * rs2;
  float sh2 = b2[c] - m2 * sc2;
  float4 dv = *(const float4*)(d + e);
  float4 xv = *(const float4*)(out1raw + e);
  float4 o;
  o.x = dv.x * sc2 + sh2 + xv.x * sc1 + sh1;
  o.y = dv.y * sc2 + sh2 + xv.y * sc1 + sh1;
  o.z = dv.z * sc2 + sh2 + xv.z * sc1 + sh1;
  o.w = dv.w * sc2 + sh2 + xv.w * sc1 + sh1;
  o.x = o.x > 0.f ? o.x : 0.f;
  o.y = o.y > 0.f ? o.y : 0.f;
  o.z = o.z > 0.f ? o.z : 0.f;
  o.w = o.w > 0.f ? o.w : 0.f;
  *(float4*)(out + e) = o;
}

// ---------------------------------------------------------------------------
extern "C" void kernel_launch(void* const* d_in, const int* in_sizes, int n_in,
                              void* d_out, int out_size, void* d_ws, size_t ws_size,
                              hipStream_t stream)
{
  const float* x       = (const float*)d_in[0];
  const float* conv1_w = (const float*)d_in[1];
  const float* bn1_g   = (const float*)d_in[2];
  const float* bn1_b   = (const float*)d_in[3];
  const float* off_w   = (const float*)d_in[4];
  const float* off_b   = (const float*)d_in[5];
  const float* dcn_w   = (const float*)d_in[6];
  const float* norm_g  = (const float*)d_in[8];
  const float* norm_b  = (const float*)d_in[9];
  float* out = (float*)d_out;

  char* ws = (char*)d_ws;
  size_t o = 0;
  float* out1    = (float*)(ws + o); o += (size_t)PTOT * CH * 4;       // 29.5 MB (RAW conv1 output)
  u16*   concat  = (u16*)  (ws + o); o += (size_t)PTOT * 512 * 2;      // 29.5 MB NHWC bf16 [flipx | xp]
  float* dbuf    = (float*)(ws + o); o += (size_t)PTOT * CH * 4;       // 29.5 MB NCHW
  float* offp3   = (float*)(ws + o); o += (size_t)96 * PTOT * 4;       // 11.1 MB
  u16*   wt_b    = (u16*)  (ws + o); o += (size_t)9 * 256 * 256 * 2;   // 1.18 MB
  u16*   wt_offb = (u16*)  (ws + o); o += (size_t)9 * 32 * 512 * 2;    // 0.29 MB
  u16*   w1b     = (u16*)  (ws + o); o += (size_t)256 * 256 * 2;       // 0.13 MB
  float4* wts4   = (float4*)(ws + o); o += (size_t)9 * PTOT * 16;      // 4.15 MB
  int4*   idx4   = (int4*) (ws + o); o += (size_t)9 * PTOT * 16;       // 4.15 MB
  float* st      = (float*)(ws + o); o += 512 * 4;
  float* st2     = (float*)(ws + o); o += 512 * 4;
  float* part_c1 = (float*)(ws + o); o += (size_t)928 * 128 * 2 * 4;   // 950 KB
  float* part_d  = (float*)(ws + o); o += (size_t)456 * 512 * 4;       // 934 KB

  prep_wts<<<2304, 256, 0, stream>>>(conv1_w, off_w, dcn_w, w1b, wt_offb, wt_b);
  flip_transpose<<<dim3(113, 8, 8), 256, 0, stream>>>(x, concat);
  conv1_mfma<<<dim3(232, 2), 256, 0, stream>>>(concat, w1b, out1, part_c1);
  stats_fin_c1<<<256, 256, 0, stream>>>(part_c1, st);
  norm_transpose<<<dim3(113, 8, 8), 256, 0, stream>>>(out1, st, bn1_g, bn1_b, concat);
  off_mfma<<<dim3(904, 3), 128, 0, stream>>>(concat, wt_offb, offp3);
  off_finalize<<<(9 * PTOT + 255) / 256, 256, 0, stream>>>(offp3, off_b, wts4, idx4);
  deform_mfma<<<456, 512, 0, stream>>>(concat, wts4, idx4, wt_b, dbuf, part_d);
  stats_fin_d<<<256, 256, 0, stream>>>(part_d, st2);
  final_nchw<<<7200, 256, 0, stream>>>(dbuf, out1, st, bn1_g, bn1_b,
                                       st2, norm_g, norm_b, out);
}

// Round 14
// 270.301 us; speedup vs baseline: 1.1443x; 1.0159x over previous
//
#include <hip/hip_runtime.h>
#include <math.h>

// Problem constants
#define BATCH 8
#define CH 256
#define HH 45
#define WW 80
#define HW 3600        // 45*80
#define PTOT 28800     // BATCH*HW

typedef unsigned short u16;
typedef unsigned int   u32;
typedef __attribute__((ext_vector_type(8))) short bf16x8;
typedef __attribute__((ext_vector_type(4))) float f32x4;

struct __align__(8) us4 { u16 x, y, z, w; };

__device__ __forceinline__ u16 bf16_rne(float x) {
  u32 u = __float_as_uint(x);
  u += 0x7FFF + ((u >> 16) & 1);
  return (u16)(u >> 16);
}

// ---------------------------------------------------------------------------
// K1: flip-transpose x -> concat[P][0:256] bf16 (w-flipped NHWC)
//     + merged weight prep (blocks with linid < 2304 also do prep slices).
// ---------------------------------------------------------------------------
__global__ __launch_bounds__(256) void flip_prep(
    const float* __restrict__ x, u16* __restrict__ concat,
    const float* __restrict__ conv1_w, const float* __restrict__ off_w,
    const float* __restrict__ dcn_w,
    u16* __restrict__ w1b, u16* __restrict__ wt_offb, u16* __restrict__ wt_b)
{
  __shared__ float tile[32][36];
  const int b  = blockIdx.z;
  const int c0 = blockIdx.y * 32;
  const int p0 = blockIdx.x * 32;
  int rem = HW - p0; if (rem > 32) rem = 32;
  const int t = threadIdx.x;

  // --- merged prep_wts (same indexing as the old kernel) ---
  {
    int linid = blockIdx.x + 113 * (blockIdx.y + 8 * blockIdx.z);
    if (linid < 2304) {
      int i = linid * 256 + t;
      if (i < 256 * 256) {
        w1b[i] = bf16_rne(conv1_w[i]);
      }
      if (i < 9 * 32 * 512) {
        int tap = i >> 14;
        int r   = i & 16383;
        int oc  = r >> 9;
        int c   = r & 511;
        float v = (oc < 27) ? off_w[((size_t)oc * 512 + c) * 9 + tap] : 0.f;
        wt_offb[i] = bf16_rne(v);
      }
      if (i < 9 * 256 * 256) {
        int c = i & 255;
        int oc = (i >> 8) & 255;
        int tap = i >> 16;
        wt_b[i] = bf16_rne(dcn_w[((size_t)oc * 256 + c) * 9 + tap]);
      }
    }
  }

  // --- flip transpose ---
  {
    int c = t >> 3, p4 = (t & 7) * 4;
    if (p4 < rem) {
      float4 v = *(const float4*)(x + ((size_t)b * CH + c0 + c) * HW + p0 + p4);
      *(float4*)&tile[c][p4] = v;
    }
  }
  __syncthreads();
  {
    int r = t >> 3, cq = (t & 7) * 4;
    if (r < rem) {
      int p = p0 + r;
      int h = p / WW, w = p - h * WW;
      int pf = h * WW + (WW - 1 - w);
      us4 o;
      o.x = bf16_rne(tile[cq + 0][r]);
      o.y = bf16_rne(tile[cq + 1][r]);
      o.z = bf16_rne(tile[cq + 2][r]);
      o.w = bf16_rne(tile[cq + 3][r]);
      *(us4*)(concat + ((size_t)b * HW + pf) * 512 + c0 + cq) = o;
    }
  }
}

// ---------------------------------------------------------------------------
// K2: conv1 via MFMA, XCD b-swizzled + fused stats partials.
// ---------------------------------------------------------------------------
__global__ __launch_bounds__(256) void conv1_mfma(
    const u16* __restrict__ concat, const u16* __restrict__ w1b,
    float* __restrict__ out1, float* __restrict__ part_c1)
{
  const int t = threadIdx.x;
  const int wv = t >> 6, lane = t & 63;
  const int lr = lane & 15, lk = lane >> 4;
  const int id = blockIdx.x;
  const int b  = id & 7;
  const int pt = id >> 3;                    // 0..28
  const int oc0 = blockIdx.y * 128 + (wv & 1) * 64;
  const int p0  = pt * 128 + (wv >> 1) * 64; // within image

  const u16* bptr[4];
#pragma unroll
  for (int nt = 0; nt < 4; nt++) {
    int pl = p0 + nt * 16 + lr;
    int pc = pl < HW ? pl : HW - 1;
    int h = pc / WW, w = pc - h * WW;
    int pf = b * HW + h * WW + (WW - 1 - w);
    bptr[nt] = concat + (size_t)pf * 512 + lk * 8;
  }
  const u16* aptr = w1b + ((size_t)(oc0 + lr)) * 256 + lk * 8;

  f32x4 acc[4][4];
#pragma unroll
  for (int mt = 0; mt < 4; mt++)
#pragma unroll
    for (int nt = 0; nt < 4; nt++) acc[mt][nt] = (f32x4)0.f;

#pragma unroll
  for (int cc = 0; cc < 8; cc++) {
    bf16x8 af[4], bfv[4];
#pragma unroll
    for (int mt = 0; mt < 4; mt++)
      af[mt] = *(const bf16x8*)(aptr + (size_t)mt * 16 * 256 + cc * 32);
#pragma unroll
    for (int nt = 0; nt < 4; nt++)
      bfv[nt] = *(const bf16x8*)(bptr[nt] + cc * 32);
#pragma unroll
    for (int mt = 0; mt < 4; mt++)
#pragma unroll
      for (int nt = 0; nt < 4; nt++)
        acc[mt][nt] = __builtin_amdgcn_mfma_f32_16x16x32_bf16(
            af[mt], bfv[nt], acc[mt][nt], 0, 0, 0);
  }

#pragma unroll
  for (int mt = 0; mt < 4; mt++) {
    int oc = oc0 + mt * 16 + lk * 4;
#pragma unroll
    for (int nt = 0; nt < 4; nt++) {
      int pl = p0 + nt * 16 + lr;
      if (pl < HW) {
        float* dst = out1 + ((size_t)(b * CH + oc)) * HW + pl;
#pragma unroll
        for (int r = 0; r < 4; r++)
          dst[(size_t)r * HW] = acc[mt][nt][r];
      }
    }
  }

  // fused stats partials: sum over this wave's valid positions
  float sv[4][4], sq[4][4];
#pragma unroll
  for (int mt = 0; mt < 4; mt++)
#pragma unroll
    for (int r = 0; r < 4; r++) { sv[mt][r] = 0.f; sq[mt][r] = 0.f; }
#pragma unroll
  for (int mt = 0; mt < 4; mt++)
#pragma unroll
    for (int nt = 0; nt < 4; nt++) {
      int pl = p0 + nt * 16 + lr;
      if (pl < HW) {
#pragma unroll
        for (int r = 0; r < 4; r++) {
          float v = acc[mt][nt][r];
          sv[mt][r] += v; sq[mt][r] += v * v;
        }
      }
    }
#pragma unroll
  for (int m = 1; m < 16; m <<= 1) {
#pragma unroll
    for (int mt = 0; mt < 4; mt++)
#pragma unroll
      for (int r = 0; r < 4; r++) {
        sv[mt][r] += __shfl_xor(sv[mt][r], m, 64);
        sq[mt][r] += __shfl_xor(sq[mt][r], m, 64);
      }
  }
  if (lr == 0) {
    int slot = (wv >> 1) + 2 * blockIdx.x + 464 * blockIdx.y;
    float* pp = part_c1 + (size_t)slot * 128 * 2;
#pragma unroll
    for (int mt = 0; mt < 4; mt++)
#pragma unroll
      for (int r = 0; r < 4; r++) {
        int ocl = (wv & 1) * 64 + mt * 16 + lk * 4 + r;
        pp[ocl * 2]     = sv[mt][r];
        pp[ocl * 2 + 1] = sq[mt][r];
      }
  }
}

// ---------------------------------------------------------------------------
// K3a: finalize conv1 stats — 256 blocks (one per channel), 256 thr each.
// ---------------------------------------------------------------------------
__global__ __launch_bounds__(256) void stats_fin_c1(
    const float* __restrict__ part_c1, float* __restrict__ st)
{
  const int c = blockIdx.x;
  const int y = c >> 7, ocl = c & 127;
  const int t = threadIdx.x;
  const float* base = part_c1 + (size_t)y * 464 * 256 + ocl * 2;
  float s = 0.f, s2 = 0.f;
  for (int i = t; i < 464; i += 256) {
    s  += base[(size_t)i * 256];
    s2 += base[(size_t)i * 256 + 1];
  }
  __shared__ float ls[256], ls2[256];
  ls[t] = s; ls2[t] = s2;
  __syncthreads();
  for (int off = 128; off > 0; off >>= 1) {
    if (t < off) { ls[t] += ls[t + off]; ls2[t] += ls2[t + off]; }
    __syncthreads();
  }
  if (t == 0) {
    float m = ls[0] / (float)PTOT;
    float var = ls2[0] / (float)PTOT - m * m;
    st[c] = m;
    st[CH + c] = rsqrtf(var + 1e-5f);
  }
}

// ---------------------------------------------------------------------------
// K3b: finalize deform stats — 256 blocks (one per channel), 256 thr each.
// ---------------------------------------------------------------------------
__global__ __launch_bounds__(256) void stats_fin_d(
    const float* __restrict__ part_d, float* __restrict__ st)
{
  const int c = blockIdx.x;
  const int t = threadIdx.x;
  float s = 0.f, s2 = 0.f;
  for (int i = t; i < 456; i += 256) {
    s  += part_d[(size_t)i * 512 + c * 2];
    s2 += part_d[(size_t)i * 512 + c * 2 + 1];
  }
  __shared__ float ls[256], ls2[256];
  ls[t] = s; ls2[t] = s2;
  __syncthreads();
  for (int off = 128; off > 0; off >>= 1) {
    if (t < off) { ls[t] += ls[t + off]; ls2[t] += ls2[t + off]; }
    __syncthreads();
  }
  if (t == 0) {
    float m = ls[0] / (float)PTOT;
    float var = ls2[0] / (float)PTOT - m * m;
    st[c] = m;
    st[CH + c] = rsqrtf(var + 1e-5f);
  }
}

// ---------------------------------------------------------------------------
// K4: read RAW out1, write normalized bf16 into concat[P][256:512].
// ---------------------------------------------------------------------------
__global__ __launch_bounds__(256) void norm_transpose(
    const float* __restrict__ out1, const float* __restrict__ st,
    const float* __restrict__ g, const float* __restrict__ bb,
    u16* __restrict__ concat)
{
  __shared__ float tile[32][36];
  const int b  = blockIdx.z;
  const int c0 = blockIdx.y * 32;
  const int p0 = blockIdx.x * 32;
  int rem = HW - p0; if (rem > 32) rem = 32;
  const int t = threadIdx.x;

  {
    int c  = t >> 3;
    int p4 = (t & 7) * 4;
    int cg = c0 + c;
    float m  = st[cg], rs = st[CH + cg];
    float sc = g[cg] * rs;
    float sh = bb[cg] - m * sc;
    if (p4 < rem) {
      size_t base = ((size_t)b * CH + cg) * HW + p0;
      float4 v = *(const float4*)(out1 + base + p4);
      v.x = v.x * sc + sh; v.y = v.y * sc + sh;
      v.z = v.z * sc + sh; v.w = v.w * sc + sh;
      *(float4*)&tile[c][p4] = v;
    }
  }
  __syncthreads();
  {
    int r  = t >> 3;
    int cq = (t & 7) * 4;
    if (r < rem) {
      us4 o;
      o.x = bf16_rne(tile[cq + 0][r]);
      o.y = bf16_rne(tile[cq + 1][r]);
      o.z = bf16_rne(tile[cq + 2][r]);
      o.w = bf16_rne(tile[cq + 3][r]);
      *(us4*)(concat + ((size_t)b * HW + p0 + r) * 512 + 256 + c0 + cq) = o;
    }
  }
}

// ---------------------------------------------------------------------------
// K5: offset conv via MFMA, tap-split 3-ways; XCD b-swizzled.
// ---------------------------------------------------------------------------
__global__ __launch_bounds__(128) void off_mfma(
    const u16* __restrict__ concat, const u16* __restrict__ wt_offb,
    float* __restrict__ offp3)
{
  const int t = threadIdx.x;
  const int g = blockIdx.y;
  const int wv = t >> 6, lane = t & 63;
  const int lr = lane & 15, lk = lane >> 4;
  const int id = blockIdx.x;
  const int b    = id & 7;
  const int tile = id >> 3;            // 0..112
  int pl = tile * 32 + wv * 16 + lr;   // 0..3615
  const bool pvalid = pl < HW;
  if (!pvalid) pl = HW - 1;
  const int P = b * HW + pl;
  const int h = pl / WW, w = pl - h * WW;

  f32x4 acc[2];
  acc[0] = (f32x4)0.f; acc[1] = (f32x4)0.f;

#pragma unroll 1
  for (int tl = 0; tl < 3; tl++) {
    int tap = g * 3 + tl;
    int dy = tap / 3 - 1, dx = tap % 3 - 1;
    bool valid = ((unsigned)(h + dy) < HH) && ((unsigned)(w + dx) < WW);
    int Ps = valid ? (P + dy * WW + dx) : P;
    const u16* bp = concat + (size_t)Ps * 512 + lk * 8;
    const u16* ap = wt_offb + ((size_t)tap * 32 + lr) * 512 + lk * 8;
#pragma unroll
    for (int cc = 0; cc < 16; cc++) {
      bf16x8 bfv = *(const bf16x8*)(bp + cc * 32);
      if (!valid) bfv = (bf16x8)(short)0;
      bf16x8 af0 = *(const bf16x8*)(ap + cc * 32);
      bf16x8 af1 = *(const bf16x8*)(ap + 16 * 512 + cc * 32);
      acc[0] = __builtin_amdgcn_mfma_f32_16x16x32_bf16(af0, bfv, acc[0], 0, 0, 0);
      acc[1] = __builtin_amdgcn_mfma_f32_16x16x32_bf16(af1, bfv, acc[1], 0, 0, 0);
    }
  }

  if (pvalid) {
#pragma unroll
    for (int mt = 0; mt < 2; mt++) {
      int oc = mt * 16 + lk * 4;
#pragma unroll
      for (int r = 0; r < 4; r++)
        offp3[((size_t)g * 32 + oc + r) * PTOT + P] = acc[mt][r];
    }
  }
}

// ---------------------------------------------------------------------------
// K6: finalize offsets -> bilinear params per (tap, P). Sums 3 tap-group partials.
// ---------------------------------------------------------------------------
__global__ __launch_bounds__(256) void off_finalize(
    const float* __restrict__ offp3, const float* __restrict__ off_b,
    float4* __restrict__ wts4, int4* __restrict__ idx4)
{
  int i = blockIdx.x * 256 + threadIdx.x;
  if (i >= 9 * PTOT) return;
  int k = i / PTOT;
  int P = i - k * PTOT;
  int b = P / HW;
  int p = P - b * HW;
  int h = p / WW;
  int w = p - h * WW;

  float dy = off_b[2 * k], dx = off_b[2 * k + 1], ml = off_b[18 + k];
#pragma unroll
  for (int g = 0; g < 3; g++) {
    const float* base = offp3 + (size_t)g * 32 * PTOT + P;
    dy += base[(size_t)(2 * k    ) * PTOT];
    dx += base[(size_t)(2 * k + 1) * PTOT];
    ml += base[(size_t)(18 + k   ) * PTOT];
  }

  float m = 1.f / (1.f + expf(-ml));
  float ph = dy + (float)(k / 3 - 1) + (float)h;
  float pw = dx + (float)(k % 3 - 1) + (float)w;
  float h0f = floorf(ph), w0f = floorf(pw);
  float lh = ph - h0f, lw = pw - w0f;
  int h0 = (int)h0f, w0 = (int)w0f;
  int h1 = h0 + 1, w1 = w0 + 1;
  float vh0 = (h0 >= 0 && h0 < HH) ? 1.f : 0.f;
  float vh1 = (h1 >= 0 && h1 < HH) ? 1.f : 0.f;
  float vw0 = (w0 >= 0 && w0 < WW) ? 1.f : 0.f;
  float vw1 = (w1 >= 0 && w1 < WW) ? 1.f : 0.f;
  float4 wv;
  wv.x = (1.f - lh) * (1.f - lw) * m * vh0 * vw0;
  wv.y = (1.f - lh) * lw         * m * vh0 * vw1;
  wv.z = lh * (1.f - lw)         * m * vh1 * vw0;
  wv.w = lh * lw                 * m * vh1 * vw1;
  int hc0 = min(max(h0, 0), HH - 1), hc1 = min(max(h1, 0), HH - 1);
  int wc0 = min(max(w0, 0), WW - 1), wc1 = min(max(w1, 0), WW - 1);
  int base = b * HW;
  int4 iv;
  iv.x = (base + hc0 * WW + wc0) * 512 + 256;
  iv.y = (base + hc0 * WW + wc1) * 512 + 256;
  iv.z = (base + hc1 * WW + wc0) * 512 + 256;
  iv.w = (base + hc1 * WW + wc1) * 512 + 256;
  wts4[i] = wv;
  idx4[i] = iv;
}

// ---------------------------------------------------------------------------
// K7: deformable conv via MFMA bf16 — R5/R10 structure with ALL-TAP param
// hoist: idx/wts for all 9 taps staged into LDS once at kernel entry, so the
// per-tap loop is build -> sync -> GEMM -> sync (2 barriers, no L2 param
// latency in the loop). Build/GEMM bodies identical to R13.
// ---------------------------------------------------------------------------
__global__ __launch_bounds__(512) void deform_mfma(
    const u16* __restrict__ concat,
    const float4* __restrict__ wts4, const int4* __restrict__ idx4,
    const u16* __restrict__ wt_b,
    float* __restrict__ d, float* __restrict__ part_d)
{
  __shared__ u16    samp[64 * 256];   // 32KB, swizzled: byte ^= (pos&7)<<4
  __shared__ int4   sidx[9][64];      // 9KB
  __shared__ float4 swq[9][64];       // 9KB

  const int t    = threadIdx.x;
  const int wv   = t >> 6;           // 0..7
  const int lane = t & 63;
  const int lr = lane & 15, lk = lane >> 4;
  const int id   = blockIdx.x;
  const int b    = id & 7;
  const int tile = id >> 3;          // 0..56
  const int P0   = b * HW + tile * 64;
  int lim  = HW - tile * 64;         // valid positions in this tile (<=64)
  if (lim > 64) lim = 64;

  // hoisted param stage: all 9 taps at once (576 items, 512 threads)
  for (int item = t; item < 9 * 64; item += 512) {
    int tap = item >> 6, pos = item & 63;
    int off = (pos < lim) ? pos : (lim - 1);
    sidx[tap][pos] = idx4[(size_t)tap * PTOT + P0 + off];
    swq[tap][pos]  = wts4[(size_t)tap * PTOT + P0 + off];
  }
  __syncthreads();

  f32x4 acc[2][4];
#pragma unroll
  for (int mt = 0; mt < 2; mt++)
#pragma unroll
    for (int nt = 0; nt < 4; nt++) acc[mt][nt] = (f32x4)0.f;

  const int c4 = lane * 4;

  for (int tap = 0; tap < 9; tap++) {
    // build samp: 8 iters, each wave one pos per iter
#pragma unroll 2
    for (int it = 0; it < 8; it++) {
      int pos = it * 8 + wv;
      int4  iv = sidx[tap][pos];
      float4 wq = swq[tap][pos];
      uint2 u0 = *(const uint2*)(concat + iv.x + c4);
      uint2 u1 = *(const uint2*)(concat + iv.y + c4);
      uint2 u2 = *(const uint2*)(concat + iv.z + c4);
      uint2 u3 = *(const uint2*)(concat + iv.w + c4);
      float a0, a1, a2, a3;
      a0  = wq.x * __uint_as_float(u0.x << 16);
      a1  = wq.x * __uint_as_float(u0.x & 0xFFFF0000u);
      a2  = wq.x * __uint_as_float(u0.y << 16);
      a3  = wq.x * __uint_as_float(u0.y & 0xFFFF0000u);
      a0 = fmaf(wq.y, __uint_as_float(u1.x << 16), a0);
      a1 = fmaf(wq.y, __uint_as_float(u1.x & 0xFFFF0000u), a1);
      a2 = fmaf(wq.y, __uint_as_float(u1.y << 16), a2);
      a3 = fmaf(wq.y, __uint_as_float(u1.y & 0xFFFF0000u), a3);
      a0 = fmaf(wq.z, __uint_as_float(u2.x << 16), a0);
      a1 = fmaf(wq.z, __uint_as_float(u2.x & 0xFFFF0000u), a1);
      a2 = fmaf(wq.z, __uint_as_float(u2.y << 16), a2);
      a3 = fmaf(wq.z, __uint_as_float(u2.y & 0xFFFF0000u), a3);
      a0 = fmaf(wq.w, __uint_as_float(u3.x << 16), a0);
      a1 = fmaf(wq.w, __uint_as_float(u3.x & 0xFFFF0000u), a1);
      a2 = fmaf(wq.w, __uint_as_float(u3.y << 16), a2);
      a3 = fmaf(wq.w, __uint_as_float(u3.y & 0xFFFF0000u), a3);
      uint2 r;
      r.x = (__float_as_uint(a0) >> 16) | (__float_as_uint(a1) & 0xFFFF0000u);
      r.y = (__float_as_uint(a2) >> 16) | (__float_as_uint(a3) & 0xFFFF0000u);
      u32 byte = (u32)pos * 512u + (u32)c4 * 2u;
      byte ^= (u32)(pos & 7) << 4;
      *(uint2*)((char*)samp + byte) = r;
    }
    __syncthreads();   // samp ready

#pragma unroll 1
    for (int cc = 0; cc < 8; cc++) {
      int c0 = cc * 32;
      bf16x8 bfr[4];
#pragma unroll
      for (int nt = 0; nt < 4; nt++) {
        int pos = nt * 16 + lr;
        u32 byte = (u32)pos * 512u + (u32)(c0 + lk * 8) * 2u;
        byte ^= (u32)(pos & 7) << 4;
        bfr[nt] = *(const bf16x8*)((const char*)samp + byte);
      }
      const u16* wp = wt_b + ((size_t)tap * 256 + wv * 32 + lr) * 256
                      + c0 + lk * 8;
      bf16x8 afr[2];
#pragma unroll
      for (int mt = 0; mt < 2; mt++)
        afr[mt] = *(const bf16x8*)(wp + (size_t)mt * 16 * 256);
#pragma unroll
      for (int mt = 0; mt < 2; mt++)
#pragma unroll
        for (int nt = 0; nt < 4; nt++)
          acc[mt][nt] = __builtin_amdgcn_mfma_f32_16x16x32_bf16(
              afr[mt], bfr[nt], acc[mt][nt], 0, 0, 0);
    }
    __syncthreads();   // GEMM done reading samp before next build
  }

  // epilogue: D[oc][pos] -> d NCHW
#pragma unroll
  for (int mt = 0; mt < 2; mt++) {
    int oc = wv * 32 + mt * 16 + lk * 4;
#pragma unroll
    for (int nt = 0; nt < 4; nt++) {
      int pl = tile * 64 + nt * 16 + lr;
      if (pl < HW) {
        float* dst = d + ((size_t)(b * CH + oc)) * HW + pl;
#pragma unroll
        for (int r = 0; r < 4; r++)
          dst[(size_t)r * HW] = acc[mt][nt][r];
      }
    }
  }

  // fused stats partials (sum over this block's valid positions)
  float sv[2][4], sq[2][4];
#pragma unroll
  for (int mt = 0; mt < 2; mt++)
#pragma unroll
    for (int r = 0; r < 4; r++) { sv[mt][r] = 0.f; sq[mt][r] = 0.f; }
#pragma unroll
  for (int mt = 0; mt < 2; mt++)
#pragma unroll
    for (int nt = 0; nt < 4; nt++) {
      int pl = tile * 64 + nt * 16 + lr;
      if (pl < HW) {
#pragma unroll
        for (int r = 0; r < 4; r++) {
          float v = acc[mt][nt][r];
          sv[mt][r] += v; sq[mt][r] += v * v;
        }
      }
    }
#pragma unroll
  for (int m = 1; m < 16; m <<= 1) {
#pragma unroll
    for (int mt = 0; mt < 2; mt++)
#pragma unroll
      for (int r = 0; r < 4; r++) {
        sv[mt][r] += __shfl_xor(sv[mt][r], m, 64);
        sq[mt][r] += __shfl_xor(sq[mt][r], m, 64);
      }
  }
  if (lr == 0) {
    float* pp = part_d + (size_t)blockIdx.x * 512;
#pragma unroll
    for (int mt = 0; mt < 2; mt++)
#pragma unroll
      for (int r = 0; r < 4; r++) {
        int oc = wv * 32 + mt * 16 + lk * 4 + r;
        pp[oc * 2]     = sv[mt][r];
        pp[oc * 2 + 1] = sq[mt][r];
      }
  }
}

// ---------------------------------------------------------------------------
// K8: final = relu(d*sc2+sh2 + (out1raw*sc1+sh1)), all NCHW, float4.
// ---------------------------------------------------------------------------
__global__ __launch_bounds__(256) void final_nchw(
    const float* __restrict__ d, const float* __restrict__ out1raw,
    const float* __restrict__ st1, const float* __restrict__ g1,
    const float* __restrict__ b1,
    const float* __restrict__ st2, const float* __restrict__ g2,
    const float* __restrict__ b2, float* __restrict__ out)
{
  u32 i4 = blockIdx.x * 256 + threadIdx.x;
  u32 e = i4 * 4;
  int row = (int)(e / HW);
  int c = row & 255;
  float m1 = st1[c], rs1 = st1[CH + c];
  float sc1 = g1[c] * rs1;
  float sh1 = b1[c] - m1 * sc1;
  float m2 = st2[c], rs2 = st2[CH + c];
  float sc2 = g2[c] * rs2;
  float sh2 = b2[c] - m2 * sc2;
  float4 dv = *(const float4*)(d + e);
  float4 xv = *(const float4*)(out1raw + e);
  float4 o;
  o.x = dv.x * sc2 + sh2 + xv.x * sc1 + sh1;
  o.y = dv.y * sc2 + sh2 + xv.y * sc1 + sh1;
  o.z = dv.z * sc2 + sh2 + xv.z * sc1 + sh1;
  o.w = dv.w * sc2 + sh2 + xv.w * sc1 + sh1;
  o.x = o.x > 0.f ? o.x : 0.f;
  o.y = o.y > 0.f ? o.y : 0.f;
  o.z = o.z > 0.f ? o.z : 0.f;
  o.w = o.w > 0.f ? o.w : 0.f;
  *(float4*)(out + e) = o;
}

// ---------------------------------------------------------------------------
extern "C" void kernel_launch(void* const* d_in, const int* in_sizes, int n_in,
                              void* d_out, int out_size, void* d_ws, size_t ws_size,
                              hipStream_t stream)
{
  const float* x       = (const float*)d_in[0];
  const float* conv1_w = (const float*)d_in[1];
  const float* bn1_g   = (const float*)d_in[2];
  const float* bn1_b   = (const float*)d_in[3];
  const float* off_w   = (const float*)d_in[4];
  const float* off_b   = (const float*)d_in[5];
  const float* dcn_w   = (const float*)d_in[6];
  const float* norm_g  = (const float*)d_in[8];
  const float* norm_b  = (const float*)d_in[9];
  float* out = (float*)d_out;

  char* ws = (char*)d_ws;
  size_t o = 0;
  float* out1    = (float*)(ws + o); o += (size_t)PTOT * CH * 4;       // 29.5 MB (RAW conv1 output)
  u16*   concat  = (u16*)  (ws + o); o += (size_t)PTOT * 512 * 2;      // 29.5 MB NHWC bf16 [flipx | xp]
  float* dbuf    = (float*)(ws + o); o += (size_t)PTOT * CH * 4;       // 29.5 MB NCHW
  float* offp3   = (float*)(ws + o); o += (size_t)96 * PTOT * 4;       // 11.1 MB
  u16*   wt_b    = (u16*)  (ws + o); o += (size_t)9 * 256 * 256 * 2;   // 1.18 MB
  u16*   wt_offb = (u16*)  (ws + o); o += (size_t)9 * 32 * 512 * 2;    // 0.29 MB
  u16*   w1b     = (u16*)  (ws + o); o += (size_t)256 * 256 * 2;       // 0.13 MB
  float4* wts4   = (float4*)(ws + o); o += (size_t)9 * PTOT * 16;      // 4.15 MB
  int4*   idx4   = (int4*) (ws + o); o += (size_t)9 * PTOT * 16;       // 4.15 MB
  float* st      = (float*)(ws + o); o += 512 * 4;
  float* st2     = (float*)(ws + o); o += 512 * 4;
  float* part_c1 = (float*)(ws + o); o += (size_t)928 * 128 * 2 * 4;   // 950 KB
  float* part_d  = (float*)(ws + o); o += (size_t)456 * 512 * 4;       // 934 KB

  flip_prep<<<dim3(113, 8, 8), 256, 0, stream>>>(x, concat, conv1_w, off_w,
                                                 dcn_w, w1b, wt_offb, wt_b);
  conv1_mfma<<<dim3(232, 2), 256, 0, stream>>>(concat, w1b, out1, part_c1);
  stats_fin_c1<<<256, 256, 0, stream>>>(part_c1, st);
  norm_transpose<<<dim3(113, 8, 8), 256, 0, stream>>>(out1, st, bn1_g, bn1_b, concat);
  off_mfma<<<dim3(904, 3), 128, 0, stream>>>(concat, wt_offb, offp3);
  off_finalize<<<(9 * PTOT + 255) / 256, 256, 0, stream>>>(offp3, off_b, wts4, idx4);
  deform_mfma<<<456, 512, 0, stream>>>(concat, wts4, idx4, wt_b, dbuf, part_d);
  stats_fin_d<<<256, 256, 0, stream>>>(part_d, st2);
  final_nchw<<<7200, 256, 0, stream>>>(dbuf, out1, st, bn1_g, bn1_b,
                                       st2, norm_g, norm_b, out);
}

// Round 15
// 240.624 us; speedup vs baseline: 1.2855x; 1.1233x over previous
//
#include <hip/hip_runtime.h>
#include <math.h>

// Problem constants
#define BATCH 8
#define CH 256
#define HH 45
#define WW 80
#define HW 3600        // 45*80
#define PTOT 28800     // BATCH*HW

typedef unsigned short u16;
typedef unsigned int   u32;
typedef __attribute__((ext_vector_type(8))) short bf16x8;
typedef __attribute__((ext_vector_type(4))) float f32x4;

struct __align__(8) us4 { u16 x, y, z, w; };

__device__ __forceinline__ u16 bf16_rne(float x) {
  u32 u = __float_as_uint(x);
  u += 0x7FFF + ((u >> 16) & 1);
  return (u16)(u >> 16);
}

// ---------------------------------------------------------------------------
// K1: flip-transpose x -> concat[P][0:256] bf16 (w-flipped NHWC)
//     + merged weight prep (blocks with linid < 2304 also do prep slices).
// ---------------------------------------------------------------------------
__global__ __launch_bounds__(256) void flip_prep(
    const float* __restrict__ x, u16* __restrict__ concat,
    const float* __restrict__ conv1_w, const float* __restrict__ off_w,
    const float* __restrict__ dcn_w,
    u16* __restrict__ w1b, u16* __restrict__ wt_offb, u16* __restrict__ wt_b)
{
  __shared__ float tile[32][36];
  const int b  = blockIdx.z;
  const int c0 = blockIdx.y * 32;
  const int p0 = blockIdx.x * 32;
  int rem = HW - p0; if (rem > 32) rem = 32;
  const int t = threadIdx.x;

  // --- merged prep_wts ---
  {
    int linid = blockIdx.x + 113 * (blockIdx.y + 8 * blockIdx.z);
    if (linid < 2304) {
      int i = linid * 256 + t;
      if (i < 256 * 256) {
        w1b[i] = bf16_rne(conv1_w[i]);
      }
      if (i < 9 * 32 * 512) {
        int tap = i >> 14;
        int r   = i & 16383;
        int oc  = r >> 9;
        int c   = r & 511;
        float v = (oc < 27) ? off_w[((size_t)oc * 512 + c) * 9 + tap] : 0.f;
        wt_offb[i] = bf16_rne(v);
      }
      if (i < 9 * 256 * 256) {
        int c = i & 255;
        int oc = (i >> 8) & 255;
        int tap = i >> 16;
        wt_b[i] = bf16_rne(dcn_w[((size_t)oc * 256 + c) * 9 + tap]);
      }
    }
  }

  // --- flip transpose ---
  {
    int c = t >> 3, p4 = (t & 7) * 4;
    if (p4 < rem) {
      float4 v = *(const float4*)(x + ((size_t)b * CH + c0 + c) * HW + p0 + p4);
      *(float4*)&tile[c][p4] = v;
    }
  }
  __syncthreads();
  {
    int r = t >> 3, cq = (t & 7) * 4;
    if (r < rem) {
      int p = p0 + r;
      int h = p / WW, w = p - h * WW;
      int pf = h * WW + (WW - 1 - w);
      us4 o;
      o.x = bf16_rne(tile[cq + 0][r]);
      o.y = bf16_rne(tile[cq + 1][r]);
      o.z = bf16_rne(tile[cq + 2][r]);
      o.w = bf16_rne(tile[cq + 3][r]);
      *(us4*)(concat + ((size_t)b * HW + pf) * 512 + c0 + cq) = o;
    }
  }
}

// ---------------------------------------------------------------------------
// K2: conv1 via MFMA, XCD b-swizzled + fused stats partials.
// ---------------------------------------------------------------------------
__global__ __launch_bounds__(256) void conv1_mfma(
    const u16* __restrict__ concat, const u16* __restrict__ w1b,
    float* __restrict__ out1, float* __restrict__ part_c1)
{
  const int t = threadIdx.x;
  const int wv = t >> 6, lane = t & 63;
  const int lr = lane & 15, lk = lane >> 4;
  const int id = blockIdx.x;
  const int b  = id & 7;
  const int pt = id >> 3;                    // 0..28
  const int oc0 = blockIdx.y * 128 + (wv & 1) * 64;
  const int p0  = pt * 128 + (wv >> 1) * 64; // within image

  const u16* bptr[4];
#pragma unroll
  for (int nt = 0; nt < 4; nt++) {
    int pl = p0 + nt * 16 + lr;
    int pc = pl < HW ? pl : HW - 1;
    int h = pc / WW, w = pc - h * WW;
    int pf = b * HW + h * WW + (WW - 1 - w);
    bptr[nt] = concat + (size_t)pf * 512 + lk * 8;
  }
  const u16* aptr = w1b + ((size_t)(oc0 + lr)) * 256 + lk * 8;

  f32x4 acc[4][4];
#pragma unroll
  for (int mt = 0; mt < 4; mt++)
#pragma unroll
    for (int nt = 0; nt < 4; nt++) acc[mt][nt] = (f32x4)0.f;

#pragma unroll
  for (int cc = 0; cc < 8; cc++) {
    bf16x8 af[4], bfv[4];
#pragma unroll
    for (int mt = 0; mt < 4; mt++)
      af[mt] = *(const bf16x8*)(aptr + (size_t)mt * 16 * 256 + cc * 32);
#pragma unroll
    for (int nt = 0; nt < 4; nt++)
      bfv[nt] = *(const bf16x8*)(bptr[nt] + cc * 32);
#pragma unroll
    for (int mt = 0; mt < 4; mt++)
#pragma unroll
      for (int nt = 0; nt < 4; nt++)
        acc[mt][nt] = __builtin_amdgcn_mfma_f32_16x16x32_bf16(
            af[mt], bfv[nt], acc[mt][nt], 0, 0, 0);
  }

#pragma unroll
  for (int mt = 0; mt < 4; mt++) {
    int oc = oc0 + mt * 16 + lk * 4;
#pragma unroll
    for (int nt = 0; nt < 4; nt++) {
      int pl = p0 + nt * 16 + lr;
      if (pl < HW) {
        float* dst = out1 + ((size_t)(b * CH + oc)) * HW + pl;
#pragma unroll
        for (int r = 0; r < 4; r++)
          dst[(size_t)r * HW] = acc[mt][nt][r];
      }
    }
  }

  // fused stats partials
  float sv[4][4], sq[4][4];
#pragma unroll
  for (int mt = 0; mt < 4; mt++)
#pragma unroll
    for (int r = 0; r < 4; r++) { sv[mt][r] = 0.f; sq[mt][r] = 0.f; }
#pragma unroll
  for (int mt = 0; mt < 4; mt++)
#pragma unroll
    for (int nt = 0; nt < 4; nt++) {
      int pl = p0 + nt * 16 + lr;
      if (pl < HW) {
#pragma unroll
        for (int r = 0; r < 4; r++) {
          float v = acc[mt][nt][r];
          sv[mt][r] += v; sq[mt][r] += v * v;
        }
      }
    }
#pragma unroll
  for (int m = 1; m < 16; m <<= 1) {
#pragma unroll
    for (int mt = 0; mt < 4; mt++)
#pragma unroll
      for (int r = 0; r < 4; r++) {
        sv[mt][r] += __shfl_xor(sv[mt][r], m, 64);
        sq[mt][r] += __shfl_xor(sq[mt][r], m, 64);
      }
  }
  if (lr == 0) {
    int slot = (wv >> 1) + 2 * blockIdx.x + 464 * blockIdx.y;
    float* pp = part_c1 + (size_t)slot * 128 * 2;
#pragma unroll
    for (int mt = 0; mt < 4; mt++)
#pragma unroll
      for (int r = 0; r < 4; r++) {
        int ocl = (wv & 1) * 64 + mt * 16 + lk * 4 + r;
        pp[ocl * 2]     = sv[mt][r];
        pp[ocl * 2 + 1] = sq[mt][r];
      }
  }
}

// ---------------------------------------------------------------------------
// K3a: finalize conv1 stats — 256 blocks (one per channel), 256 thr each.
// ---------------------------------------------------------------------------
__global__ __launch_bounds__(256) void stats_fin_c1(
    const float* __restrict__ part_c1, float* __restrict__ st)
{
  const int c = blockIdx.x;
  const int y = c >> 7, ocl = c & 127;
  const int t = threadIdx.x;
  const float* base = part_c1 + (size_t)y * 464 * 256 + ocl * 2;
  float s = 0.f, s2 = 0.f;
  for (int i = t; i < 464; i += 256) {
    s  += base[(size_t)i * 256];
    s2 += base[(size_t)i * 256 + 1];
  }
  __shared__ float ls[256], ls2[256];
  ls[t] = s; ls2[t] = s2;
  __syncthreads();
  for (int off = 128; off > 0; off >>= 1) {
    if (t < off) { ls[t] += ls[t + off]; ls2[t] += ls2[t + off]; }
    __syncthreads();
  }
  if (t == 0) {
    float m = ls[0] / (float)PTOT;
    float var = ls2[0] / (float)PTOT - m * m;
    st[c] = m;
    st[CH + c] = rsqrtf(var + 1e-5f);
  }
}

// ---------------------------------------------------------------------------
// K3b: finalize deform stats — 256 blocks (one per channel), 256 thr each.
// ---------------------------------------------------------------------------
__global__ __launch_bounds__(256) void stats_fin_d(
    const float* __restrict__ part_d, float* __restrict__ st)
{
  const int c = blockIdx.x;
  const int t = threadIdx.x;
  float s = 0.f, s2 = 0.f;
  for (int i = t; i < 456; i += 256) {
    s  += part_d[(size_t)i * 512 + c * 2];
    s2 += part_d[(size_t)i * 512 + c * 2 + 1];
  }
  __shared__ float ls[256], ls2[256];
  ls[t] = s; ls2[t] = s2;
  __syncthreads();
  for (int off = 128; off > 0; off >>= 1) {
    if (t < off) { ls[t] += ls[t + off]; ls2[t] += ls2[t + off]; }
    __syncthreads();
  }
  if (t == 0) {
    float m = ls[0] / (float)PTOT;
    float var = ls2[0] / (float)PTOT - m * m;
    st[c] = m;
    st[CH + c] = rsqrtf(var + 1e-5f);
  }
}

// ---------------------------------------------------------------------------
// K4: read RAW out1, write normalized bf16 into concat[P][256:512].
// ---------------------------------------------------------------------------
__global__ __launch_bounds__(256) void norm_transpose(
    const float* __restrict__ out1, const float* __restrict__ st,
    const float* __restrict__ g, const float* __restrict__ bb,
    u16* __restrict__ concat)
{
  __shared__ float tile[32][36];
  const int b  = blockIdx.z;
  const int c0 = blockIdx.y * 32;
  const int p0 = blockIdx.x * 32;
  int rem = HW - p0; if (rem > 32) rem = 32;
  const int t = threadIdx.x;

  {
    int c  = t >> 3;
    int p4 = (t & 7) * 4;
    int cg = c0 + c;
    float m  = st[cg], rs = st[CH + cg];
    float sc = g[cg] * rs;
    float sh = bb[cg] - m * sc;
    if (p4 < rem) {
      size_t base = ((size_t)b * CH + cg) * HW + p0;
      float4 v = *(const float4*)(out1 + base + p4);
      v.x = v.x * sc + sh; v.y = v.y * sc + sh;
      v.z = v.z * sc + sh; v.w = v.w * sc + sh;
      *(float4*)&tile[c][p4] = v;
    }
  }
  __syncthreads();
  {
    int r  = t >> 3;
    int cq = (t & 7) * 4;
    if (r < rem) {
      us4 o;
      o.x = bf16_rne(tile[cq + 0][r]);
      o.y = bf16_rne(tile[cq + 1][r]);
      o.z = bf16_rne(tile[cq + 2][r]);
      o.w = bf16_rne(tile[cq + 3][r]);
      *(us4*)(concat + ((size_t)b * HW + p0 + r) * 512 + 256 + c0 + cq) = o;
    }
  }
}

// ---------------------------------------------------------------------------
// K5: offset conv via MFMA, tap-split 3-ways; XCD b-swizzled.
// Wave = 32 pos x 32 oc (N doubled vs R14): per cc {4 loads : 4 MFMA},
// A-frags reused across 2 position-frags. Grid (456, 3), 128 thr.
// FP accumulation order per output element unchanged (bitwise identical).
// ---------------------------------------------------------------------------
__global__ __launch_bounds__(128) void off_mfma(
    const u16* __restrict__ concat, const u16* __restrict__ wt_offb,
    float* __restrict__ offp3)
{
  const int t = threadIdx.x;
  const int g = blockIdx.y;
  const int wv = t >> 6, lane = t & 63;
  const int lr = lane & 15, lk = lane >> 4;
  const int id = blockIdx.x;
  const int b    = id & 7;
  const int tile = id >> 3;            // 0..56
  const int pbase = tile * 64 + wv * 32;

  int   pl[2];
  int   h[2], w[2];
  bool  pv[2];
#pragma unroll
  for (int nt = 0; nt < 2; nt++) {
    int p = pbase + nt * 16 + lr;
    pv[nt] = p < HW;
    if (!pv[nt]) p = HW - 1;
    pl[nt] = p;
    h[nt] = p / WW;
    w[nt] = p - h[nt] * WW;
  }

  f32x4 acc[2][2];
#pragma unroll
  for (int mt = 0; mt < 2; mt++)
#pragma unroll
    for (int nt = 0; nt < 2; nt++) acc[mt][nt] = (f32x4)0.f;

#pragma unroll 1
  for (int tl = 0; tl < 3; tl++) {
    int tap = g * 3 + tl;
    int dy = tap / 3 - 1, dx = tap % 3 - 1;
    const u16* bp[2];
    bool valid[2];
#pragma unroll
    for (int nt = 0; nt < 2; nt++) {
      valid[nt] = ((unsigned)(h[nt] + dy) < HH) && ((unsigned)(w[nt] + dx) < WW);
      int Ps = b * HW + (valid[nt] ? (pl[nt] + dy * WW + dx) : pl[nt]);
      bp[nt] = concat + (size_t)Ps * 512 + lk * 8;
    }
    const u16* ap = wt_offb + ((size_t)tap * 32 + lr) * 512 + lk * 8;
#pragma unroll
    for (int cc = 0; cc < 16; cc++) {
      bf16x8 bfv[2];
#pragma unroll
      for (int nt = 0; nt < 2; nt++) {
        bfv[nt] = *(const bf16x8*)(bp[nt] + cc * 32);
        if (!valid[nt]) bfv[nt] = (bf16x8)(short)0;
      }
      bf16x8 af0 = *(const bf16x8*)(ap + cc * 32);
      bf16x8 af1 = *(const bf16x8*)(ap + 16 * 512 + cc * 32);
#pragma unroll
      for (int nt = 0; nt < 2; nt++) {
        acc[0][nt] = __builtin_amdgcn_mfma_f32_16x16x32_bf16(af0, bfv[nt], acc[0][nt], 0, 0, 0);
        acc[1][nt] = __builtin_amdgcn_mfma_f32_16x16x32_bf16(af1, bfv[nt], acc[1][nt], 0, 0, 0);
      }
    }
  }

#pragma unroll
  for (int nt = 0; nt < 2; nt++) {
    if (pv[nt]) {
      int P = b * HW + pl[nt];
#pragma unroll
      for (int mt = 0; mt < 2; mt++) {
        int oc = mt * 16 + lk * 4;
#pragma unroll
        for (int r = 0; r < 4; r++)
          offp3[((size_t)g * 32 + oc + r) * PTOT + P] = acc[mt][nt][r];
      }
    }
  }
}

// ---------------------------------------------------------------------------
// K6: finalize offsets -> bilinear params per (tap, P). Sums 3 tap-group partials.
// ---------------------------------------------------------------------------
__global__ __launch_bounds__(256) void off_finalize(
    const float* __restrict__ offp3, const float* __restrict__ off_b,
    float4* __restrict__ wts4, int4* __restrict__ idx4)
{
  int i = blockIdx.x * 256 + threadIdx.x;
  if (i >= 9 * PTOT) return;
  int k = i / PTOT;
  int P = i - k * PTOT;
  int b = P / HW;
  int p = P - b * HW;
  int h = p / WW;
  int w = p - h * WW;

  float dy = off_b[2 * k], dx = off_b[2 * k + 1], ml = off_b[18 + k];
#pragma unroll
  for (int g = 0; g < 3; g++) {
    const float* base = offp3 + (size_t)g * 32 * PTOT + P;
    dy += base[(size_t)(2 * k    ) * PTOT];
    dx += base[(size_t)(2 * k + 1) * PTOT];
    ml += base[(size_t)(18 + k   ) * PTOT];
  }

  float m = 1.f / (1.f + expf(-ml));
  float ph = dy + (float)(k / 3 - 1) + (float)h;
  float pw = dx + (float)(k % 3 - 1) + (float)w;
  float h0f = floorf(ph), w0f = floorf(pw);
  float lh = ph - h0f, lw = pw - w0f;
  int h0 = (int)h0f, w0 = (int)w0f;
  int h1 = h0 + 1, w1 = w0 + 1;
  float vh0 = (h0 >= 0 && h0 < HH) ? 1.f : 0.f;
  float vh1 = (h1 >= 0 && h1 < HH) ? 1.f : 0.f;
  float vw0 = (w0 >= 0 && w0 < WW) ? 1.f : 0.f;
  float vw1 = (w1 >= 0 && w1 < WW) ? 1.f : 0.f;
  float4 wv;
  wv.x = (1.f - lh) * (1.f - lw) * m * vh0 * vw0;
  wv.y = (1.f - lh) * lw         * m * vh0 * vw1;
  wv.z = lh * (1.f - lw)         * m * vh1 * vw0;
  wv.w = lh * lw                 * m * vh1 * vw1;
  int hc0 = min(max(h0, 0), HH - 1), hc1 = min(max(h1, 0), HH - 1);
  int wc0 = min(max(w0, 0), WW - 1), wc1 = min(max(w1, 0), WW - 1);
  int base = b * HW;
  int4 iv;
  iv.x = (base + hc0 * WW + wc0) * 512 + 256;
  iv.y = (base + hc0 * WW + wc1) * 512 + 256;
  iv.z = (base + hc1 * WW + wc0) * 512 + 256;
  iv.w = (base + hc1 * WW + wc1) * 512 + 256;
  wts4[i] = wv;
  idx4[i] = iv;
}

// ---------------------------------------------------------------------------
// K7: deformable conv via MFMA bf16 — frozen R14 structure (116 us) +
// all-tap param hoist + fused stats partials.
// ---------------------------------------------------------------------------
__global__ __launch_bounds__(512) void deform_mfma(
    const u16* __restrict__ concat,
    const float4* __restrict__ wts4, const int4* __restrict__ idx4,
    const u16* __restrict__ wt_b,
    float* __restrict__ d, float* __restrict__ part_d)
{
  __shared__ u16    samp[64 * 256];   // 32KB, swizzled: byte ^= (pos&7)<<4
  __shared__ int4   sidx[9][64];      // 9KB
  __shared__ float4 swq[9][64];       // 9KB

  const int t    = threadIdx.x;
  const int wv   = t >> 6;           // 0..7
  const int lane = t & 63;
  const int lr = lane & 15, lk = lane >> 4;
  const int id   = blockIdx.x;
  const int b    = id & 7;
  const int tile = id >> 3;          // 0..56
  const int P0   = b * HW + tile * 64;
  int lim  = HW - tile * 64;
  if (lim > 64) lim = 64;

  for (int item = t; item < 9 * 64; item += 512) {
    int tap = item >> 6, pos = item & 63;
    int off = (pos < lim) ? pos : (lim - 1);
    sidx[tap][pos] = idx4[(size_t)tap * PTOT + P0 + off];
    swq[tap][pos]  = wts4[(size_t)tap * PTOT + P0 + off];
  }
  __syncthreads();

  f32x4 acc[2][4];
#pragma unroll
  for (int mt = 0; mt < 2; mt++)
#pragma unroll
    for (int nt = 0; nt < 4; nt++) acc[mt][nt] = (f32x4)0.f;

  const int c4 = lane * 4;

  for (int tap = 0; tap < 9; tap++) {
#pragma unroll 2
    for (int it = 0; it < 8; it++) {
      int pos = it * 8 + wv;
      int4  iv = sidx[tap][pos];
      float4 wq = swq[tap][pos];
      uint2 u0 = *(const uint2*)(concat + iv.x + c4);
      uint2 u1 = *(const uint2*)(concat + iv.y + c4);
      uint2 u2 = *(const uint2*)(concat + iv.z + c4);
      uint2 u3 = *(const uint2*)(concat + iv.w + c4);
      float a0, a1, a2, a3;
      a0  = wq.x * __uint_as_float(u0.x << 16);
      a1  = wq.x * __uint_as_float(u0.x & 0xFFFF0000u);
      a2  = wq.x * __uint_as_float(u0.y << 16);
      a3  = wq.x * __uint_as_float(u0.y & 0xFFFF0000u);
      a0 = fmaf(wq.y, __uint_as_float(u1.x << 16), a0);
      a1 = fmaf(wq.y, __uint_as_float(u1.x & 0xFFFF0000u), a1);
      a2 = fmaf(wq.y, __uint_as_float(u1.y << 16), a2);
      a3 = fmaf(wq.y, __uint_as_float(u1.y & 0xFFFF0000u), a3);
      a0 = fmaf(wq.z, __uint_as_float(u2.x << 16), a0);
      a1 = fmaf(wq.z, __uint_as_float(u2.x & 0xFFFF0000u), a1);
      a2 = fmaf(wq.z, __uint_as_float(u2.y << 16), a2);
      a3 = fmaf(wq.z, __uint_as_float(u2.y & 0xFFFF0000u), a3);
      a0 = fmaf(wq.w, __uint_as_float(u3.x << 16), a0);
      a1 = fmaf(wq.w, __uint_as_float(u3.x & 0xFFFF0000u), a1);
      a2 = fmaf(wq.w, __uint_as_float(u3.y << 16), a2);
      a3 = fmaf(wq.w, __uint_as_float(u3.y & 0xFFFF0000u), a3);
      uint2 r;
      r.x = (__float_as_uint(a0) >> 16) | (__float_as_uint(a1) & 0xFFFF0000u);
      r.y = (__float_as_uint(a2) >> 16) | (__float_as_uint(a3) & 0xFFFF0000u);
      u32 byte = (u32)pos * 512u + (u32)c4 * 2u;
      byte ^= (u32)(pos & 7) << 4;
      *(uint2*)((char*)samp + byte) = r;
    }
    __syncthreads();   // samp ready

#pragma unroll 1
    for (int cc = 0; cc < 8; cc++) {
      int c0 = cc * 32;
      bf16x8 bfr[4];
#pragma unroll
      for (int nt = 0; nt < 4; nt++) {
        int pos = nt * 16 + lr;
        u32 byte = (u32)pos * 512u + (u32)(c0 + lk * 8) * 2u;
        byte ^= (u32)(pos & 7) << 4;
        bfr[nt] = *(const bf16x8*)((const char*)samp + byte);
      }
      const u16* wp = wt_b + ((size_t)tap * 256 + wv * 32 + lr) * 256
                      + c0 + lk * 8;
      bf16x8 afr[2];
#pragma unroll
      for (int mt = 0; mt < 2; mt++)
        afr[mt] = *(const bf16x8*)(wp + (size_t)mt * 16 * 256);
#pragma unroll
      for (int mt = 0; mt < 2; mt++)
#pragma unroll
        for (int nt = 0; nt < 4; nt++)
          acc[mt][nt] = __builtin_amdgcn_mfma_f32_16x16x32_bf16(
              afr[mt], bfr[nt], acc[mt][nt], 0, 0, 0);
    }
    __syncthreads();   // GEMM done reading samp before next build
  }

  // epilogue: D[oc][pos] -> d NCHW
#pragma unroll
  for (int mt = 0; mt < 2; mt++) {
    int oc = wv * 32 + mt * 16 + lk * 4;
#pragma unroll
    for (int nt = 0; nt < 4; nt++) {
      int pl = tile * 64 + nt * 16 + lr;
      if (pl < HW) {
        float* dst = d + ((size_t)(b * CH + oc)) * HW + pl;
#pragma unroll
        for (int r = 0; r < 4; r++)
          dst[(size_t)r * HW] = acc[mt][nt][r];
      }
    }
  }

  // fused stats partials
  float sv[2][4], sq[2][4];
#pragma unroll
  for (int mt = 0; mt < 2; mt++)
#pragma unroll
    for (int r = 0; r < 4; r++) { sv[mt][r] = 0.f; sq[mt][r] = 0.f; }
#pragma unroll
  for (int mt = 0; mt < 2; mt++)
#pragma unroll
    for (int nt = 0; nt < 4; nt++) {
      int pl = tile * 64 + nt * 16 + lr;
      if (pl < HW) {
#pragma unroll
        for (int r = 0; r < 4; r++) {
          float v = acc[mt][nt][r];
          sv[mt][r] += v; sq[mt][r] += v * v;
        }
      }
    }
#pragma unroll
  for (int m = 1; m < 16; m <<= 1) {
#pragma unroll
    for (int mt = 0; mt < 2; mt++)
#pragma unroll
      for (int r = 0; r < 4; r++) {
        sv[mt][r] += __shfl_xor(sv[mt][r], m, 64);
        sq[mt][r] += __shfl_xor(sq[mt][r], m, 64);
      }
  }
  if (lr == 0) {
    float* pp = part_d + (size_t)blockIdx.x * 512;
#pragma unroll
    for (int mt = 0; mt < 2; mt++)
#pragma unroll
      for (int r = 0; r < 4; r++) {
        int oc = wv * 32 + mt * 16 + lk * 4 + r;
        pp[oc * 2]     = sv[mt][r];
        pp[oc * 2 + 1] = sq[mt][r];
      }
  }
}

// ---------------------------------------------------------------------------
// K8: final = relu(d*sc2+sh2 + (out1raw*sc1+sh1)), all NCHW, float4.
// ---------------------------------------------------------------------------
__global__ __launch_bounds__(256) void final_nchw(
    const float* __restrict__ d, const float* __restrict__ out1raw,
    const float* __restrict__ st1, const float* __restrict__ g1,
    const float* __restrict__ b1,
    const float* __restrict__ st2, const float* __restrict__ g2,
    const float* __restrict__ b2, float* __restrict__ out)
{
  u32 i4 = blockIdx.x * 256 + threadIdx.x;
  u32 e = i4 * 4;
  int row = (int)(e / HW);
  int c = row & 255;
  float m1 = st1[c], rs1 = st1[CH + c];
  float sc1 = g1[c] * rs1;
  float sh1 = b1[c] - m1 * sc1;
  float m2 = st2[c], rs2 = st2[CH + c];
  float sc2 = g2[c] * rs2;
  float sh2 = b2[c] - m2 * sc2;
  float4 dv = *(const float4*)(d + e);
  float4 xv = *(const float4*)(out1raw + e);
  float4 o;
  o.x = dv.x * sc2 + sh2 + xv.x * sc1 + sh1;
  o.y = dv.y * sc2 + sh2 + xv.y * sc1 + sh1;
  o.z = dv.z * sc2 + sh2 + xv.z * sc1 + sh1;
  o.w = dv.w * sc2 + sh2 + xv.w * sc1 + sh1;
  o.x = o.x > 0.f ? o.x : 0.f;
  o.y = o.y > 0.f ? o.y : 0.f;
  o.z = o.z > 0.f ? o.z : 0.f;
  o.w = o.w > 0.f ? o.w : 0.f;
  *(float4*)(out + e) = o;
}

// ---------------------------------------------------------------------------
extern "C" void kernel_launch(void* const* d_in, const int* in_sizes, int n_in,
                              void* d_out, int out_size, void* d_ws, size_t ws_size,
                              hipStream_t stream)
{
  const float* x       = (const float*)d_in[0];
  const float* conv1_w = (const float*)d_in[1];
  const float* bn1_g   = (const float*)d_in[2];
  const float* bn1_b   = (const float*)d_in[3];
  const float* off_w   = (const float*)d_in[4];
  const float* off_b   = (const float*)d_in[5];
  const float* dcn_w   = (const float*)d_in[6];
  const float* norm_g  = (const float*)d_in[8];
  const float* norm_b  = (const float*)d_in[9];
  float* out = (float*)d_out;

  char* ws = (char*)d_ws;
  size_t o = 0;
  float* out1    = (float*)(ws + o); o += (size_t)PTOT * CH * 4;       // 29.5 MB (RAW conv1 output)
  u16*   concat  = (u16*)  (ws + o); o += (size_t)PTOT * 512 * 2;      // 29.5 MB NHWC bf16 [flipx | xp]
  float* dbuf    = (float*)(ws + o); o += (size_t)PTOT * CH * 4;       // 29.5 MB NCHW
  float* offp3   = (float*)(ws + o); o += (size_t)96 * PTOT * 4;       // 11.1 MB
  u16*   wt_b    = (u16*)  (ws + o); o += (size_t)9 * 256 * 256 * 2;   // 1.18 MB
  u16*   wt_offb = (u16*)  (ws + o); o += (size_t)9 * 32 * 512 * 2;    // 0.29 MB
  u16*   w1b     = (u16*)  (ws + o); o += (size_t)256 * 256 * 2;       // 0.13 MB
  float4* wts4   = (float4*)(ws + o); o += (size_t)9 * PTOT * 16;      // 4.15 MB
  int4*   idx4   = (int4*) (ws + o); o += (size_t)9 * PTOT * 16;       // 4.15 MB
  float* st      = (float*)(ws + o); o += 512 * 4;
  float* st2     = (float*)(ws + o); o += 512 * 4;
  float* part_c1 = (float*)(ws + o); o += (size_t)928 * 128 * 2 * 4;   // 950 KB
  float* part_d  = (float*)(ws + o); o += (size_t)456 * 512 * 4;       // 934 KB

  flip_prep<<<dim3(113, 8, 8), 256, 0, stream>>>(x, concat, conv1_w, off_w,
                                                 dcn_w, w1b, wt_offb, wt_b);
  conv1_mfma<<<dim3(232, 2), 256, 0, stream>>>(concat, w1b, out1, part_c1);
  stats_fin_c1<<<256, 256, 0, stream>>>(part_c1, st);
  norm_transpose<<<dim3(113, 8, 8), 256, 0, stream>>>(out1, st, bn1_g, bn1_b, concat);
  off_mfma<<<dim3(456, 3), 128, 0, stream>>>(concat, wt_offb, offp3);
  off_finalize<<<(9 * PTOT + 255) / 256, 256, 0, stream>>>(offp3, off_b, wts4, idx4);
  deform_mfma<<<456, 512, 0, stream>>>(concat, wts4, idx4, wt_b, dbuf, part_d);
  stats_fin_d<<<256, 256, 0, stream>>>(part_d, st2);
  final_nchw<<<7200, 256, 0, stream>>>(dbuf, out1, st, bn1_g, bn1_b,
                                       st2, norm_g, norm_b, out);
}

// Round 16
// 234.967 us; speedup vs baseline: 1.3164x; 1.0241x over previous
//
#include <hip/hip_runtime.h>
#include <math.h>

// Problem constants
#define BATCH 8
#define CH 256
#define HH 45
#define WW 80
#define HW 3600        // 45*80
#define PTOT 28800     // BATCH*HW

typedef unsigned short u16;
typedef unsigned int   u32;
typedef __attribute__((ext_vector_type(8))) short bf16x8;
typedef __attribute__((ext_vector_type(4))) float f32x4;

struct __align__(8) us4 { u16 x, y, z, w; };

__device__ __forceinline__ u16 bf16_rne(float x) {
  u32 u = __float_as_uint(x);
  u += 0x7FFF + ((u >> 16) & 1);
  return (u16)(u >> 16);
}
__device__ __forceinline__ float bf16_f(u16 v) {
  return __uint_as_float((u32)v << 16);
}

// ---------------------------------------------------------------------------
// K1: flip-transpose x -> concat[P][0:256] bf16 (w-flipped NHWC)
//     + merged weight prep (blocks with linid < 2304 also do prep slices).
// ---------------------------------------------------------------------------
__global__ __launch_bounds__(256) void flip_prep(
    const float* __restrict__ x, u16* __restrict__ concat,
    const float* __restrict__ conv1_w, const float* __restrict__ off_w,
    const float* __restrict__ dcn_w,
    u16* __restrict__ w1b, u16* __restrict__ wt_offb, u16* __restrict__ wt_b)
{
  __shared__ float tile[32][36];
  const int b  = blockIdx.z;
  const int c0 = blockIdx.y * 32;
  const int p0 = blockIdx.x * 32;
  int rem = HW - p0; if (rem > 32) rem = 32;
  const int t = threadIdx.x;

  // --- merged prep_wts ---
  {
    int linid = blockIdx.x + 113 * (blockIdx.y + 8 * blockIdx.z);
    if (linid < 2304) {
      int i = linid * 256 + t;
      if (i < 256 * 256) {
        w1b[i] = bf16_rne(conv1_w[i]);
      }
      if (i < 9 * 32 * 512) {
        int tap = i >> 14;
        int r   = i & 16383;
        int oc  = r >> 9;
        int c   = r & 511;
        float v = (oc < 27) ? off_w[((size_t)oc * 512 + c) * 9 + tap] : 0.f;
        wt_offb[i] = bf16_rne(v);
      }
      if (i < 9 * 256 * 256) {
        int c = i & 255;
        int oc = (i >> 8) & 255;
        int tap = i >> 16;
        wt_b[i] = bf16_rne(dcn_w[((size_t)oc * 256 + c) * 9 + tap]);
      }
    }
  }

  // --- flip transpose ---
  {
    int c = t >> 3, p4 = (t & 7) * 4;
    if (p4 < rem) {
      float4 v = *(const float4*)(x + ((size_t)b * CH + c0 + c) * HW + p0 + p4);
      *(float4*)&tile[c][p4] = v;
    }
  }
  __syncthreads();
  {
    int r = t >> 3, cq = (t & 7) * 4;
    if (r < rem) {
      int p = p0 + r;
      int h = p / WW, w = p - h * WW;
      int pf = h * WW + (WW - 1 - w);
      us4 o;
      o.x = bf16_rne(tile[cq + 0][r]);
      o.y = bf16_rne(tile[cq + 1][r]);
      o.z = bf16_rne(tile[cq + 2][r]);
      o.w = bf16_rne(tile[cq + 3][r]);
      *(us4*)(concat + ((size_t)b * HW + pf) * 512 + c0 + cq) = o;
    }
  }
}

// ---------------------------------------------------------------------------
// K2: conv1 via MFMA, XCD b-swizzled + fused stats partials.
// out1b stored bf16 (raw, pre-norm); stats partials computed from f32 acc.
// ---------------------------------------------------------------------------
__global__ __launch_bounds__(256) void conv1_mfma(
    const u16* __restrict__ concat, const u16* __restrict__ w1b,
    u16* __restrict__ out1b, float* __restrict__ part_c1)
{
  const int t = threadIdx.x;
  const int wv = t >> 6, lane = t & 63;
  const int lr = lane & 15, lk = lane >> 4;
  const int id = blockIdx.x;
  const int b  = id & 7;
  const int pt = id >> 3;                    // 0..28
  const int oc0 = blockIdx.y * 128 + (wv & 1) * 64;
  const int p0  = pt * 128 + (wv >> 1) * 64; // within image

  const u16* bptr[4];
#pragma unroll
  for (int nt = 0; nt < 4; nt++) {
    int pl = p0 + nt * 16 + lr;
    int pc = pl < HW ? pl : HW - 1;
    int h = pc / WW, w = pc - h * WW;
    int pf = b * HW + h * WW + (WW - 1 - w);
    bptr[nt] = concat + (size_t)pf * 512 + lk * 8;
  }
  const u16* aptr = w1b + ((size_t)(oc0 + lr)) * 256 + lk * 8;

  f32x4 acc[4][4];
#pragma unroll
  for (int mt = 0; mt < 4; mt++)
#pragma unroll
    for (int nt = 0; nt < 4; nt++) acc[mt][nt] = (f32x4)0.f;

#pragma unroll
  for (int cc = 0; cc < 8; cc++) {
    bf16x8 af[4], bfv[4];
#pragma unroll
    for (int mt = 0; mt < 4; mt++)
      af[mt] = *(const bf16x8*)(aptr + (size_t)mt * 16 * 256 + cc * 32);
#pragma unroll
    for (int nt = 0; nt < 4; nt++)
      bfv[nt] = *(const bf16x8*)(bptr[nt] + cc * 32);
#pragma unroll
    for (int mt = 0; mt < 4; mt++)
#pragma unroll
      for (int nt = 0; nt < 4; nt++)
        acc[mt][nt] = __builtin_amdgcn_mfma_f32_16x16x32_bf16(
            af[mt], bfv[nt], acc[mt][nt], 0, 0, 0);
  }

#pragma unroll
  for (int mt = 0; mt < 4; mt++) {
    int oc = oc0 + mt * 16 + lk * 4;
#pragma unroll
    for (int nt = 0; nt < 4; nt++) {
      int pl = p0 + nt * 16 + lr;
      if (pl < HW) {
        u16* dst = out1b + ((size_t)(b * CH + oc)) * HW + pl;
#pragma unroll
        for (int r = 0; r < 4; r++)
          dst[(size_t)r * HW] = bf16_rne(acc[mt][nt][r]);
      }
    }
  }

  // fused stats partials (f32, from registers)
  float sv[4][4], sq[4][4];
#pragma unroll
  for (int mt = 0; mt < 4; mt++)
#pragma unroll
    for (int r = 0; r < 4; r++) { sv[mt][r] = 0.f; sq[mt][r] = 0.f; }
#pragma unroll
  for (int mt = 0; mt < 4; mt++)
#pragma unroll
    for (int nt = 0; nt < 4; nt++) {
      int pl = p0 + nt * 16 + lr;
      if (pl < HW) {
#pragma unroll
        for (int r = 0; r < 4; r++) {
          float v = acc[mt][nt][r];
          sv[mt][r] += v; sq[mt][r] += v * v;
        }
      }
    }
#pragma unroll
  for (int m = 1; m < 16; m <<= 1) {
#pragma unroll
    for (int mt = 0; mt < 4; mt++)
#pragma unroll
      for (int r = 0; r < 4; r++) {
        sv[mt][r] += __shfl_xor(sv[mt][r], m, 64);
        sq[mt][r] += __shfl_xor(sq[mt][r], m, 64);
      }
  }
  if (lr == 0) {
    int slot = (wv >> 1) + 2 * blockIdx.x + 464 * blockIdx.y;
    float* pp = part_c1 + (size_t)slot * 128 * 2;
#pragma unroll
    for (int mt = 0; mt < 4; mt++)
#pragma unroll
      for (int r = 0; r < 4; r++) {
        int ocl = (wv & 1) * 64 + mt * 16 + lk * 4 + r;
        pp[ocl * 2]     = sv[mt][r];
        pp[ocl * 2 + 1] = sq[mt][r];
      }
  }
}

// ---------------------------------------------------------------------------
// K3a: finalize conv1 stats — 256 blocks (one per channel), 256 thr each.
// ---------------------------------------------------------------------------
__global__ __launch_bounds__(256) void stats_fin_c1(
    const float* __restrict__ part_c1, float* __restrict__ st)
{
  const int c = blockIdx.x;
  const int y = c >> 7, ocl = c & 127;
  const int t = threadIdx.x;
  const float* base = part_c1 + (size_t)y * 464 * 256 + ocl * 2;
  float s = 0.f, s2 = 0.f;
  for (int i = t; i < 464; i += 256) {
    s  += base[(size_t)i * 256];
    s2 += base[(size_t)i * 256 + 1];
  }
  __shared__ float ls[256], ls2[256];
  ls[t] = s; ls2[t] = s2;
  __syncthreads();
  for (int off = 128; off > 0; off >>= 1) {
    if (t < off) { ls[t] += ls[t + off]; ls2[t] += ls2[t + off]; }
    __syncthreads();
  }
  if (t == 0) {
    float m = ls[0] / (float)PTOT;
    float var = ls2[0] / (float)PTOT - m * m;
    st[c] = m;
    st[CH + c] = rsqrtf(var + 1e-5f);
  }
}

// ---------------------------------------------------------------------------
// K3b: finalize deform stats — 256 blocks (one per channel), 256 thr each.
// ---------------------------------------------------------------------------
__global__ __launch_bounds__(256) void stats_fin_d(
    const float* __restrict__ part_d, float* __restrict__ st)
{
  const int c = blockIdx.x;
  const int t = threadIdx.x;
  float s = 0.f, s2 = 0.f;
  for (int i = t; i < 456; i += 256) {
    s  += part_d[(size_t)i * 512 + c * 2];
    s2 += part_d[(size_t)i * 512 + c * 2 + 1];
  }
  __shared__ float ls[256], ls2[256];
  ls[t] = s; ls2[t] = s2;
  __syncthreads();
  for (int off = 128; off > 0; off >>= 1) {
    if (t < off) { ls[t] += ls[t + off]; ls2[t] += ls2[t + off]; }
    __syncthreads();
  }
  if (t == 0) {
    float m = ls[0] / (float)PTOT;
    float var = ls2[0] / (float)PTOT - m * m;
    st[c] = m;
    st[CH + c] = rsqrtf(var + 1e-5f);
  }
}

// ---------------------------------------------------------------------------
// K4: read bf16 raw out1b, write normalized bf16 into concat[P][256:512].
// ---------------------------------------------------------------------------
__global__ __launch_bounds__(256) void norm_transpose(
    const u16* __restrict__ out1b, const float* __restrict__ st,
    const float* __restrict__ g, const float* __restrict__ bb,
    u16* __restrict__ concat)
{
  __shared__ float tile[32][36];
  const int b  = blockIdx.z;
  const int c0 = blockIdx.y * 32;
  const int p0 = blockIdx.x * 32;
  int rem = HW - p0; if (rem > 32) rem = 32;
  const int t = threadIdx.x;

  {
    int c  = t >> 3;
    int p4 = (t & 7) * 4;
    int cg = c0 + c;
    float m  = st[cg], rs = st[CH + cg];
    float sc = g[cg] * rs;
    float sh = bb[cg] - m * sc;
    if (p4 < rem) {
      size_t base = ((size_t)b * CH + cg) * HW + p0;
      us4 v4 = *(const us4*)(out1b + base + p4);
      tile[c][p4 + 0] = bf16_f(v4.x) * sc + sh;
      tile[c][p4 + 1] = bf16_f(v4.y) * sc + sh;
      tile[c][p4 + 2] = bf16_f(v4.z) * sc + sh;
      tile[c][p4 + 3] = bf16_f(v4.w) * sc + sh;
    }
  }
  __syncthreads();
  {
    int r  = t >> 3;
    int cq = (t & 7) * 4;
    if (r < rem) {
      us4 o;
      o.x = bf16_rne(tile[cq + 0][r]);
      o.y = bf16_rne(tile[cq + 1][r]);
      o.z = bf16_rne(tile[cq + 2][r]);
      o.w = bf16_rne(tile[cq + 3][r]);
      *(us4*)(concat + ((size_t)b * HW + p0 + r) * 512 + 256 + c0 + cq) = o;
    }
  }
}

// ---------------------------------------------------------------------------
// K5: offset conv via MFMA, tap-split 3-ways; XCD b-swizzled.
// Wave = 32 pos x 32 oc; grid (456, 3), 128 thr.
// ---------------------------------------------------------------------------
__global__ __launch_bounds__(128) void off_mfma(
    const u16* __restrict__ concat, const u16* __restrict__ wt_offb,
    float* __restrict__ offp3)
{
  const int t = threadIdx.x;
  const int g = blockIdx.y;
  const int wv = t >> 6, lane = t & 63;
  const int lr = lane & 15, lk = lane >> 4;
  const int id = blockIdx.x;
  const int b    = id & 7;
  const int tile = id >> 3;            // 0..56
  const int pbase = tile * 64 + wv * 32;

  int   pl[2];
  int   h[2], w[2];
  bool  pv[2];
#pragma unroll
  for (int nt = 0; nt < 2; nt++) {
    int p = pbase + nt * 16 + lr;
    pv[nt] = p < HW;
    if (!pv[nt]) p = HW - 1;
    pl[nt] = p;
    h[nt] = p / WW;
    w[nt] = p - h[nt] * WW;
  }

  f32x4 acc[2][2];
#pragma unroll
  for (int mt = 0; mt < 2; mt++)
#pragma unroll
    for (int nt = 0; nt < 2; nt++) acc[mt][nt] = (f32x4)0.f;

#pragma unroll 1
  for (int tl = 0; tl < 3; tl++) {
    int tap = g * 3 + tl;
    int dy = tap / 3 - 1, dx = tap % 3 - 1;
    const u16* bp[2];
    bool valid[2];
#pragma unroll
    for (int nt = 0; nt < 2; nt++) {
      valid[nt] = ((unsigned)(h[nt] + dy) < HH) && ((unsigned)(w[nt] + dx) < WW);
      int Ps = b * HW + (valid[nt] ? (pl[nt] + dy * WW + dx) : pl[nt]);
      bp[nt] = concat + (size_t)Ps * 512 + lk * 8;
    }
    const u16* ap = wt_offb + ((size_t)tap * 32 + lr) * 512 + lk * 8;
#pragma unroll
    for (int cc = 0; cc < 16; cc++) {
      bf16x8 bfv[2];
#pragma unroll
      for (int nt = 0; nt < 2; nt++) {
        bfv[nt] = *(const bf16x8*)(bp[nt] + cc * 32);
        if (!valid[nt]) bfv[nt] = (bf16x8)(short)0;
      }
      bf16x8 af0 = *(const bf16x8*)(ap + cc * 32);
      bf16x8 af1 = *(const bf16x8*)(ap + 16 * 512 + cc * 32);
#pragma unroll
      for (int nt = 0; nt < 2; nt++) {
        acc[0][nt] = __builtin_amdgcn_mfma_f32_16x16x32_bf16(af0, bfv[nt], acc[0][nt], 0, 0, 0);
        acc[1][nt] = __builtin_amdgcn_mfma_f32_16x16x32_bf16(af1, bfv[nt], acc[1][nt], 0, 0, 0);
      }
    }
  }

#pragma unroll
  for (int nt = 0; nt < 2; nt++) {
    if (pv[nt]) {
      int P = b * HW + pl[nt];
#pragma unroll
      for (int mt = 0; mt < 2; mt++) {
        int oc = mt * 16 + lk * 4;
#pragma unroll
        for (int r = 0; r < 4; r++)
          offp3[((size_t)g * 32 + oc + r) * PTOT + P] = acc[mt][nt][r];
      }
    }
  }
}

// ---------------------------------------------------------------------------
// K6: finalize offsets -> bilinear params per (tap, P). Sums 3 tap-group partials.
// ---------------------------------------------------------------------------
__global__ __launch_bounds__(256) void off_finalize(
    const float* __restrict__ offp3, const float* __restrict__ off_b,
    float4* __restrict__ wts4, int4* __restrict__ idx4)
{
  int i = blockIdx.x * 256 + threadIdx.x;
  if (i >= 9 * PTOT) return;
  int k = i / PTOT;
  int P = i - k * PTOT;
  int b = P / HW;
  int p = P - b * HW;
  int h = p / WW;
  int w = p - h * WW;

  float dy = off_b[2 * k], dx = off_b[2 * k + 1], ml = off_b[18 + k];
#pragma unroll
  for (int g = 0; g < 3; g++) {
    const float* base = offp3 + (size_t)g * 32 * PTOT + P;
    dy += base[(size_t)(2 * k    ) * PTOT];
    dx += base[(size_t)(2 * k + 1) * PTOT];
    ml += base[(size_t)(18 + k   ) * PTOT];
  }

  float m = 1.f / (1.f + expf(-ml));
  float ph = dy + (float)(k / 3 - 1) + (float)h;
  float pw = dx + (float)(k % 3 - 1) + (float)w;
  float h0f = floorf(ph), w0f = floorf(pw);
  float lh = ph - h0f, lw = pw - w0f;
  int h0 = (int)h0f, w0 = (int)w0f;
  int h1 = h0 + 1, w1 = w0 + 1;
  float vh0 = (h0 >= 0 && h0 < HH) ? 1.f : 0.f;
  float vh1 = (h1 >= 0 && h1 < HH) ? 1.f : 0.f;
  float vw0 = (w0 >= 0 && w0 < WW) ? 1.f : 0.f;
  float vw1 = (w1 >= 0 && w1 < WW) ? 1.f : 0.f;
  float4 wv;
  wv.x = (1.f - lh) * (1.f - lw) * m * vh0 * vw0;
  wv.y = (1.f - lh) * lw         * m * vh0 * vw1;
  wv.z = lh * (1.f - lw)         * m * vh1 * vw0;
  wv.w = lh * lw                 * m * vh1 * vw1;
  int hc0 = min(max(h0, 0), HH - 1), hc1 = min(max(h1, 0), HH - 1);
  int wc0 = min(max(w0, 0), WW - 1), wc1 = min(max(w1, 0), WW - 1);
  int base = b * HW;
  int4 iv;
  iv.x = (base + hc0 * WW + wc0) * 512 + 256;
  iv.y = (base + hc0 * WW + wc1) * 512 + 256;
  iv.z = (base + hc1 * WW + wc0) * 512 + 256;
  iv.w = (base + hc1 * WW + wc1) * 512 + 256;
  wts4[i] = wv;
  idx4[i] = iv;
}

// ---------------------------------------------------------------------------
// K7: deformable conv via MFMA bf16 — frozen structure; d stored bf16.
// ---------------------------------------------------------------------------
__global__ __launch_bounds__(512) void deform_mfma(
    const u16* __restrict__ concat,
    const float4* __restrict__ wts4, const int4* __restrict__ idx4,
    const u16* __restrict__ wt_b,
    u16* __restrict__ dbufb, float* __restrict__ part_d)
{
  __shared__ u16    samp[64 * 256];   // 32KB, swizzled: byte ^= (pos&7)<<4
  __shared__ int4   sidx[9][64];      // 9KB
  __shared__ float4 swq[9][64];       // 9KB

  const int t    = threadIdx.x;
  const int wv   = t >> 6;           // 0..7
  const int lane = t & 63;
  const int lr = lane & 15, lk = lane >> 4;
  const int id   = blockIdx.x;
  const int b    = id & 7;
  const int tile = id >> 3;          // 0..56
  const int P0   = b * HW + tile * 64;
  int lim  = HW - tile * 64;
  if (lim > 64) lim = 64;

  for (int item = t; item < 9 * 64; item += 512) {
    int tap = item >> 6, pos = item & 63;
    int off = (pos < lim) ? pos : (lim - 1);
    sidx[tap][pos] = idx4[(size_t)tap * PTOT + P0 + off];
    swq[tap][pos]  = wts4[(size_t)tap * PTOT + P0 + off];
  }
  __syncthreads();

  f32x4 acc[2][4];
#pragma unroll
  for (int mt = 0; mt < 2; mt++)
#pragma unroll
    for (int nt = 0; nt < 4; nt++) acc[mt][nt] = (f32x4)0.f;

  const int c4 = lane * 4;

  for (int tap = 0; tap < 9; tap++) {
#pragma unroll 2
    for (int it = 0; it < 8; it++) {
      int pos = it * 8 + wv;
      int4  iv = sidx[tap][pos];
      float4 wq = swq[tap][pos];
      uint2 u0 = *(const uint2*)(concat + iv.x + c4);
      uint2 u1 = *(const uint2*)(concat + iv.y + c4);
      uint2 u2 = *(const uint2*)(concat + iv.z + c4);
      uint2 u3 = *(const uint2*)(concat + iv.w + c4);
      float a0, a1, a2, a3;
      a0  = wq.x * __uint_as_float(u0.x << 16);
      a1  = wq.x * __uint_as_float(u0.x & 0xFFFF0000u);
      a2  = wq.x * __uint_as_float(u0.y << 16);
      a3  = wq.x * __uint_as_float(u0.y & 0xFFFF0000u);
      a0 = fmaf(wq.y, __uint_as_float(u1.x << 16), a0);
      a1 = fmaf(wq.y, __uint_as_float(u1.x & 0xFFFF0000u), a1);
      a2 = fmaf(wq.y, __uint_as_float(u1.y << 16), a2);
      a3 = fmaf(wq.y, __uint_as_float(u1.y & 0xFFFF0000u), a3);
      a0 = fmaf(wq.z, __uint_as_float(u2.x << 16), a0);
      a1 = fmaf(wq.z, __uint_as_float(u2.x & 0xFFFF0000u), a1);
      a2 = fmaf(wq.z, __uint_as_float(u2.y << 16), a2);
      a3 = fmaf(wq.z, __uint_as_float(u2.y & 0xFFFF0000u), a3);
      a0 = fmaf(wq.w, __uint_as_float(u3.x << 16), a0);
      a1 = fmaf(wq.w, __uint_as_float(u3.x & 0xFFFF0000u), a1);
      a2 = fmaf(wq.w, __uint_as_float(u3.y << 16), a2);
      a3 = fmaf(wq.w, __uint_as_float(u3.y & 0xFFFF0000u), a3);
      uint2 r;
      r.x = (__float_as_uint(a0) >> 16) | (__float_as_uint(a1) & 0xFFFF0000u);
      r.y = (__float_as_uint(a2) >> 16) | (__float_as_uint(a3) & 0xFFFF0000u);
      u32 byte = (u32)pos * 512u + (u32)c4 * 2u;
      byte ^= (u32)(pos & 7) << 4;
      *(uint2*)((char*)samp + byte) = r;
    }
    __syncthreads();   // samp ready

#pragma unroll 1
    for (int cc = 0; cc < 8; cc++) {
      int c0 = cc * 32;
      bf16x8 bfr[4];
#pragma unroll
      for (int nt = 0; nt < 4; nt++) {
        int pos = nt * 16 + lr;
        u32 byte = (u32)pos * 512u + (u32)(c0 + lk * 8) * 2u;
        byte ^= (u32)(pos & 7) << 4;
        bfr[nt] = *(const bf16x8*)((const char*)samp + byte);
      }
      const u16* wp = wt_b + ((size_t)tap * 256 + wv * 32 + lr) * 256
                      + c0 + lk * 8;
      bf16x8 afr[2];
#pragma unroll
      for (int mt = 0; mt < 2; mt++)
        afr[mt] = *(const bf16x8*)(wp + (size_t)mt * 16 * 256);
#pragma unroll
      for (int mt = 0; mt < 2; mt++)
#pragma unroll
        for (int nt = 0; nt < 4; nt++)
          acc[mt][nt] = __builtin_amdgcn_mfma_f32_16x16x32_bf16(
              afr[mt], bfr[nt], acc[mt][nt], 0, 0, 0);
    }
    __syncthreads();   // GEMM done reading samp before next build
  }

  // epilogue: D[oc][pos] -> dbufb NCHW bf16
#pragma unroll
  for (int mt = 0; mt < 2; mt++) {
    int oc = wv * 32 + mt * 16 + lk * 4;
#pragma unroll
    for (int nt = 0; nt < 4; nt++) {
      int pl = tile * 64 + nt * 16 + lr;
      if (pl < HW) {
        u16* dst = dbufb + ((size_t)(b * CH + oc)) * HW + pl;
#pragma unroll
        for (int r = 0; r < 4; r++)
          dst[(size_t)r * HW] = bf16_rne(acc[mt][nt][r]);
      }
    }
  }

  // fused stats partials (f32, from registers)
  float sv[2][4], sq[2][4];
#pragma unroll
  for (int mt = 0; mt < 2; mt++)
#pragma unroll
    for (int r = 0; r < 4; r++) { sv[mt][r] = 0.f; sq[mt][r] = 0.f; }
#pragma unroll
  for (int mt = 0; mt < 2; mt++)
#pragma unroll
    for (int nt = 0; nt < 4; nt++) {
      int pl = tile * 64 + nt * 16 + lr;
      if (pl < HW) {
#pragma unroll
        for (int r = 0; r < 4; r++) {
          float v = acc[mt][nt][r];
          sv[mt][r] += v; sq[mt][r] += v * v;
        }
      }
    }
#pragma unroll
  for (int m = 1; m < 16; m <<= 1) {
#pragma unroll
    for (int mt = 0; mt < 2; mt++)
#pragma unroll
      for (int r = 0; r < 4; r++) {
        sv[mt][r] += __shfl_xor(sv[mt][r], m, 64);
        sq[mt][r] += __shfl_xor(sq[mt][r], m, 64);
      }
  }
  if (lr == 0) {
    float* pp = part_d + (size_t)blockIdx.x * 512;
#pragma unroll
    for (int mt = 0; mt < 2; mt++)
#pragma unroll
      for (int r = 0; r < 4; r++) {
        int oc = wv * 32 + mt * 16 + lk * 4 + r;
        pp[oc * 2]     = sv[mt][r];
        pp[oc * 2 + 1] = sq[mt][r];
      }
  }
}

// ---------------------------------------------------------------------------
// K8: final = relu(d*sc2+sh2 + (out1raw*sc1+sh1)), bf16 inputs, f32 out.
// ---------------------------------------------------------------------------
__global__ __launch_bounds__(256) void final_nchw(
    const u16* __restrict__ dbufb, const u16* __restrict__ out1b,
    const float* __restrict__ st1, const float* __restrict__ g1,
    const float* __restrict__ b1,
    const float* __restrict__ st2, const float* __restrict__ g2,
    const float* __restrict__ b2, float* __restrict__ out)
{
  u32 i4 = blockIdx.x * 256 + threadIdx.x;
  u32 e = i4 * 4;
  int row = (int)(e / HW);
  int c = row & 255;
  float m1 = st1[c], rs1 = st1[CH + c];
  float sc1 = g1[c] * rs1;
  float sh1 = b1[c] - m1 * sc1;
  float m2 = st2[c], rs2 = st2[CH + c];
  float sc2 = g2[c] * rs2;
  float sh2 = b2[c] - m2 * sc2;
  us4 dv4 = *(const us4*)(dbufb + e);
  us4 xv4 = *(const us4*)(out1b + e);
  float4 o;
  o.x = bf16_f(dv4.x) * sc2 + sh2 + bf16_f(xv4.x) * sc1 + sh1;
  o.y = bf16_f(dv4.y) * sc2 + sh2 + bf16_f(xv4.y) * sc1 + sh1;
  o.z = bf16_f(dv4.z) * sc2 + sh2 + bf16_f(xv4.z) * sc1 + sh1;
  o.w = bf16_f(dv4.w) * sc2 + sh2 + bf16_f(xv4.w) * sc1 + sh1;
  o.x = o.x > 0.f ? o.x : 0.f;
  o.y = o.y > 0.f ? o.y : 0.f;
  o.z = o.z > 0.f ? o.z : 0.f;
  o.w = o.w > 0.f ? o.w : 0.f;
  *(float4*)(out + e) = o;
}

// ---------------------------------------------------------------------------
extern "C" void kernel_launch(void* const* d_in, const int* in_sizes, int n_in,
                              void* d_out, int out_size, void* d_ws, size_t ws_size,
                              hipStream_t stream)
{
  const float* x       = (const float*)d_in[0];
  const float* conv1_w = (const float*)d_in[1];
  const float* bn1_g   = (const float*)d_in[2];
  const float* bn1_b   = (const float*)d_in[3];
  const float* off_w   = (const float*)d_in[4];
  const float* off_b   = (const float*)d_in[5];
  const float* dcn_w   = (const float*)d_in[6];
  const float* norm_g  = (const float*)d_in[8];
  const float* norm_b  = (const float*)d_in[9];
  float* out = (float*)d_out;

  char* ws = (char*)d_ws;
  size_t o = 0;
  u16*   out1b   = (u16*)  (ws + o); o += (size_t)PTOT * CH * 2;       // 14.7 MB bf16 raw conv1
  u16*   concat  = (u16*)  (ws + o); o += (size_t)PTOT * 512 * 2;      // 29.5 MB NHWC bf16 [flipx | xp]
  u16*   dbufb   = (u16*)  (ws + o); o += (size_t)PTOT * CH * 2;       // 14.7 MB NCHW bf16
  float* offp3   = (float*)(ws + o); o += (size_t)96 * PTOT * 4;       // 11.1 MB
  u16*   wt_b    = (u16*)  (ws + o); o += (size_t)9 * 256 * 256 * 2;   // 1.18 MB
  u16*   wt_offb = (u16*)  (ws + o); o += (size_t)9 * 32 * 512 * 2;    // 0.29 MB
  u16*   w1b     = (u16*)  (ws + o); o += (size_t)256 * 256 * 2;       // 0.13 MB
  float4* wts4   = (float4*)(ws + o); o += (size_t)9 * PTOT * 16;      // 4.15 MB
  int4*   idx4   = (int4*) (ws + o); o += (size_t)9 * PTOT * 16;       // 4.15 MB
  float* st      = (float*)(ws + o); o += 512 * 4;
  float* st2     = (float*)(ws + o); o += 512 * 4;
  float* part_c1 = (float*)(ws + o); o += (size_t)928 * 128 * 2 * 4;   // 950 KB
  float* part_d  = (float*)(ws + o); o += (size_t)456 * 512 * 4;       // 934 KB

  flip_prep<<<dim3(113, 8, 8), 256, 0, stream>>>(x, concat, conv1_w, off_w,
                                                 dcn_w, w1b, wt_offb, wt_b);
  conv1_mfma<<<dim3(232, 2), 256, 0, stream>>>(concat, w1b, out1b, part_c1);
  stats_fin_c1<<<256, 256, 0, stream>>>(part_c1, st);
  norm_transpose<<<dim3(113, 8, 8), 256, 0, stream>>>(out1b, st, bn1_g, bn1_b, concat);
  off_mfma<<<dim3(456, 3), 128, 0, stream>>>(concat, wt_offb, offp3);
  off_finalize<<<(9 * PTOT + 255) / 256, 256, 0, stream>>>(offp3, off_b, wts4, idx4);
  deform_mfma<<<456, 512, 0, stream>>>(concat, wts4, idx4, wt_b, dbufb, part_d);
  stats_fin_d<<<256, 256, 0, stream>>>(part_d, st2);
  final_nchw<<<7200, 256, 0, stream>>>(dbufb, out1b, st, bn1_g, bn1_b,
                                       st2, norm_g, norm_b, out);
}

// Round 17
// 231.393 us; speedup vs baseline: 1.3367x; 1.0154x over previous
//
#include <hip/hip_runtime.h>
#include <math.h>

// Problem constants
#define BATCH 8
#define CH 256
#define HH 45
#define WW 80
#define HW 3600        // 45*80
#define PTOT 28800     // BATCH*HW

typedef unsigned short u16;
typedef unsigned int   u32;
typedef __attribute__((ext_vector_type(8))) short bf16x8;
typedef __attribute__((ext_vector_type(4))) float f32x4;

struct __align__(8) us4 { u16 x, y, z, w; };

__device__ __forceinline__ u16 bf16_rne(float x) {
  u32 u = __float_as_uint(x);
  u += 0x7FFF + ((u >> 16) & 1);
  return (u16)(u >> 16);
}
__device__ __forceinline__ float bf16_f(u16 v) {
  return __uint_as_float((u32)v << 16);
}

// ---------------------------------------------------------------------------
// K1: flip-transpose x -> concat[P][0:256] bf16 (w-flipped NHWC)
//     + merged weight prep (blocks with linid < 2304 also do prep slices).
// ---------------------------------------------------------------------------
__global__ __launch_bounds__(256) void flip_prep(
    const float* __restrict__ x, u16* __restrict__ concat,
    const float* __restrict__ conv1_w, const float* __restrict__ off_w,
    const float* __restrict__ dcn_w,
    u16* __restrict__ w1b, u16* __restrict__ wt_offb, u16* __restrict__ wt_b)
{
  __shared__ float tile[32][36];
  const int b  = blockIdx.z;
  const int c0 = blockIdx.y * 32;
  const int p0 = blockIdx.x * 32;
  int rem = HW - p0; if (rem > 32) rem = 32;
  const int t = threadIdx.x;

  // --- merged prep_wts ---
  {
    int linid = blockIdx.x + 113 * (blockIdx.y + 8 * blockIdx.z);
    if (linid < 2304) {
      int i = linid * 256 + t;
      if (i < 256 * 256) {
        w1b[i] = bf16_rne(conv1_w[i]);
      }
      if (i < 9 * 32 * 512) {
        int tap = i >> 14;
        int r   = i & 16383;
        int oc  = r >> 9;
        int c   = r & 511;
        float v = (oc < 27) ? off_w[((size_t)oc * 512 + c) * 9 + tap] : 0.f;
        wt_offb[i] = bf16_rne(v);
      }
      if (i < 9 * 256 * 256) {
        int c = i & 255;
        int oc = (i >> 8) & 255;
        int tap = i >> 16;
        wt_b[i] = bf16_rne(dcn_w[((size_t)oc * 256 + c) * 9 + tap]);
      }
    }
  }

  // --- flip transpose ---
  {
    int c = t >> 3, p4 = (t & 7) * 4;
    if (p4 < rem) {
      float4 v = *(const float4*)(x + ((size_t)b * CH + c0 + c) * HW + p0 + p4);
      *(float4*)&tile[c][p4] = v;
    }
  }
  __syncthreads();
  {
    int r = t >> 3, cq = (t & 7) * 4;
    if (r < rem) {
      int p = p0 + r;
      int h = p / WW, w = p - h * WW;
      int pf = h * WW + (WW - 1 - w);
      us4 o;
      o.x = bf16_rne(tile[cq + 0][r]);
      o.y = bf16_rne(tile[cq + 1][r]);
      o.z = bf16_rne(tile[cq + 2][r]);
      o.w = bf16_rne(tile[cq + 3][r]);
      *(us4*)(concat + ((size_t)b * HW + pf) * 512 + c0 + cq) = o;
    }
  }
}

// ---------------------------------------------------------------------------
// K2: conv1 via MFMA, XCD b-swizzled + fused stats partials.
// ---------------------------------------------------------------------------
__global__ __launch_bounds__(256) void conv1_mfma(
    const u16* __restrict__ concat, const u16* __restrict__ w1b,
    u16* __restrict__ out1b, float* __restrict__ part_c1)
{
  const int t = threadIdx.x;
  const int wv = t >> 6, lane = t & 63;
  const int lr = lane & 15, lk = lane >> 4;
  const int id = blockIdx.x;
  const int b  = id & 7;
  const int pt = id >> 3;                    // 0..28
  const int oc0 = blockIdx.y * 128 + (wv & 1) * 64;
  const int p0  = pt * 128 + (wv >> 1) * 64; // within image

  const u16* bptr[4];
#pragma unroll
  for (int nt = 0; nt < 4; nt++) {
    int pl = p0 + nt * 16 + lr;
    int pc = pl < HW ? pl : HW - 1;
    int h = pc / WW, w = pc - h * WW;
    int pf = b * HW + h * WW + (WW - 1 - w);
    bptr[nt] = concat + (size_t)pf * 512 + lk * 8;
  }
  const u16* aptr = w1b + ((size_t)(oc0 + lr)) * 256 + lk * 8;

  f32x4 acc[4][4];
#pragma unroll
  for (int mt = 0; mt < 4; mt++)
#pragma unroll
    for (int nt = 0; nt < 4; nt++) acc[mt][nt] = (f32x4)0.f;

#pragma unroll
  for (int cc = 0; cc < 8; cc++) {
    bf16x8 af[4], bfv[4];
#pragma unroll
    for (int mt = 0; mt < 4; mt++)
      af[mt] = *(const bf16x8*)(aptr + (size_t)mt * 16 * 256 + cc * 32);
#pragma unroll
    for (int nt = 0; nt < 4; nt++)
      bfv[nt] = *(const bf16x8*)(bptr[nt] + cc * 32);
#pragma unroll
    for (int mt = 0; mt < 4; mt++)
#pragma unroll
      for (int nt = 0; nt < 4; nt++)
        acc[mt][nt] = __builtin_amdgcn_mfma_f32_16x16x32_bf16(
            af[mt], bfv[nt], acc[mt][nt], 0, 0, 0);
  }

#pragma unroll
  for (int mt = 0; mt < 4; mt++) {
    int oc = oc0 + mt * 16 + lk * 4;
#pragma unroll
    for (int nt = 0; nt < 4; nt++) {
      int pl = p0 + nt * 16 + lr;
      if (pl < HW) {
        u16* dst = out1b + ((size_t)(b * CH + oc)) * HW + pl;
#pragma unroll
        for (int r = 0; r < 4; r++)
          dst[(size_t)r * HW] = bf16_rne(acc[mt][nt][r]);
      }
    }
  }

  // fused stats partials (f32, from registers)
  float sv[4][4], sq[4][4];
#pragma unroll
  for (int mt = 0; mt < 4; mt++)
#pragma unroll
    for (int r = 0; r < 4; r++) { sv[mt][r] = 0.f; sq[mt][r] = 0.f; }
#pragma unroll
  for (int mt = 0; mt < 4; mt++)
#pragma unroll
    for (int nt = 0; nt < 4; nt++) {
      int pl = p0 + nt * 16 + lr;
      if (pl < HW) {
#pragma unroll
        for (int r = 0; r < 4; r++) {
          float v = acc[mt][nt][r];
          sv[mt][r] += v; sq[mt][r] += v * v;
        }
      }
    }
#pragma unroll
  for (int m = 1; m < 16; m <<= 1) {
#pragma unroll
    for (int mt = 0; mt < 4; mt++)
#pragma unroll
      for (int r = 0; r < 4; r++) {
        sv[mt][r] += __shfl_xor(sv[mt][r], m, 64);
        sq[mt][r] += __shfl_xor(sq[mt][r], m, 64);
      }
  }
  if (lr == 0) {
    int slot = (wv >> 1) + 2 * blockIdx.x + 464 * blockIdx.y;
    float* pp = part_c1 + (size_t)slot * 128 * 2;
#pragma unroll
    for (int mt = 0; mt < 4; mt++)
#pragma unroll
      for (int r = 0; r < 4; r++) {
        int ocl = (wv & 1) * 64 + mt * 16 + lk * 4 + r;
        pp[ocl * 2]     = sv[mt][r];
        pp[ocl * 2 + 1] = sq[mt][r];
      }
  }
}

// ---------------------------------------------------------------------------
// K3a: finalize conv1 stats — 256 blocks (one per channel), 256 thr each.
// ---------------------------------------------------------------------------
__global__ __launch_bounds__(256) void stats_fin_c1(
    const float* __restrict__ part_c1, float* __restrict__ st)
{
  const int c = blockIdx.x;
  const int y = c >> 7, ocl = c & 127;
  const int t = threadIdx.x;
  const float* base = part_c1 + (size_t)y * 464 * 256 + ocl * 2;
  float s = 0.f, s2 = 0.f;
  for (int i = t; i < 464; i += 256) {
    s  += base[(size_t)i * 256];
    s2 += base[(size_t)i * 256 + 1];
  }
  __shared__ float ls[256], ls2[256];
  ls[t] = s; ls2[t] = s2;
  __syncthreads();
  for (int off = 128; off > 0; off >>= 1) {
    if (t < off) { ls[t] += ls[t + off]; ls2[t] += ls2[t + off]; }
    __syncthreads();
  }
  if (t == 0) {
    float m = ls[0] / (float)PTOT;
    float var = ls2[0] / (float)PTOT - m * m;
    st[c] = m;
    st[CH + c] = rsqrtf(var + 1e-5f);
  }
}

// ---------------------------------------------------------------------------
// K3b: finalize deform stats — 256 blocks (one per channel), 256 thr each.
// ---------------------------------------------------------------------------
__global__ __launch_bounds__(256) void stats_fin_d(
    const float* __restrict__ part_d, float* __restrict__ st)
{
  const int c = blockIdx.x;
  const int t = threadIdx.x;
  float s = 0.f, s2 = 0.f;
  for (int i = t; i < 456; i += 256) {
    s  += part_d[(size_t)i * 512 + c * 2];
    s2 += part_d[(size_t)i * 512 + c * 2 + 1];
  }
  __shared__ float ls[256], ls2[256];
  ls[t] = s; ls2[t] = s2;
  __syncthreads();
  for (int off = 128; off > 0; off >>= 1) {
    if (t < off) { ls[t] += ls[t + off]; ls2[t] += ls2[t + off]; }
    __syncthreads();
  }
  if (t == 0) {
    float m = ls[0] / (float)PTOT;
    float var = ls2[0] / (float)PTOT - m * m;
    st[c] = m;
    st[CH + c] = rsqrtf(var + 1e-5f);
  }
}

// ---------------------------------------------------------------------------
// K4: read bf16 raw out1b, write normalized bf16 into concat[P][256:512].
// ---------------------------------------------------------------------------
__global__ __launch_bounds__(256) void norm_transpose(
    const u16* __restrict__ out1b, const float* __restrict__ st,
    const float* __restrict__ g, const float* __restrict__ bb,
    u16* __restrict__ concat)
{
  __shared__ float tile[32][36];
  const int b  = blockIdx.z;
  const int c0 = blockIdx.y * 32;
  const int p0 = blockIdx.x * 32;
  int rem = HW - p0; if (rem > 32) rem = 32;
  const int t = threadIdx.x;

  {
    int c  = t >> 3;
    int p4 = (t & 7) * 4;
    int cg = c0 + c;
    float m  = st[cg], rs = st[CH + cg];
    float sc = g[cg] * rs;
    float sh = bb[cg] - m * sc;
    if (p4 < rem) {
      size_t base = ((size_t)b * CH + cg) * HW + p0;
      us4 v4 = *(const us4*)(out1b + base + p4);
      tile[c][p4 + 0] = bf16_f(v4.x) * sc + sh;
      tile[c][p4 + 1] = bf16_f(v4.y) * sc + sh;
      tile[c][p4 + 2] = bf16_f(v4.z) * sc + sh;
      tile[c][p4 + 3] = bf16_f(v4.w) * sc + sh;
    }
  }
  __syncthreads();
  {
    int r  = t >> 3;
    int cq = (t & 7) * 4;
    if (r < rem) {
      us4 o;
      o.x = bf16_rne(tile[cq + 0][r]);
      o.y = bf16_rne(tile[cq + 1][r]);
      o.z = bf16_rne(tile[cq + 2][r]);
      o.w = bf16_rne(tile[cq + 3][r]);
      *(us4*)(concat + ((size_t)b * HW + p0 + r) * 512 + 256 + c0 + cq) = o;
    }
  }
}

// ---------------------------------------------------------------------------
// K5: offset conv via MFMA, tap-split 3-ways; XCD b-swizzled.
// Wave = 32 pos x 32 oc; grid (456, 3), 128 thr.
// ---------------------------------------------------------------------------
__global__ __launch_bounds__(128) void off_mfma(
    const u16* __restrict__ concat, const u16* __restrict__ wt_offb,
    float* __restrict__ offp3)
{
  const int t = threadIdx.x;
  const int g = blockIdx.y;
  const int wv = t >> 6, lane = t & 63;
  const int lr = lane & 15, lk = lane >> 4;
  const int id = blockIdx.x;
  const int b    = id & 7;
  const int tile = id >> 3;            // 0..56
  const int pbase = tile * 64 + wv * 32;

  int   pl[2];
  int   h[2], w[2];
  bool  pv[2];
#pragma unroll
  for (int nt = 0; nt < 2; nt++) {
    int p = pbase + nt * 16 + lr;
    pv[nt] = p < HW;
    if (!pv[nt]) p = HW - 1;
    pl[nt] = p;
    h[nt] = p / WW;
    w[nt] = p - h[nt] * WW;
  }

  f32x4 acc[2][2];
#pragma unroll
  for (int mt = 0; mt < 2; mt++)
#pragma unroll
    for (int nt = 0; nt < 2; nt++) acc[mt][nt] = (f32x4)0.f;

#pragma unroll 1
  for (int tl = 0; tl < 3; tl++) {
    int tap = g * 3 + tl;
    int dy = tap / 3 - 1, dx = tap % 3 - 1;
    const u16* bp[2];
    bool valid[2];
#pragma unroll
    for (int nt = 0; nt < 2; nt++) {
      valid[nt] = ((unsigned)(h[nt] + dy) < HH) && ((unsigned)(w[nt] + dx) < WW);
      int Ps = b * HW + (valid[nt] ? (pl[nt] + dy * WW + dx) : pl[nt]);
      bp[nt] = concat + (size_t)Ps * 512 + lk * 8;
    }
    const u16* ap = wt_offb + ((size_t)tap * 32 + lr) * 512 + lk * 8;
#pragma unroll
    for (int cc = 0; cc < 16; cc++) {
      bf16x8 bfv[2];
#pragma unroll
      for (int nt = 0; nt < 2; nt++) {
        bfv[nt] = *(const bf16x8*)(bp[nt] + cc * 32);
        if (!valid[nt]) bfv[nt] = (bf16x8)(short)0;
      }
      bf16x8 af0 = *(const bf16x8*)(ap + cc * 32);
      bf16x8 af1 = *(const bf16x8*)(ap + 16 * 512 + cc * 32);
#pragma unroll
      for (int nt = 0; nt < 2; nt++) {
        acc[0][nt] = __builtin_amdgcn_mfma_f32_16x16x32_bf16(af0, bfv[nt], acc[0][nt], 0, 0, 0);
        acc[1][nt] = __builtin_amdgcn_mfma_f32_16x16x32_bf16(af1, bfv[nt], acc[1][nt], 0, 0, 0);
      }
    }
  }

#pragma unroll
  for (int nt = 0; nt < 2; nt++) {
    if (pv[nt]) {
      int P = b * HW + pl[nt];
#pragma unroll
      for (int mt = 0; mt < 2; mt++) {
        int oc = mt * 16 + lk * 4;
#pragma unroll
        for (int r = 0; r < 4; r++)
          offp3[((size_t)g * 32 + oc + r) * PTOT + P] = acc[mt][nt][r];
      }
    }
  }
}

// ---------------------------------------------------------------------------
// K7: deformable conv via MFMA bf16 — frozen structure; bilinear-param
// computation (old off_finalize) fused into the hoisted param stage:
// each (tap,pos) item sums the 3 tap-group partials from offp3, applies
// sigmoid/floor/validity, and writes sidx/swq LDS directly. Same g-order
// summation as the old kernel -> bitwise-identical params.
// ---------------------------------------------------------------------------
__global__ __launch_bounds__(512) void deform_mfma(
    const u16* __restrict__ concat,
    const float* __restrict__ offp3, const float* __restrict__ off_b,
    const u16* __restrict__ wt_b,
    u16* __restrict__ dbufb, float* __restrict__ part_d)
{
  __shared__ u16    samp[64 * 256];   // 32KB, swizzled: byte ^= (pos&7)<<4
  __shared__ int4   sidx[9][64];      // 9KB
  __shared__ float4 swq[9][64];       // 9KB

  const int t    = threadIdx.x;
  const int wv   = t >> 6;           // 0..7
  const int lane = t & 63;
  const int lr = lane & 15, lk = lane >> 4;
  const int id   = blockIdx.x;
  const int b    = id & 7;
  const int tile = id >> 3;          // 0..56
  const int P0   = b * HW + tile * 64;
  int lim  = HW - tile * 64;
  if (lim > 64) lim = 64;

  // fused param stage (old off_finalize), all 9 taps
  for (int item = t; item < 9 * 64; item += 512) {
    int tap = item >> 6, pos = item & 63;
    int off = (pos < lim) ? pos : (lim - 1);
    int pl = tile * 64 + off;
    int P  = b * HW + pl;
    int h = pl / WW, w = pl - h * WW;

    float dy = off_b[2 * tap], dx = off_b[2 * tap + 1], ml = off_b[18 + tap];
#pragma unroll
    for (int g = 0; g < 3; g++) {
      const float* basep = offp3 + (size_t)g * 32 * PTOT + P;
      dy += basep[(size_t)(2 * tap    ) * PTOT];
      dx += basep[(size_t)(2 * tap + 1) * PTOT];
      ml += basep[(size_t)(18 + tap   ) * PTOT];
    }
    float m = 1.f / (1.f + expf(-ml));
    float ph = dy + (float)(tap / 3 - 1) + (float)h;
    float pw = dx + (float)(tap % 3 - 1) + (float)w;
    float h0f = floorf(ph), w0f = floorf(pw);
    float lh = ph - h0f, lw = pw - w0f;
    int h0 = (int)h0f, w0 = (int)w0f;
    int h1 = h0 + 1, w1 = w0 + 1;
    float vh0 = (h0 >= 0 && h0 < HH) ? 1.f : 0.f;
    float vh1 = (h1 >= 0 && h1 < HH) ? 1.f : 0.f;
    float vw0 = (w0 >= 0 && w0 < WW) ? 1.f : 0.f;
    float vw1 = (w1 >= 0 && w1 < WW) ? 1.f : 0.f;
    float4 wvq;
    wvq.x = (1.f - lh) * (1.f - lw) * m * vh0 * vw0;
    wvq.y = (1.f - lh) * lw         * m * vh0 * vw1;
    wvq.z = lh * (1.f - lw)         * m * vh1 * vw0;
    wvq.w = lh * lw                 * m * vh1 * vw1;
    int hc0 = min(max(h0, 0), HH - 1), hc1 = min(max(h1, 0), HH - 1);
    int wc0 = min(max(w0, 0), WW - 1), wc1 = min(max(w1, 0), WW - 1);
    int gbase = b * HW;
    int4 iv;
    iv.x = (gbase + hc0 * WW + wc0) * 512 + 256;
    iv.y = (gbase + hc0 * WW + wc1) * 512 + 256;
    iv.z = (gbase + hc1 * WW + wc0) * 512 + 256;
    iv.w = (gbase + hc1 * WW + wc1) * 512 + 256;
    swq[tap][pos]  = wvq;
    sidx[tap][pos] = iv;
  }
  __syncthreads();

  f32x4 acc[2][4];
#pragma unroll
  for (int mt = 0; mt < 2; mt++)
#pragma unroll
    for (int nt = 0; nt < 4; nt++) acc[mt][nt] = (f32x4)0.f;

  const int c4 = lane * 4;

  for (int tap = 0; tap < 9; tap++) {
#pragma unroll 2
    for (int it = 0; it < 8; it++) {
      int pos = it * 8 + wv;
      int4  iv = sidx[tap][pos];
      float4 wq = swq[tap][pos];
      uint2 u0 = *(const uint2*)(concat + iv.x + c4);
      uint2 u1 = *(const uint2*)(concat + iv.y + c4);
      uint2 u2 = *(const uint2*)(concat + iv.z + c4);
      uint2 u3 = *(const uint2*)(concat + iv.w + c4);
      float a0, a1, a2, a3;
      a0  = wq.x * __uint_as_float(u0.x << 16);
      a1  = wq.x * __uint_as_float(u0.x & 0xFFFF0000u);
      a2  = wq.x * __uint_as_float(u0.y << 16);
      a3  = wq.x * __uint_as_float(u0.y & 0xFFFF0000u);
      a0 = fmaf(wq.y, __uint_as_float(u1.x << 16), a0);
      a1 = fmaf(wq.y, __uint_as_float(u1.x & 0xFFFF0000u), a1);
      a2 = fmaf(wq.y, __uint_as_float(u1.y << 16), a2);
      a3 = fmaf(wq.y, __uint_as_float(u1.y & 0xFFFF0000u), a3);
      a0 = fmaf(wq.z, __uint_as_float(u2.x << 16), a0);
      a1 = fmaf(wq.z, __uint_as_float(u2.x & 0xFFFF0000u), a1);
      a2 = fmaf(wq.z, __uint_as_float(u2.y << 16), a2);
      a3 = fmaf(wq.z, __uint_as_float(u2.y & 0xFFFF0000u), a3);
      a0 = fmaf(wq.w, __uint_as_float(u3.x << 16), a0);
      a1 = fmaf(wq.w, __uint_as_float(u3.x & 0xFFFF0000u), a1);
      a2 = fmaf(wq.w, __uint_as_float(u3.y << 16), a2);
      a3 = fmaf(wq.w, __uint_as_float(u3.y & 0xFFFF0000u), a3);
      uint2 r;
      r.x = (__float_as_uint(a0) >> 16) | (__float_as_uint(a1) & 0xFFFF0000u);
      r.y = (__float_as_uint(a2) >> 16) | (__float_as_uint(a3) & 0xFFFF0000u);
      u32 byte = (u32)pos * 512u + (u32)c4 * 2u;
      byte ^= (u32)(pos & 7) << 4;
      *(uint2*)((char*)samp + byte) = r;
    }
    __syncthreads();   // samp ready

#pragma unroll 1
    for (int cc = 0; cc < 8; cc++) {
      int c0 = cc * 32;
      bf16x8 bfr[4];
#pragma unroll
      for (int nt = 0; nt < 4; nt++) {
        int pos = nt * 16 + lr;
        u32 byte = (u32)pos * 512u + (u32)(c0 + lk * 8) * 2u;
        byte ^= (u32)(pos & 7) << 4;
        bfr[nt] = *(const bf16x8*)((const char*)samp + byte);
      }
      const u16* wp = wt_b + ((size_t)tap * 256 + wv * 32 + lr) * 256
                      + c0 + lk * 8;
      bf16x8 afr[2];
#pragma unroll
      for (int mt = 0; mt < 2; mt++)
        afr[mt] = *(const bf16x8*)(wp + (size_t)mt * 16 * 256);
#pragma unroll
      for (int mt = 0; mt < 2; mt++)
#pragma unroll
        for (int nt = 0; nt < 4; nt++)
          acc[mt][nt] = __builtin_amdgcn_mfma_f32_16x16x32_bf16(
              afr[mt], bfr[nt], acc[mt][nt], 0, 0, 0);
    }
    __syncthreads();   // GEMM done reading samp before next build
  }

  // epilogue: D[oc][pos] -> dbufb NCHW bf16
#pragma unroll
  for (int mt = 0; mt < 2; mt++) {
    int oc = wv * 32 + mt * 16 + lk * 4;
#pragma unroll
    for (int nt = 0; nt < 4; nt++) {
      int pl = tile * 64 + nt * 16 + lr;
      if (pl < HW) {
        u16* dst = dbufb + ((size_t)(b * CH + oc)) * HW + pl;
#pragma unroll
        for (int r = 0; r < 4; r++)
          dst[(size_t)r * HW] = bf16_rne(acc[mt][nt][r]);
      }
    }
  }

  // fused stats partials (f32, from registers)
  float sv[2][4], sq[2][4];
#pragma unroll
  for (int mt = 0; mt < 2; mt++)
#pragma unroll
    for (int r = 0; r < 4; r++) { sv[mt][r] = 0.f; sq[mt][r] = 0.f; }
#pragma unroll
  for (int mt = 0; mt < 2; mt++)
#pragma unroll
    for (int nt = 0; nt < 4; nt++) {
      int pl = tile * 64 + nt * 16 + lr;
      if (pl < HW) {
#pragma unroll
        for (int r = 0; r < 4; r++) {
          float v = acc[mt][nt][r];
          sv[mt][r] += v; sq[mt][r] += v * v;
        }
      }
    }
#pragma unroll
  for (int m = 1; m < 16; m <<= 1) {
#pragma unroll
    for (int mt = 0; mt < 2; mt++)
#pragma unroll
      for (int r = 0; r < 4; r++) {
        sv[mt][r] += __shfl_xor(sv[mt][r], m, 64);
        sq[mt][r] += __shfl_xor(sq[mt][r], m, 64);
      }
  }
  if (lr == 0) {
    float* pp = part_d + (size_t)blockIdx.x * 512;
#pragma unroll
    for (int mt = 0; mt < 2; mt++)
#pragma unroll
      for (int r = 0; r < 4; r++) {
        int oc = wv * 32 + mt * 16 + lk * 4 + r;
        pp[oc * 2]     = sv[mt][r];
        pp[oc * 2 + 1] = sq[mt][r];
      }
  }
}

// ---------------------------------------------------------------------------
// K8: final = relu(d*sc2+sh2 + (out1raw*sc1+sh1)), bf16 inputs, f32 out.
// ---------------------------------------------------------------------------
__global__ __launch_bounds__(256) void final_nchw(
    const u16* __restrict__ dbufb, const u16* __restrict__ out1b,
    const float* __restrict__ st1, const float* __restrict__ g1,
    const float* __restrict__ b1,
    const float* __restrict__ st2, const float* __restrict__ g2,
    const float* __restrict__ b2, float* __restrict__ out)
{
  u32 i4 = blockIdx.x * 256 + threadIdx.x;
  u32 e = i4 * 4;
  int row = (int)(e / HW);
  int c = row & 255;
  float m1 = st1[c], rs1 = st1[CH + c];
  float sc1 = g1[c] * rs1;
  float sh1 = b1[c] - m1 * sc1;
  float m2 = st2[c], rs2 = st2[CH + c];
  float sc2 = g2[c] * rs2;
  float sh2 = b2[c] - m2 * sc2;
  us4 dv4 = *(const us4*)(dbufb + e);
  us4 xv4 = *(const us4*)(out1b + e);
  float4 o;
  o.x = bf16_f(dv4.x) * sc2 + sh2 + bf16_f(xv4.x) * sc1 + sh1;
  o.y = bf16_f(dv4.y) * sc2 + sh2 + bf16_f(xv4.y) * sc1 + sh1;
  o.z = bf16_f(dv4.z) * sc2 + sh2 + bf16_f(xv4.z) * sc1 + sh1;
  o.w = bf16_f(dv4.w) * sc2 + sh2 + bf16_f(xv4.w) * sc1 + sh1;
  o.x = o.x > 0.f ? o.x : 0.f;
  o.y = o.y > 0.f ? o.y : 0.f;
  o.z = o.z > 0.f ? o.z : 0.f;
  o.w = o.w > 0.f ? o.w : 0.f;
  *(float4*)(out + e) = o;
}

// ---------------------------------------------------------------------------
extern "C" void kernel_launch(void* const* d_in, const int* in_sizes, int n_in,
                              void* d_out, int out_size, void* d_ws, size_t ws_size,
                              hipStream_t stream)
{
  const float* x       = (const float*)d_in[0];
  const float* conv1_w = (const float*)d_in[1];
  const float* bn1_g   = (const float*)d_in[2];
  const float* bn1_b   = (const float*)d_in[3];
  const float* off_w   = (const float*)d_in[4];
  const float* off_b   = (const float*)d_in[5];
  const float* dcn_w   = (const float*)d_in[6];
  const float* norm_g  = (const float*)d_in[8];
  const float* norm_b  = (const float*)d_in[9];
  float* out = (float*)d_out;

  char* ws = (char*)d_ws;
  size_t o = 0;
  u16*   out1b   = (u16*)  (ws + o); o += (size_t)PTOT * CH * 2;       // 14.7 MB bf16 raw conv1
  u16*   concat  = (u16*)  (ws + o); o += (size_t)PTOT * 512 * 2;      // 29.5 MB NHWC bf16 [flipx | xp]
  u16*   dbufb   = (u16*)  (ws + o); o += (size_t)PTOT * CH * 2;       // 14.7 MB NCHW bf16
  float* offp3   = (float*)(ws + o); o += (size_t)96 * PTOT * 4;       // 11.1 MB
  u16*   wt_b    = (u16*)  (ws + o); o += (size_t)9 * 256 * 256 * 2;   // 1.18 MB
  u16*   wt_offb = (u16*)  (ws + o); o += (size_t)9 * 32 * 512 * 2;    // 0.29 MB
  u16*   w1b     = (u16*)  (ws + o); o += (size_t)256 * 256 * 2;       // 0.13 MB
  float* st      = (float*)(ws + o); o += 512 * 4;
  float* st2     = (float*)(ws + o); o += 512 * 4;
  float* part_c1 = (float*)(ws + o); o += (size_t)928 * 128 * 2 * 4;   // 950 KB
  float* part_d  = (float*)(ws + o); o += (size_t)456 * 512 * 4;       // 934 KB

  flip_prep<<<dim3(113, 8, 8), 256, 0, stream>>>(x, concat, conv1_w, off_w,
                                                 dcn_w, w1b, wt_offb, wt_b);
  conv1_mfma<<<dim3(232, 2), 256, 0, stream>>>(concat, w1b, out1b, part_c1);
  stats_fin_c1<<<256, 256, 0, stream>>>(part_c1, st);
  norm_transpose<<<dim3(113, 8, 8), 256, 0, stream>>>(out1b, st, bn1_g, bn1_b, concat);
  off_mfma<<<dim3(456, 3), 128, 0, stream>>>(concat, wt_offb, offp3);
  deform_mfma<<<456, 512, 0, stream>>>(concat, offp3, off_b, wt_b, dbufb, part_d);
  stats_fin_d<<<256, 256, 0, stream>>>(part_d, st2);
  final_nchw<<<7200, 256, 0, stream>>>(dbufb, out1b, st, bn1_g, bn1_b,
                                       st2, norm_g, norm_b, out);
}

// Round 18
// 226.912 us; speedup vs baseline: 1.3631x; 1.0197x over previous
//
#include <hip/hip_runtime.h>
#include <math.h>

// Problem constants
#define BATCH 8
#define CH 256
#define HH 45
#define WW 80
#define HW 3600        // 45*80
#define PTOT 28800     // BATCH*HW

typedef unsigned short u16;
typedef unsigned int   u32;
typedef __attribute__((ext_vector_type(8))) short bf16x8;
typedef __attribute__((ext_vector_type(4))) float f32x4;

struct __align__(8) us4 { u16 x, y, z, w; };

__device__ __forceinline__ u16 bf16_rne(float x) {
  u32 u = __float_as_uint(x);
  u += 0x7FFF + ((u >> 16) & 1);
  return (u16)(u >> 16);
}
__device__ __forceinline__ float bf16_f(u16 v) {
  return __uint_as_float((u32)v << 16);
}

// ---------------------------------------------------------------------------
// K1: flip-transpose x -> concat[P][0:256] bf16 (w-flipped NHWC)
//     + merged weight prep (blocks with linid < 2304 also do prep slices).
// ---------------------------------------------------------------------------
__global__ __launch_bounds__(256) void flip_prep(
    const float* __restrict__ x, u16* __restrict__ concat,
    const float* __restrict__ conv1_w, const float* __restrict__ off_w,
    const float* __restrict__ dcn_w,
    u16* __restrict__ w1b, u16* __restrict__ wt_offb, u16* __restrict__ wt_b)
{
  __shared__ float tile[32][36];
  const int b  = blockIdx.z;
  const int c0 = blockIdx.y * 32;
  const int p0 = blockIdx.x * 32;
  int rem = HW - p0; if (rem > 32) rem = 32;
  const int t = threadIdx.x;

  // --- merged prep_wts ---
  {
    int linid = blockIdx.x + 113 * (blockIdx.y + 8 * blockIdx.z);
    if (linid < 2304) {
      int i = linid * 256 + t;
      if (i < 256 * 256) {
        w1b[i] = bf16_rne(conv1_w[i]);
      }
      if (i < 9 * 32 * 512) {
        int tap = i >> 14;
        int r   = i & 16383;
        int oc  = r >> 9;
        int c   = r & 511;
        float v = (oc < 27) ? off_w[((size_t)oc * 512 + c) * 9 + tap] : 0.f;
        wt_offb[i] = bf16_rne(v);
      }
      if (i < 9 * 256 * 256) {
        int c = i & 255;
        int oc = (i >> 8) & 255;
        int tap = i >> 16;
        wt_b[i] = bf16_rne(dcn_w[((size_t)oc * 256 + c) * 9 + tap]);
      }
    }
  }

  // --- flip transpose ---
  {
    int c = t >> 3, p4 = (t & 7) * 4;
    if (p4 < rem) {
      float4 v = *(const float4*)(x + ((size_t)b * CH + c0 + c) * HW + p0 + p4);
      *(float4*)&tile[c][p4] = v;
    }
  }
  __syncthreads();
  {
    int r = t >> 3, cq = (t & 7) * 4;
    if (r < rem) {
      int p = p0 + r;
      int h = p / WW, w = p - h * WW;
      int pf = h * WW + (WW - 1 - w);
      us4 o;
      o.x = bf16_rne(tile[cq + 0][r]);
      o.y = bf16_rne(tile[cq + 1][r]);
      o.z = bf16_rne(tile[cq + 2][r]);
      o.w = bf16_rne(tile[cq + 3][r]);
      *(us4*)(concat + ((size_t)b * HW + pf) * 512 + c0 + cq) = o;
    }
  }
}

// ---------------------------------------------------------------------------
// K2: conv1 via MFMA, XCD b-swizzled + fused stats partials.
// ---------------------------------------------------------------------------
__global__ __launch_bounds__(256) void conv1_mfma(
    const u16* __restrict__ concat, const u16* __restrict__ w1b,
    u16* __restrict__ out1b, float* __restrict__ part_c1)
{
  const int t = threadIdx.x;
  const int wv = t >> 6, lane = t & 63;
  const int lr = lane & 15, lk = lane >> 4;
  const int id = blockIdx.x;
  const int b  = id & 7;
  const int pt = id >> 3;                    // 0..28
  const int oc0 = blockIdx.y * 128 + (wv & 1) * 64;
  const int p0  = pt * 128 + (wv >> 1) * 64; // within image

  const u16* bptr[4];
#pragma unroll
  for (int nt = 0; nt < 4; nt++) {
    int pl = p0 + nt * 16 + lr;
    int pc = pl < HW ? pl : HW - 1;
    int h = pc / WW, w = pc - h * WW;
    int pf = b * HW + h * WW + (WW - 1 - w);
    bptr[nt] = concat + (size_t)pf * 512 + lk * 8;
  }
  const u16* aptr = w1b + ((size_t)(oc0 + lr)) * 256 + lk * 8;

  f32x4 acc[4][4];
#pragma unroll
  for (int mt = 0; mt < 4; mt++)
#pragma unroll
    for (int nt = 0; nt < 4; nt++) acc[mt][nt] = (f32x4)0.f;

#pragma unroll
  for (int cc = 0; cc < 8; cc++) {
    bf16x8 af[4], bfv[4];
#pragma unroll
    for (int mt = 0; mt < 4; mt++)
      af[mt] = *(const bf16x8*)(aptr + (size_t)mt * 16 * 256 + cc * 32);
#pragma unroll
    for (int nt = 0; nt < 4; nt++)
      bfv[nt] = *(const bf16x8*)(bptr[nt] + cc * 32);
#pragma unroll
    for (int mt = 0; mt < 4; mt++)
#pragma unroll
      for (int nt = 0; nt < 4; nt++)
        acc[mt][nt] = __builtin_amdgcn_mfma_f32_16x16x32_bf16(
            af[mt], bfv[nt], acc[mt][nt], 0, 0, 0);
  }

#pragma unroll
  for (int mt = 0; mt < 4; mt++) {
    int oc = oc0 + mt * 16 + lk * 4;
#pragma unroll
    for (int nt = 0; nt < 4; nt++) {
      int pl = p0 + nt * 16 + lr;
      if (pl < HW) {
        u16* dst = out1b + ((size_t)(b * CH + oc)) * HW + pl;
#pragma unroll
        for (int r = 0; r < 4; r++)
          dst[(size_t)r * HW] = bf16_rne(acc[mt][nt][r]);
      }
    }
  }

  // fused stats partials (f32, from registers)
  float sv[4][4], sq[4][4];
#pragma unroll
  for (int mt = 0; mt < 4; mt++)
#pragma unroll
    for (int r = 0; r < 4; r++) { sv[mt][r] = 0.f; sq[mt][r] = 0.f; }
#pragma unroll
  for (int mt = 0; mt < 4; mt++)
#pragma unroll
    for (int nt = 0; nt < 4; nt++) {
      int pl = p0 + nt * 16 + lr;
      if (pl < HW) {
#pragma unroll
        for (int r = 0; r < 4; r++) {
          float v = acc[mt][nt][r];
          sv[mt][r] += v; sq[mt][r] += v * v;
        }
      }
    }
#pragma unroll
  for (int m = 1; m < 16; m <<= 1) {
#pragma unroll
    for (int mt = 0; mt < 4; mt++)
#pragma unroll
      for (int r = 0; r < 4; r++) {
        sv[mt][r] += __shfl_xor(sv[mt][r], m, 64);
        sq[mt][r] += __shfl_xor(sq[mt][r], m, 64);
      }
  }
  if (lr == 0) {
    int slot = (wv >> 1) + 2 * blockIdx.x + 464 * blockIdx.y;
    float* pp = part_c1 + (size_t)slot * 128 * 2;
#pragma unroll
    for (int mt = 0; mt < 4; mt++)
#pragma unroll
      for (int r = 0; r < 4; r++) {
        int ocl = (wv & 1) * 64 + mt * 16 + lk * 4 + r;
        pp[ocl * 2]     = sv[mt][r];
        pp[ocl * 2 + 1] = sq[mt][r];
      }
  }
}

// ---------------------------------------------------------------------------
// K3a: finalize conv1 stats — 256 blocks (one per channel), 256 thr each.
// ---------------------------------------------------------------------------
__global__ __launch_bounds__(256) void stats_fin_c1(
    const float* __restrict__ part_c1, float* __restrict__ st)
{
  const int c = blockIdx.x;
  const int y = c >> 7, ocl = c & 127;
  const int t = threadIdx.x;
  const float* base = part_c1 + (size_t)y * 464 * 256 + ocl * 2;
  float s = 0.f, s2 = 0.f;
  for (int i = t; i < 464; i += 256) {
    s  += base[(size_t)i * 256];
    s2 += base[(size_t)i * 256 + 1];
  }
  __shared__ float ls[256], ls2[256];
  ls[t] = s; ls2[t] = s2;
  __syncthreads();
  for (int off = 128; off > 0; off >>= 1) {
    if (t < off) { ls[t] += ls[t + off]; ls2[t] += ls2[t + off]; }
    __syncthreads();
  }
  if (t == 0) {
    float m = ls[0] / (float)PTOT;
    float var = ls2[0] / (float)PTOT - m * m;
    st[c] = m;
    st[CH + c] = rsqrtf(var + 1e-5f);
  }
}

// ---------------------------------------------------------------------------
// K3b: finalize deform stats — 256 blocks (one per channel), 256 thr each.
// ---------------------------------------------------------------------------
__global__ __launch_bounds__(256) void stats_fin_d(
    const float* __restrict__ part_d, float* __restrict__ st)
{
  const int c = blockIdx.x;
  const int t = threadIdx.x;
  float s = 0.f, s2 = 0.f;
  for (int i = t; i < 456; i += 256) {
    s  += part_d[(size_t)i * 512 + c * 2];
    s2 += part_d[(size_t)i * 512 + c * 2 + 1];
  }
  __shared__ float ls[256], ls2[256];
  ls[t] = s; ls2[t] = s2;
  __syncthreads();
  for (int off = 128; off > 0; off >>= 1) {
    if (t < off) { ls[t] += ls[t + off]; ls2[t] += ls2[t + off]; }
    __syncthreads();
  }
  if (t == 0) {
    float m = ls[0] / (float)PTOT;
    float var = ls2[0] / (float)PTOT - m * m;
    st[c] = m;
    st[CH + c] = rsqrtf(var + 1e-5f);
  }
}

// ---------------------------------------------------------------------------
// K4: read bf16 raw out1b, write normalized bf16 into concat[P][256:512].
// ---------------------------------------------------------------------------
__global__ __launch_bounds__(256) void norm_transpose(
    const u16* __restrict__ out1b, const float* __restrict__ st,
    const float* __restrict__ g, const float* __restrict__ bb,
    u16* __restrict__ concat)
{
  __shared__ float tile[32][36];
  const int b  = blockIdx.z;
  const int c0 = blockIdx.y * 32;
  const int p0 = blockIdx.x * 32;
  int rem = HW - p0; if (rem > 32) rem = 32;
  const int t = threadIdx.x;

  {
    int c  = t >> 3;
    int p4 = (t & 7) * 4;
    int cg = c0 + c;
    float m  = st[cg], rs = st[CH + cg];
    float sc = g[cg] * rs;
    float sh = bb[cg] - m * sc;
    if (p4 < rem) {
      size_t base = ((size_t)b * CH + cg) * HW + p0;
      us4 v4 = *(const us4*)(out1b + base + p4);
      tile[c][p4 + 0] = bf16_f(v4.x) * sc + sh;
      tile[c][p4 + 1] = bf16_f(v4.y) * sc + sh;
      tile[c][p4 + 2] = bf16_f(v4.z) * sc + sh;
      tile[c][p4 + 3] = bf16_f(v4.w) * sc + sh;
    }
  }
  __syncthreads();
  {
    int r  = t >> 3;
    int cq = (t & 7) * 4;
    if (r < rem) {
      us4 o;
      o.x = bf16_rne(tile[cq + 0][r]);
      o.y = bf16_rne(tile[cq + 1][r]);
      o.z = bf16_rne(tile[cq + 2][r]);
      o.w = bf16_rne(tile[cq + 3][r]);
      *(us4*)(concat + ((size_t)b * HW + p0 + r) * 512 + 256 + c0 + cq) = o;
    }
  }
}

// ---------------------------------------------------------------------------
// K7: FUSED offset-conv + deformable conv.
// Phase A: 8 waves = (pos-half ph = wv&1) x (K-group kg = wv>>1 over taps
// {0-2},{3-4},{5-6},{7-8}); each wave = R15 off_mfma body (32 pos x 32 oc),
// partials -> LDS offpart[4][32][64] (overlaid on samp, dead then).
// Param stage: sums 4 LDS partials (replaces offp3 global read), then the
// frozen tap loop runs unchanged.
// ---------------------------------------------------------------------------
__global__ __launch_bounds__(512) void deform_mfma(
    const u16* __restrict__ concat, const u16* __restrict__ wt_offb,
    const float* __restrict__ off_b,
    const u16* __restrict__ wt_b,
    u16* __restrict__ dbufb, float* __restrict__ part_d)
{
  __shared__ u16    samp[64 * 256];   // 32KB; phase A overlays offpart here
  __shared__ int4   sidx[9][64];      // 9KB
  __shared__ float4 swq[9][64];       // 9KB

  float* offpart = (float*)samp;      // [4][32][64] = 32KB

  const int t    = threadIdx.x;
  const int wv   = t >> 6;           // 0..7
  const int lane = t & 63;
  const int lr = lane & 15, lk = lane >> 4;
  const int id   = blockIdx.x;
  const int b    = id & 7;
  const int tile = id >> 3;          // 0..56
  const int P0   = b * HW + tile * 64;
  int lim  = HW - tile * 64;
  if (lim > 64) lim = 64;

  // ---------------- Phase A: offset-conv partials into LDS ----------------
  {
    const int ph = wv & 1;           // pos-half
    const int kg = wv >> 1;          // K-group 0..3
    const int tap_lo = (kg == 0) ? 0 : (kg == 1) ? 3 : (kg == 2) ? 5 : 7;
    const int tap_hi = (kg == 0) ? 3 : (kg == 1) ? 5 : (kg == 2) ? 7 : 9;

    int pl2[2], h2[2], w2[2];
#pragma unroll
    for (int nt = 0; nt < 2; nt++) {
      int p = tile * 64 + ph * 32 + nt * 16 + lr;
      if (p >= HW) p = HW - 1;
      pl2[nt] = p;
      h2[nt] = p / WW;
      w2[nt] = p - h2[nt] * WW;
    }

    f32x4 oacc[2][2];
#pragma unroll
    for (int mt = 0; mt < 2; mt++)
#pragma unroll
      for (int nt = 0; nt < 2; nt++) oacc[mt][nt] = (f32x4)0.f;

#pragma unroll 1
    for (int tap = tap_lo; tap < tap_hi; tap++) {
      int dy = tap / 3 - 1, dx = tap % 3 - 1;
      const u16* bp[2];
      bool valid[2];
#pragma unroll
      for (int nt = 0; nt < 2; nt++) {
        valid[nt] = ((unsigned)(h2[nt] + dy) < HH) && ((unsigned)(w2[nt] + dx) < WW);
        int Ps = b * HW + (valid[nt] ? (pl2[nt] + dy * WW + dx) : pl2[nt]);
        bp[nt] = concat + (size_t)Ps * 512 + lk * 8;
      }
      const u16* ap = wt_offb + ((size_t)tap * 32 + lr) * 512 + lk * 8;
#pragma unroll
      for (int cc = 0; cc < 16; cc++) {
        bf16x8 bfv[2];
#pragma unroll
        for (int nt = 0; nt < 2; nt++) {
          bfv[nt] = *(const bf16x8*)(bp[nt] + cc * 32);
          if (!valid[nt]) bfv[nt] = (bf16x8)(short)0;
        }
        bf16x8 af0 = *(const bf16x8*)(ap + cc * 32);
        bf16x8 af1 = *(const bf16x8*)(ap + 16 * 512 + cc * 32);
#pragma unroll
        for (int nt = 0; nt < 2; nt++) {
          oacc[0][nt] = __builtin_amdgcn_mfma_f32_16x16x32_bf16(af0, bfv[nt], oacc[0][nt], 0, 0, 0);
          oacc[1][nt] = __builtin_amdgcn_mfma_f32_16x16x32_bf16(af1, bfv[nt], oacc[1][nt], 0, 0, 0);
        }
      }
    }

    // write partials: offpart[kg][oc][pos]
#pragma unroll
    for (int mt = 0; mt < 2; mt++) {
#pragma unroll
      for (int nt = 0; nt < 2; nt++) {
        int pos = ph * 32 + nt * 16 + lr;
#pragma unroll
        for (int r = 0; r < 4; r++) {
          int oc = mt * 16 + lk * 4 + r;
          offpart[(kg * 32 + oc) * 64 + pos] = oacc[mt][nt][r];
        }
      }
    }
  }
  __syncthreads();

  // ---------------- Param stage: sum 4 LDS partials, bilinear params ------
  for (int item = t; item < 9 * 64; item += 512) {
    int tap = item >> 6, pos = item & 63;
    int off = (pos < lim) ? pos : (lim - 1);
    int pl = tile * 64 + off;
    int h = pl / WW, w = pl - h * WW;

    float dy = off_b[2 * tap], dx = off_b[2 * tap + 1], ml = off_b[18 + tap];
#pragma unroll
    for (int kg = 0; kg < 4; kg++) {
      const float* bp = offpart + (size_t)kg * 32 * 64 + off;
      dy += bp[(2 * tap    ) * 64];
      dx += bp[(2 * tap + 1) * 64];
      ml += bp[(18 + tap   ) * 64];
    }
    float m = 1.f / (1.f + expf(-ml));
    float ph = dy + (float)(tap / 3 - 1) + (float)h;
    float pw = dx + (float)(tap % 3 - 1) + (float)w;
    float h0f = floorf(ph), w0f = floorf(pw);
    float lh = ph - h0f, lw = pw - w0f;
    int h0 = (int)h0f, w0 = (int)w0f;
    int h1 = h0 + 1, w1 = w0 + 1;
    float vh0 = (h0 >= 0 && h0 < HH) ? 1.f : 0.f;
    float vh1 = (h1 >= 0 && h1 < HH) ? 1.f : 0.f;
    float vw0 = (w0 >= 0 && w0 < WW) ? 1.f : 0.f;
    float vw1 = (w1 >= 0 && w1 < WW) ? 1.f : 0.f;
    float4 wvq;
    wvq.x = (1.f - lh) * (1.f - lw) * m * vh0 * vw0;
    wvq.y = (1.f - lh) * lw         * m * vh0 * vw1;
    wvq.z = lh * (1.f - lw)         * m * vh1 * vw0;
    wvq.w = lh * lw                 * m * vh1 * vw1;
    int hc0 = min(max(h0, 0), HH - 1), hc1 = min(max(h1, 0), HH - 1);
    int wc0 = min(max(w0, 0), WW - 1), wc1 = min(max(w1, 0), WW - 1);
    int gbase = b * HW;
    int4 iv;
    iv.x = (gbase + hc0 * WW + wc0) * 512 + 256;
    iv.y = (gbase + hc0 * WW + wc1) * 512 + 256;
    iv.z = (gbase + hc1 * WW + wc0) * 512 + 256;
    iv.w = (gbase + hc1 * WW + wc1) * 512 + 256;
    swq[tap][pos]  = wvq;
    sidx[tap][pos] = iv;
  }
  __syncthreads();   // params ready; offpart reads done before samp reuse

  f32x4 acc[2][4];
#pragma unroll
  for (int mt = 0; mt < 2; mt++)
#pragma unroll
    for (int nt = 0; nt < 4; nt++) acc[mt][nt] = (f32x4)0.f;

  const int c4 = lane * 4;

  for (int tap = 0; tap < 9; tap++) {
#pragma unroll 2
    for (int it = 0; it < 8; it++) {
      int pos = it * 8 + wv;
      int4  iv = sidx[tap][pos];
      float4 wq = swq[tap][pos];
      uint2 u0 = *(const uint2*)(concat + iv.x + c4);
      uint2 u1 = *(const uint2*)(concat + iv.y + c4);
      uint2 u2 = *(const uint2*)(concat + iv.z + c4);
      uint2 u3 = *(const uint2*)(concat + iv.w + c4);
      float a0, a1, a2, a3;
      a0  = wq.x * __uint_as_float(u0.x << 16);
      a1  = wq.x * __uint_as_float(u0.x & 0xFFFF0000u);
      a2  = wq.x * __uint_as_float(u0.y << 16);
      a3  = wq.x * __uint_as_float(u0.y & 0xFFFF0000u);
      a0 = fmaf(wq.y, __uint_as_float(u1.x << 16), a0);
      a1 = fmaf(wq.y, __uint_as_float(u1.x & 0xFFFF0000u), a1);
      a2 = fmaf(wq.y, __uint_as_float(u1.y << 16), a2);
      a3 = fmaf(wq.y, __uint_as_float(u1.y & 0xFFFF0000u), a3);
      a0 = fmaf(wq.z, __uint_as_float(u2.x << 16), a0);
      a1 = fmaf(wq.z, __uint_as_float(u2.x & 0xFFFF0000u), a1);
      a2 = fmaf(wq.z, __uint_as_float(u2.y << 16), a2);
      a3 = fmaf(wq.z, __uint_as_float(u2.y & 0xFFFF0000u), a3);
      a0 = fmaf(wq.w, __uint_as_float(u3.x << 16), a0);
      a1 = fmaf(wq.w, __uint_as_float(u3.x & 0xFFFF0000u), a1);
      a2 = fmaf(wq.w, __uint_as_float(u3.y << 16), a2);
      a3 = fmaf(wq.w, __uint_as_float(u3.y & 0xFFFF0000u), a3);
      uint2 r;
      r.x = (__float_as_uint(a0) >> 16) | (__float_as_uint(a1) & 0xFFFF0000u);
      r.y = (__float_as_uint(a2) >> 16) | (__float_as_uint(a3) & 0xFFFF0000u);
      u32 byte = (u32)pos * 512u + (u32)c4 * 2u;
      byte ^= (u32)(pos & 7) << 4;
      *(uint2*)((char*)samp + byte) = r;
    }
    __syncthreads();   // samp ready

#pragma unroll 1
    for (int cc = 0; cc < 8; cc++) {
      int c0 = cc * 32;
      bf16x8 bfr[4];
#pragma unroll
      for (int nt = 0; nt < 4; nt++) {
        int pos = nt * 16 + lr;
        u32 byte = (u32)pos * 512u + (u32)(c0 + lk * 8) * 2u;
        byte ^= (u32)(pos & 7) << 4;
        bfr[nt] = *(const bf16x8*)((const char*)samp + byte);
      }
      const u16* wp = wt_b + ((size_t)tap * 256 + wv * 32 + lr) * 256
                      + c0 + lk * 8;
      bf16x8 afr[2];
#pragma unroll
      for (int mt = 0; mt < 2; mt++)
        afr[mt] = *(const bf16x8*)(wp + (size_t)mt * 16 * 256);
#pragma unroll
      for (int mt = 0; mt < 2; mt++)
#pragma unroll
        for (int nt = 0; nt < 4; nt++)
          acc[mt][nt] = __builtin_amdgcn_mfma_f32_16x16x32_bf16(
              afr[mt], bfr[nt], acc[mt][nt], 0, 0, 0);
    }
    __syncthreads();   // GEMM done reading samp before next build
  }

  // epilogue: D[oc][pos] -> dbufb NCHW bf16
#pragma unroll
  for (int mt = 0; mt < 2; mt++) {
    int oc = wv * 32 + mt * 16 + lk * 4;
#pragma unroll
    for (int nt = 0; nt < 4; nt++) {
      int pl = tile * 64 + nt * 16 + lr;
      if (pl < HW) {
        u16* dst = dbufb + ((size_t)(b * CH + oc)) * HW + pl;
#pragma unroll
        for (int r = 0; r < 4; r++)
          dst[(size_t)r * HW] = bf16_rne(acc[mt][nt][r]);
      }
    }
  }

  // fused stats partials (f32, from registers)
  float sv[2][4], sq[2][4];
#pragma unroll
  for (int mt = 0; mt < 2; mt++)
#pragma unroll
    for (int r = 0; r < 4; r++) { sv[mt][r] = 0.f; sq[mt][r] = 0.f; }
#pragma unroll
  for (int mt = 0; mt < 2; mt++)
#pragma unroll
    for (int nt = 0; nt < 4; nt++) {
      int pl = tile * 64 + nt * 16 + lr;
      if (pl < HW) {
#pragma unroll
        for (int r = 0; r < 4; r++) {
          float v = acc[mt][nt][r];
          sv[mt][r] += v; sq[mt][r] += v * v;
        }
      }
    }
#pragma unroll
  for (int m = 1; m < 16; m <<= 1) {
#pragma unroll
    for (int mt = 0; mt < 2; mt++)
#pragma unroll
      for (int r = 0; r < 4; r++) {
        sv[mt][r] += __shfl_xor(sv[mt][r], m, 64);
        sq[mt][r] += __shfl_xor(sq[mt][r], m, 64);
      }
  }
  if (lr == 0) {
    float* pp = part_d + (size_t)blockIdx.x * 512;
#pragma unroll
    for (int mt = 0; mt < 2; mt++)
#pragma unroll
      for (int r = 0; r < 4; r++) {
        int oc = wv * 32 + mt * 16 + lk * 4 + r;
        pp[oc * 2]     = sv[mt][r];
        pp[oc * 2 + 1] = sq[mt][r];
      }
  }
}

// ---------------------------------------------------------------------------
// K8: final = relu(d*sc2+sh2 + (out1raw*sc1+sh1)), bf16 inputs, f32 out.
// ---------------------------------------------------------------------------
__global__ __launch_bounds__(256) void final_nchw(
    const u16* __restrict__ dbufb, const u16* __restrict__ out1b,
    const float* __restrict__ st1, const float* __restrict__ g1,
    const float* __restrict__ b1,
    const float* __restrict__ st2, const float* __restrict__ g2,
    const float* __restrict__ b2, float* __restrict__ out)
{
  u32 i4 = blockIdx.x * 256 + threadIdx.x;
  u32 e = i4 * 4;
  int row = (int)(e / HW);
  int c = row & 255;
  float m1 = st1[c], rs1 = st1[CH + c];
  float sc1 = g1[c] * rs1;
  float sh1 = b1[c] - m1 * sc1;
  float m2 = st2[c], rs2 = st2[CH + c];
  float sc2 = g2[c] * rs2;
  float sh2 = b2[c] - m2 * sc2;
  us4 dv4 = *(const us4*)(dbufb + e);
  us4 xv4 = *(const us4*)(out1b + e);
  float4 o;
  o.x = bf16_f(dv4.x) * sc2 + sh2 + bf16_f(xv4.x) * sc1 + sh1;
  o.y = bf16_f(dv4.y) * sc2 + sh2 + bf16_f(xv4.y) * sc1 + sh1;
  o.z = bf16_f(dv4.z) * sc2 + sh2 + bf16_f(xv4.z) * sc1 + sh1;
  o.w = bf16_f(dv4.w) * sc2 + sh2 + bf16_f(xv4.w) * sc1 + sh1;
  o.x = o.x > 0.f ? o.x : 0.f;
  o.y = o.y > 0.f ? o.y : 0.f;
  o.z = o.z > 0.f ? o.z : 0.f;
  o.w = o.w > 0.f ? o.w : 0.f;
  *(float4*)(out + e) = o;
}

// ---------------------------------------------------------------------------
extern "C" void kernel_launch(void* const* d_in, const int* in_sizes, int n_in,
                              void* d_out, int out_size, void* d_ws, size_t ws_size,
                              hipStream_t stream)
{
  const float* x       = (const float*)d_in[0];
  const float* conv1_w = (const float*)d_in[1];
  const float* bn1_g   = (const float*)d_in[2];
  const float* bn1_b   = (const float*)d_in[3];
  const float* off_w   = (const float*)d_in[4];
  const float* off_b   = (const float*)d_in[5];
  const float* dcn_w   = (const float*)d_in[6];
  const float* norm_g  = (const float*)d_in[8];
  const float* norm_b  = (const float*)d_in[9];
  float* out = (float*)d_out;

  char* ws = (char*)d_ws;
  size_t o = 0;
  u16*   out1b   = (u16*)  (ws + o); o += (size_t)PTOT * CH * 2;       // 14.7 MB bf16 raw conv1
  u16*   concat  = (u16*)  (ws + o); o += (size_t)PTOT * 512 * 2;      // 29.5 MB NHWC bf16 [flipx | xp]
  u16*   dbufb   = (u16*)  (ws + o); o += (size_t)PTOT * CH * 2;       // 14.7 MB NCHW bf16
  u16*   wt_b    = (u16*)  (ws + o); o += (size_t)9 * 256 * 256 * 2;   // 1.18 MB
  u16*   wt_offb = (u16*)  (ws + o); o += (size_t)9 * 32 * 512 * 2;    // 0.29 MB
  u16*   w1b     = (u16*)  (ws + o); o += (size_t)256 * 256 * 2;       // 0.13 MB
  float* st      = (float*)(ws + o); o += 512 * 4;
  float* st2     = (float*)(ws + o); o += 512 * 4;
  float* part_c1 = (float*)(ws + o); o += (size_t)928 * 128 * 2 * 4;   // 950 KB
  float* part_d  = (float*)(ws + o); o += (size_t)456 * 512 * 4;       // 934 KB

  flip_prep<<<dim3(113, 8, 8), 256, 0, stream>>>(x, concat, conv1_w, off_w,
                                                 dcn_w, w1b, wt_offb, wt_b);
  conv1_mfma<<<dim3(232, 2), 256, 0, stream>>>(concat, w1b, out1b, part_c1);
  stats_fin_c1<<<256, 256, 0, stream>>>(part_c1, st);
  norm_transpose<<<dim3(113, 8, 8), 256, 0, stream>>>(out1b, st, bn1_g, bn1_b, concat);
  deform_mfma<<<456, 512, 0, stream>>>(concat, wt_offb, off_b, wt_b, dbufb, part_d);
  stats_fin_d<<<256, 256, 0, stream>>>(part_d, st2);
  final_nchw<<<7200, 256, 0, stream>>>(dbufb, out1b, st, bn1_g, bn1_b,
                                       st2, norm_g, norm_b, out);
}